// Round 2
// baseline (5567.277 us; speedup 1.0000x reference)
//
#include <hip/hip_runtime.h>

typedef unsigned int u32;

#define NNODE 4096
#define NEDGE 8192
#define NEG   12288   /* edges incl self-loops */

// ---------------- graph prep ----------------
__global__ __launch_bounds__(256) void zero_i(int* p, int n){
  int i = blockIdx.x*256 + threadIdx.x; if (i<n) p[i]=0;
}
__global__ __launch_bounds__(256) void hist_k(const int* __restrict__ ei, int* deg_g, int* deg_t){
  int e = blockIdx.x*256 + threadIdx.x; if (e>=NEG) return;
  int dv = (e<NEDGE) ? ei[NEDGE+e] : e-NEDGE;
  atomicAdd(&deg_g[dv],1);
  if (e<NEDGE) atomicAdd(&deg_t[dv],1);
}
__global__ __launch_bounds__(1024) void scan4096(const int* __restrict__ deg, int* __restrict__ off){
  __shared__ int lds[1024];
  int tid = threadIdx.x;
  int v[4]; int s=0;
  #pragma unroll
  for (int j=0;j<4;j++){ v[j]=deg[tid*4+j]; s+=v[j]; }
  lds[tid]=s; __syncthreads();
  for (int d=1; d<1024; d<<=1){
    int t = (tid>=d) ? lds[tid-d] : 0;
    __syncthreads();
    lds[tid] += t;
    __syncthreads();
  }
  int base = (tid>0) ? lds[tid-1] : 0;
  #pragma unroll
  for (int j=0;j<4;j++){ off[tid*4+j]=base; base+=v[j]; }
  if (tid==1023) off[4096]=base;
}
__global__ __launch_bounds__(256) void scatter_k(const int* __restrict__ ei,
    const int* __restrict__ off_g, int* cur_g, int* csr_g,
    const int* __restrict__ off_t, int* cur_t, int* csr_t){
  int e = blockIdx.x*256 + threadIdx.x; if (e>=NEG) return;
  int s, dv;
  if (e<NEDGE){ s=ei[e]; dv=ei[NEDGE+e]; } else { s=dv=e-NEDGE; }
  int p = atomicAdd(&cur_g[dv],1);
  csr_g[off_g[dv]+p]=s;
  if (e<NEDGE){ int p2 = atomicAdd(&cur_t[dv],1); csr_t[off_t[dv]+p2]=s; }
}
__global__ __launch_bounds__(256) void mkdis(const int* __restrict__ deg, float* dis){
  int i = blockIdx.x*256 + threadIdx.x; if (i>=NNODE) return;
  int d = deg[i]; dis[i] = d>0 ? rsqrtf((float)d) : 0.f;
}
__global__ __launch_bounds__(128) void pad_x(const float* __restrict__ x, float* __restrict__ xp){
  int n = blockIdx.x, c = threadIdx.x;
  if (c<80) xp[(size_t)n*80+c] = (c<78) ? x[(size_t)n*78+c] : 0.f;
}
// W1r[(h*80+k), c] = g1_w[k, h*2048+c], zero-padded k>=78
__global__ __launch_bounds__(256) void repack_w1(const float* __restrict__ g1w, float* __restrict__ w1r){
  int i = blockIdx.x*256 + threadIdx.x;   // 640*2048
  int kk = i >> 11, c = i & 2047;
  int h = kk/80, k2 = kk - h*80;
  w1r[i] = (k2<78) ? g1w[(size_t)k2*16384 + h*2048 + c] : 0.f;
}

// ---------------- SGEMM: C[M,N] = A[M,Kp] * B[Kreal,N] (B natural [K,N] layout) ----------------
// EPI: 0 none, 1 +bias, 2 relu(+bias), 3 relu(scale*acc+bias)
#define GBM 128
#define GBN 128
#define GBK 16
template<int EPI>
__global__ __launch_bounds__(256) void sgemm(
    const float* __restrict__ A, int lda,
    const float* __restrict__ B, int ldb,
    float* __restrict__ C, int ldc,
    int Kp, int Kreal, const float* __restrict__ bias, float scale)
{
  __shared__ float As[GBK][GBM];
  __shared__ float Bs[GBK][GBN];
  int tid = threadIdx.x;
  int bm = blockIdx.y*GBM, bn = blockIdx.x*GBN;
  int tm = tid >> 4, tn = tid & 15;
  int rowA = tid >> 1, kA = (tid & 1) * 8;
  int kB = tid >> 4, nB = (tid & 15) * 8;
  float acc[8][8];
  #pragma unroll
  for (int i=0;i<8;i++)
    #pragma unroll
    for (int j=0;j<8;j++) acc[i][j]=0.f;

  for (int k0=0; k0<Kp; k0+=GBK){
    float4 a0 = *reinterpret_cast<const float4*>(A + (size_t)(bm+rowA)*lda + k0 + kA);
    float4 a1 = *reinterpret_cast<const float4*>(A + (size_t)(bm+rowA)*lda + k0 + kA + 4);
    float4 b0 = make_float4(0.f,0.f,0.f,0.f), b1 = make_float4(0.f,0.f,0.f,0.f);
    if (k0 + kB < Kreal){
      b0 = *reinterpret_cast<const float4*>(B + (size_t)(k0+kB)*ldb + bn + nB);
      b1 = *reinterpret_cast<const float4*>(B + (size_t)(k0+kB)*ldb + bn + nB + 4);
    }
    __syncthreads();
    As[kA+0][rowA]=a0.x; As[kA+1][rowA]=a0.y; As[kA+2][rowA]=a0.z; As[kA+3][rowA]=a0.w;
    As[kA+4][rowA]=a1.x; As[kA+5][rowA]=a1.y; As[kA+6][rowA]=a1.z; As[kA+7][rowA]=a1.w;
    *reinterpret_cast<float4*>(&Bs[kB][nB])   = b0;
    *reinterpret_cast<float4*>(&Bs[kB][nB+4]) = b1;
    __syncthreads();
    #pragma unroll
    for (int kk=0;kk<GBK;kk++){
      float a[8], b[8];
      #pragma unroll
      for (int i=0;i<8;i++) a[i] = As[kk][tm*8+i];
      #pragma unroll
      for (int j=0;j<8;j++) b[j] = Bs[kk][tn*8+j];
      #pragma unroll
      for (int i=0;i<8;i++)
        #pragma unroll
        for (int j=0;j<8;j++) acc[i][j] += a[i]*b[j];
    }
  }
  #pragma unroll
  for (int i=0;i<8;i++){
    int row = bm + tm*8 + i;
    #pragma unroll
    for (int j=0;j<8;j++){
      int col = bn + tn*8 + j;
      float v = acc[i][j];
      if (EPI==3) v = v*scale;
      if (EPI>=1) v += bias[col];
      if (EPI>=2) v = fmaxf(v, 0.f);
      C[(size_t)row*ldc + col] = v;
    }
  }
}

// ---------------- GAT attention-vector precompute ----------------
// ws[k*H+h] = sum_c W[k, h*C+c]*as[h*C+c]   (k < Kp, zero for k>=Kreal)
__global__ __launch_bounds__(256) void wsvec(const float* __restrict__ W,
    const float* __restrict__ as_, const float* __restrict__ ad_,
    float* __restrict__ ws, float* __restrict__ wd,
    int Kreal, int H, int C)
{
  int wv = blockIdx.x*4 + (threadIdx.x>>6);
  int lane = threadIdx.x & 63;
  int k = wv / H, h = wv - k*H;
  float ps=0.f, pd=0.f;
  if (k < Kreal){
    const float* wr = W + (size_t)k*((size_t)H*C) + (size_t)h*C;
    const float* ar = as_ + (size_t)h*C;
    const float* dr = ad_ + (size_t)h*C;
    for (int c=lane;c<C;c+=64){ float w=wr[c]; ps += w*ar[c]; pd += w*dr[c]; }
  }
  #pragma unroll
  for (int o=32;o;o>>=1){ ps += __shfl_down(ps,o); pd += __shfl_down(pd,o); }
  if (lane==0){ ws[k*H+h]=ps; wd[k*H+h]=pd; }
}
// als[n,h] = sum_k X[n,k]*ws[k,h]  (H=8)
__global__ __launch_bounds__(256) void alk(const float* __restrict__ X,
    const float* __restrict__ ws, const float* __restrict__ wd,
    float* __restrict__ als, float* __restrict__ ald, int Kp)
{
  int n = blockIdx.x, tid = threadIdx.x;
  int hh = tid>>5, l32 = tid&31;
  const float* xr = X + (size_t)n*Kp;
  float ps=0.f, pd=0.f;
  for (int k=l32;k<Kp;k+=32){
    float xv = xr[k];
    ps += xv*ws[k*8+hh];
    pd += xv*wd[k*8+hh];
  }
  #pragma unroll
  for (int o=16;o;o>>=1){ ps += __shfl_down(ps,o,32); pd += __shfl_down(pd,o,32); }
  if (l32==0){ als[n*8+hh]=ps; ald[n*8+hh]=pd; }
}

// ---------------- GAT1 aggregate-first gather: y1[d, h*80+k] = sum_e alpha[e,h]*xpad[src,k] ----------------
__global__ __launch_bounds__(256) void gat1_gather(
    const float* __restrict__ xpad, const float* __restrict__ als, const float* __restrict__ ald,
    const int* __restrict__ off, const int* __restrict__ csr, float* __restrict__ y1)
{
  int d = blockIdx.x, tid = threadIdx.x;
  int hh = tid>>5, l32 = tid&31;
  int e0 = off[d], e1 = off[d+1];
  __shared__ float mh[8], lih[8], adh[8];
  __shared__ float wl[32][8];
  __shared__ int sl[32];
  if (tid < 8){
    float ad = ald[d*8+tid]; adh[tid]=ad;
    float m=-1e30f, l=0.f;
    for (int e=e0;e<e1;++e){
      float xv = als[csr[e]*8+tid] + ad;
      xv = xv>0.f?xv:0.2f*xv;
      if (xv>m){ l = l*__expf(m-xv)+1.f; m=xv; } else l += __expf(xv-m);
    }
    mh[tid]=m; lih[tid]=1.f/l;
  }
  __syncthreads();
  float acc0=0.f, acc1=0.f, acc2v=0.f;
  for (int cb=e0; cb<e1; cb+=32){
    int ce = min(32, e1-cb);
    if (tid < ce*8){
      int j = tid>>3, h2 = tid&7;
      int s = csr[cb+j];
      if (h2==0) sl[j]=s;
      float xv = als[s*8+h2] + adh[h2];
      xv = xv>0.f?xv:0.2f*xv;
      wl[j][h2] = __expf(xv-mh[h2])*lih[h2];
    }
    __syncthreads();
    for (int j=0;j<ce;++j){
      float w = wl[j][hh];
      const float* xr = xpad + (size_t)sl[j]*80;
      acc0 += w*xr[l32];
      acc1 += w*xr[l32+32];
      if (l32 < 16) acc2v += w*xr[l32+64];
    }
    __syncthreads();
  }
  float* yr = y1 + (size_t)d*640 + hh*80;
  yr[l32] = acc0; yr[l32+32] = acc1;
  if (l32<16) yr[l32+64] = acc2v;
}

// ---------------- GAT per-head aggregation: accum[d,c] += sum_e alpha[e]*h[src,c] ----------------
template<int C>
__global__ __launch_bounds__(256) void gat_agg_head(
    const float* __restrict__ hh_, const float* __restrict__ als, const float* __restrict__ ald,
    const int* __restrict__ off, const int* __restrict__ csr,
    float* __restrict__ accum, int head)
{
  constexpr int V = C/256;
  int d = blockIdx.x, tid = threadIdx.x;
  int e0=off[d], e1=off[d+1];
  __shared__ float wl[32];
  __shared__ int sl[32];
  __shared__ float ml[2];
  float ad = ald[d*8+head];
  if (tid==0){
    float m=-1e30f,l=0.f;
    for (int e=e0;e<e1;++e){
      float xv = als[csr[e]*8+head]+ad;
      xv = xv>0.f?xv:0.2f*xv;
      if (xv>m){ l=l*__expf(m-xv)+1.f; m=xv; } else l+=__expf(xv-m);
    }
    ml[0]=m; ml[1]=1.f/l;
  }
  __syncthreads();
  float m = ml[0], li = ml[1];
  float acc[V];
  #pragma unroll
  for (int v=0;v<V;v++) acc[v]=0.f;
  for (int cb=e0;cb<e1;cb+=32){
    int ce = min(32, e1-cb);
    if (tid<ce){
      int s = csr[cb+tid]; sl[tid]=s;
      float xv = als[s*8+head]+ad;
      xv = xv>0.f?xv:0.2f*xv;
      wl[tid] = __expf(xv-m)*li;
    }
    __syncthreads();
    for (int j=0;j<ce;++j){
      float w = wl[j];
      const float* hr = hh_ + (size_t)sl[j]*C;
      #pragma unroll
      for (int v=0;v<V;v++) acc[v] += w*hr[tid + v*256];
    }
    __syncthreads();
  }
  float* ar = accum + (size_t)d*C;
  #pragma unroll
  for (int v=0;v<V;v++) ar[tid+v*256] += acc[v];
}
// x = relu(acc/8 + b[c])
__global__ __launch_bounds__(256) void finishx(const float* __restrict__ accum,
    const float* __restrict__ bias, float* __restrict__ xo, int Cmask){
  int i = blockIdx.x*256 + threadIdx.x;
  int c = i & Cmask;
  xo[i] = fmaxf(accum[i]*0.125f + bias[c], 0.f);
}

// ---------------- GCN aggregation ----------------
__global__ __launch_bounds__(256) void gcn_agg(const float* __restrict__ hg, const float* __restrict__ dis,
    const int* __restrict__ off, const int* __restrict__ csr,
    const float* __restrict__ bias, float* __restrict__ out)
{
  int d = blockIdx.x, c = threadIdx.x; // C=256
  int e0=off[d], e1=off[d+1];
  float acc=0.f;
  for (int e=e0;e<e1;++e){ int s=csr[e]; acc += dis[s]*hg[(size_t)s*256+c]; }
  out[(size_t)d*256+c] = acc*dis[d] + bias[c];
}

// ---------------- TransformerConv aggregation (H=4, C=512; wave=head) ----------------
__global__ __launch_bounds__(256) void tr_agg(
  const float* __restrict__ q, const float* __restrict__ k, const float* __restrict__ v,
  const float* __restrict__ xs, const int* __restrict__ off, const int* __restrict__ csr,
  float* __restrict__ xt)
{
  int d = blockIdx.x, tid = threadIdx.x;
  int wv = tid>>6, lane = tid&63;
  int e0=off[d], e1=off[d+1];
  __shared__ float osum[4][512];
  float qf[8];
  const float* qr = q + (size_t)d*2048 + wv*512 + lane*8;
  #pragma unroll
  for (int j=0;j<8;j++) qf[j]=qr[j];
  const float scale = 0.04419417382415922f; // 1/sqrt(512)
  float m=-1e30f,l=0.f;
  for (int e=e0;e<e1;++e){
    const float* kr = k + (size_t)csr[e]*2048 + wv*512 + lane*8;
    float p=0.f;
    #pragma unroll
    for (int j=0;j<8;j++) p += qf[j]*kr[j];
    #pragma unroll
    for (int o=32;o;o>>=1) p += __shfl_xor(p,o);
    p *= scale;
    if (p>m){ l=l*__expf(m-p)+1.f; m=p; } else l+=__expf(p-m);
  }
  float li = (e1>e0)?1.f/l:0.f;
  float acc[8]={0.f,0.f,0.f,0.f,0.f,0.f,0.f,0.f};
  for (int e=e0;e<e1;++e){
    int s = csr[e];
    const float* kr = k + (size_t)s*2048 + wv*512 + lane*8;
    float p=0.f;
    #pragma unroll
    for (int j=0;j<8;j++) p += qf[j]*kr[j];
    #pragma unroll
    for (int o=32;o;o>>=1) p += __shfl_xor(p,o);
    float w = __expf(p*scale - m)*li;
    const float* vr = v + (size_t)s*2048 + wv*512 + lane*8;
    #pragma unroll
    for (int j=0;j<8;j++) acc[j] += w*vr[j];
  }
  #pragma unroll
  for (int j=0;j<8;j++) osum[wv][lane*8+j]=acc[j];
  __syncthreads();
  for (int c=tid;c<512;c+=256){
    float o = (osum[0][c]+osum[1][c]+osum[2][c]+osum[3][c])*0.25f + xs[(size_t)d*512+c];
    xt[(size_t)d*512+c] = fmaxf(o,0.f);
  }
}

// ---------------- pooling (batch = i//32) ----------------
__global__ __launch_bounds__(256) void gap_gat(const float* __restrict__ nodes, float* __restrict__ xc){
  int g = blockIdx.x, c = threadIdx.x;
  float s=0.f;
  for (int i=0;i<32;i++) s += nodes[(size_t)(g*32+i)*256 + c];
  xc[(size_t)g*1024 + c] = s*(1.f/32.f);
}
__global__ __launch_bounds__(256) void gap_tr(const float* __restrict__ xt, float* __restrict__ xc){
  int g = blockIdx.x;
  for (int c=threadIdx.x;c<512;c+=256){
    float s=0.f;
    for (int i=0;i<32;i++) s += xt[(size_t)(g*32+i)*512 + c];
    xc[(size_t)g*1024 + 256 + c] = s*(1.f/32.f);
  }
}

// ---------------- small MLPs (M=128) ----------------
__global__ __launch_bounds__(256) void mlpf(const float* __restrict__ A,
      const float* __restrict__ W, const float* __restrict__ b,
      float* __restrict__ out, int K, int N, int ldo, int act)
{
  int m_ = blockIdx.x, n = threadIdx.x;
  if (n >= N) return;
  float acc = b[n];
  for (int kk=0;kk<K;kk++) acc += A[(size_t)m_*K+kk]*W[(size_t)kk*N+n];
  if (act) acc = fmaxf(acc, 0.f);
  out[(size_t)m_*ldo+n] = acc;
}
__global__ __launch_bounds__(128) void b4_sig(const float* __restrict__ A,
      const float* __restrict__ w, const float* __restrict__ b, float* __restrict__ out)
{
  int m_ = threadIdx.x;
  float acc = b[0];
  for (int kk=0;kk<64;kk++) acc += A[(size_t)m_*64+kk]*w[kk];
  out[m_] = 1.f/(1.f+__expf(-acc));
}

extern "C" void kernel_launch(void* const* d_in, const int* in_sizes, int n_in,
                              void* d_out, int out_size, void* d_ws, size_t ws_size,
                              hipStream_t stream)
{
  (void)in_sizes; (void)n_in; (void)out_size; (void)ws_size;
  const float* x     = (const float*)d_in[0];
  const float* fp    = (const float*)d_in[1];
  const int*   ei    = (const int*)d_in[2];
  // d_in[3] = batch (i//32 by construction; unused)
  const float* g1_w  = (const float*)d_in[4];
  const float* g1_as = (const float*)d_in[5];
  const float* g1_ad = (const float*)d_in[6];
  const float* g1_b  = (const float*)d_in[7];
  const float* g2_w  = (const float*)d_in[8];
  const float* g2_as = (const float*)d_in[9];
  const float* g2_ad = (const float*)d_in[10];
  const float* g2_b  = (const float*)d_in[11];
  const float* g3_w  = (const float*)d_in[12];
  const float* g3_as = (const float*)d_in[13];
  const float* g3_ad = (const float*)d_in[14];
  const float* g3_b  = (const float*)d_in[15];
  const float* gcn_w = (const float*)d_in[16];
  const float* gcn_b = (const float*)d_in[17];
  const float* t_wq  = (const float*)d_in[18];
  const float* t_wk  = (const float*)d_in[19];
  const float* t_wv  = (const float*)d_in[20];
  const float* t_bq  = (const float*)d_in[21];
  const float* t_bk  = (const float*)d_in[22];
  const float* t_bv  = (const float*)d_in[23];
  const float* t_ws  = (const float*)d_in[24];
  const float* t_bs  = (const float*)d_in[25];
  const float* fc1_w = (const float*)d_in[26];
  const float* fc1_b = (const float*)d_in[27];
  const float* fc2_w = (const float*)d_in[28];
  const float* fc2_b = (const float*)d_in[29];
  const float* b1_w  = (const float*)d_in[30];
  const float* b1_b  = (const float*)d_in[31];
  const float* b2_w  = (const float*)d_in[32];
  const float* b2_b  = (const float*)d_in[33];
  const float* b3_w  = (const float*)d_in[34];
  const float* b3_b  = (const float*)d_in[35];
  const float* b4_w  = (const float*)d_in[36];
  const float* b4_b  = (const float*)d_in[37];

  char* base = (char*)d_ws;
  size_t offb = 0;
  auto alloc = [&](size_t bytes)->void*{
    void* p = base + offb; offb = (offb + bytes + 255) & ~(size_t)255; return p;
  };
  int*   cnt   = (int*)alloc(16384*4);
  int*   off_g = (int*)alloc(4097*4);
  int*   off_t = (int*)alloc(4097*4);
  int*   csr_g = (int*)alloc(12288*4);
  int*   csr_t = (int*)alloc(8192*4);
  float* dis   = (float*)alloc(4096*4);
  float* xpad  = (float*)alloc((size_t)4096*80*4);
  float* als   = (float*)alloc((size_t)4096*8*4);
  float* ald   = (float*)alloc((size_t)4096*8*4);
  float* wsv   = (float*)alloc((size_t)2048*8*4);
  float* wdv   = (float*)alloc((size_t)2048*8*4);
  float* xc    = (float*)alloc((size_t)128*1024*4);
  float* fpn1  = (float*)alloc((size_t)128*128*4);
  float* m1    = (float*)alloc((size_t)128*256*4);
  float* m2    = (float*)alloc((size_t)128*128*4);
  float* m3    = (float*)alloc((size_t)128*64*4);
  float* x3    = (float*)alloc((size_t)4096*512*4);
  float* hg    = (float*)alloc((size_t)4096*256*4);
  float* gcnN  = (float*)alloc((size_t)4096*256*4);
  float* w1r   = (float*)alloc((size_t)640*2048*4);
  char*  big   = (char*)alloc((size_t)112<<20);
  // phase-1 overlays inside big
  float* y1   = (float*)(big);                      // 10 MB  [0,16)
  float* x1   = (float*)(big + ((size_t)16<<20));   // 32 MB  [16,48)
  float* h2h  = (float*)(big + ((size_t)48<<20));   // 16 MB  [48,64)
  float* acc2 = (float*)(big + ((size_t)64<<20));   // 16 MB  [64,80)
  float* x2   = (float*)(big + ((size_t)80<<20));   // 16 MB  [80,96)
  float* h3h  = (float*)(big + ((size_t)96<<20));   //  8 MB  [96,104)
  float* acc3 = (float*)(big + ((size_t)104<<20));  //  8 MB  [104,112)
  // phase-2 overlays (after GAT stack is done)
  float* qb   = (float*)(big);                      // 32 MB  [0,32)
  float* kb   = (float*)(big + ((size_t)32<<20));   // 32 MB  [32,64)
  float* vb   = (float*)(big + ((size_t)64<<20));   // 32 MB  [64,96)
  float* xs   = (float*)(big + ((size_t)96<<20));   //  8 MB  [96,104)
  float* xt   = (float*)(big + ((size_t)104<<20));  //  8 MB  [104,112)

  int* deg_g = cnt;       int* cur_g = cnt+4096;
  int* deg_t = cnt+8192;  int* cur_t = cnt+12288;

  // ---- graph prep ----
  zero_i<<<64,256,0,stream>>>(cnt, 16384);
  hist_k<<<48,256,0,stream>>>(ei, deg_g, deg_t);
  scan4096<<<1,1024,0,stream>>>(deg_g, off_g);
  scan4096<<<1,1024,0,stream>>>(deg_t, off_t);
  scatter_k<<<48,256,0,stream>>>(ei, off_g, cur_g, csr_g, off_t, cur_t, csr_t);
  mkdis<<<16,256,0,stream>>>(deg_g, dis);
  pad_x<<<4096,128,0,stream>>>(x, xpad);
  repack_w1<<<5120,256,0,stream>>>(g1_w, w1r);

  // ---- GAT1 (aggregate-first) ----
  wsvec<<<160,256,0,stream>>>(g1_w, g1_as, g1_ad, wsv, wdv, 78, 8, 2048);
  alk<<<4096,256,0,stream>>>(xpad, wsv, wdv, als, ald, 80);
  gat1_gather<<<4096,256,0,stream>>>(xpad, als, ald, off_g, csr_g, y1);
  sgemm<3><<<dim3(16,32),256,0,stream>>>(y1, 640, w1r, 2048, x1, 2048, 640, 640, g1_b, 0.125f);

  // ---- GAT2 (head-wise transform-first) ----
  wsvec<<<4096,256,0,stream>>>(g2_w, g2_as, g2_ad, wsv, wdv, 2048, 8, 1024);
  alk<<<4096,256,0,stream>>>(x1, wsv, wdv, als, ald, 2048);
  hipMemsetAsync(acc2, 0, (size_t)4096*1024*4, stream);
  for (int h=0; h<8; ++h){
    sgemm<0><<<dim3(8,32),256,0,stream>>>(x1, 2048, g2_w + h*1024, 8192, h2h, 1024, 2048, 2048, nullptr, 0.f);
    gat_agg_head<1024><<<4096,256,0,stream>>>(h2h, als, ald, off_g, csr_g, acc2, h);
  }
  finishx<<<16384,256,0,stream>>>(acc2, g2_b, x2, 1023);

  // ---- GAT3 (head-wise) ----
  wsvec<<<2048,256,0,stream>>>(g3_w, g3_as, g3_ad, wsv, wdv, 1024, 8, 512);
  alk<<<4096,256,0,stream>>>(x2, wsv, wdv, als, ald, 1024);
  hipMemsetAsync(acc3, 0, (size_t)4096*512*4, stream);
  for (int h=0; h<8; ++h){
    sgemm<0><<<dim3(4,32),256,0,stream>>>(x2, 1024, g3_w + h*512, 4096, h3h, 512, 1024, 1024, nullptr, 0.f);
    gat_agg_head<512><<<4096,256,0,stream>>>(h3h, als, ald, off_g, csr_g, acc3, h);
  }
  finishx<<<8192,256,0,stream>>>(acc3, g3_b, x3, 511);

  // ---- GCN + pool ----
  sgemm<0><<<dim3(2,32),256,0,stream>>>(x3, 512, gcn_w, 256, hg, 256, 512, 512, nullptr, 0.f);
  gcn_agg<<<4096,256,0,stream>>>(hg, dis, off_g, csr_g, gcn_b, gcnN);
  gap_gat<<<128,256,0,stream>>>(gcnN, xc);

  // ---- Transformer branch ----
  sgemm<1><<<dim3(16,32),256,0,stream>>>(xpad, 80, t_wq, 2048, qb, 2048, 80, 78, t_bq, 0.f);
  sgemm<1><<<dim3(16,32),256,0,stream>>>(xpad, 80, t_wk, 2048, kb, 2048, 80, 78, t_bk, 0.f);
  sgemm<1><<<dim3(16,32),256,0,stream>>>(xpad, 80, t_wv, 2048, vb, 2048, 80, 78, t_bv, 0.f);
  sgemm<1><<<dim3(4,32), 256,0,stream>>>(xpad, 80, t_ws, 512,  xs, 512,  80, 78, t_bs, 0.f);
  tr_agg<<<4096,256,0,stream>>>(qb, kb, vb, xs, off_t, csr_t, xt);
  gap_tr<<<128,256,0,stream>>>(xt, xc);

  // ---- fingerprint branch ----
  mlpf<<<128,256,0,stream>>>(fp,   fc1_w, fc1_b, fpn1,   1489, 128, 128, 1);
  mlpf<<<128,256,0,stream>>>(fpn1, fc2_w, fc2_b, xc+768, 128,  256, 1024, 1);

  // ---- head ----
  mlpf<<<128,256,0,stream>>>(xc, b1_w, b1_b, m1, 1024, 256, 256, 1);
  mlpf<<<128,256,0,stream>>>(m1, b2_w, b2_b, m2, 256,  128, 128, 1);
  mlpf<<<128,256,0,stream>>>(m2, b3_w, b3_b, m3, 128,  64,  64,  1);
  b4_sig<<<1,128,0,stream>>>(m3, b4_w, b4_b, (float*)d_out);
}

// Round 3
// 1696.986 us; speedup vs baseline: 3.2807x; 3.2807x over previous
//
#include <hip/hip_runtime.h>

typedef unsigned short u16;
typedef unsigned int   u32;

typedef __bf16 bf16x8 __attribute__((ext_vector_type(8)));
typedef float  f32x4  __attribute__((ext_vector_type(4)));

#define NNODE 4096
#define NEDGE 8192
#define NEG   12288   /* edges incl self-loops */

__device__ __forceinline__ void split_bf(float a, u16& hi, u16& lo){
  u32 u = __float_as_uint(a);
  u32 r = u + 0x7fffu + ((u>>16)&1u);
  hi = (u16)(r>>16);
  float h = __uint_as_float(r & 0xffff0000u);
  float l = a - h;                      // exact (Sterbenz)
  u32 u2 = __float_as_uint(l);
  lo = (u16)((u2 + 0x7fffu + ((u2>>16)&1u)) >> 16);
}

// ---------------- graph prep ----------------
__global__ __launch_bounds__(256) void zero_i(int* p, int n){
  int i = blockIdx.x*256 + threadIdx.x; if (i<n) p[i]=0;
}
__global__ __launch_bounds__(256) void hist_k(const int* __restrict__ ei, int* deg_g, int* deg_t){
  int e = blockIdx.x*256 + threadIdx.x; if (e>=NEG) return;
  int dv = (e<NEDGE) ? ei[NEDGE+e] : e-NEDGE;
  atomicAdd(&deg_g[dv],1);
  if (e<NEDGE) atomicAdd(&deg_t[dv],1);
}
__global__ __launch_bounds__(1024) void scan4096(const int* __restrict__ deg, int* __restrict__ off){
  __shared__ int lds[1024];
  int tid = threadIdx.x;
  int v[4]; int s=0;
  #pragma unroll
  for (int j=0;j<4;j++){ v[j]=deg[tid*4+j]; s+=v[j]; }
  lds[tid]=s; __syncthreads();
  for (int d=1; d<1024; d<<=1){
    int t = (tid>=d) ? lds[tid-d] : 0;
    __syncthreads();
    lds[tid] += t;
    __syncthreads();
  }
  int base = (tid>0) ? lds[tid-1] : 0;
  #pragma unroll
  for (int j=0;j<4;j++){ off[tid*4+j]=base; base+=v[j]; }
  if (tid==1023) off[4096]=base;
}
__global__ __launch_bounds__(256) void scatter_k(const int* __restrict__ ei,
    const int* __restrict__ off_g, int* cur_g, int* csr_g,
    const int* __restrict__ off_t, int* cur_t, int* csr_t){
  int e = blockIdx.x*256 + threadIdx.x; if (e>=NEG) return;
  int s, dv;
  if (e<NEDGE){ s=ei[e]; dv=ei[NEDGE+e]; } else { s=dv=e-NEDGE; }
  int p = atomicAdd(&cur_g[dv],1);
  csr_g[off_g[dv]+p]=s;
  if (e<NEDGE){ int p2 = atomicAdd(&cur_t[dv],1); csr_t[off_t[dv]+p2]=s; }
}
__global__ __launch_bounds__(256) void mkdis(const int* __restrict__ deg, float* dis){
  int i = blockIdx.x*256 + threadIdx.x; if (i>=NNODE) return;
  int d = deg[i]; dis[i] = d>0 ? rsqrtf((float)d) : 0.f;
}
__global__ __launch_bounds__(128) void pad_x(const float* __restrict__ x, float* __restrict__ xp){
  int n = blockIdx.x, c = threadIdx.x;
  if (c<80) xp[(size_t)n*80+c] = (c<78) ? x[(size_t)n*78+c] : 0.f;
}
// W1r[(h*80+k), c] = g1_w[k, h*2048+c], zero-padded k>=78
__global__ __launch_bounds__(256) void repack_w1(const float* __restrict__ g1w, float* __restrict__ w1r){
  int i = blockIdx.x*256 + threadIdx.x;   // 640*2048
  int kk = i >> 11, c = i & 2047;
  int h = kk/80, k2 = kk - h*80;
  w1r[i] = (k2<78) ? g1w[(size_t)k2*16384 + h*2048 + c] : 0.f;
}

// ---------------- fp32 -> bf16 hi/lo decompose (row-major [M,K] -> [M,Kp]) ----------------
__global__ __launch_bounds__(256) void dec(const float* __restrict__ A,
    u16* __restrict__ hi, u16* __restrict__ lo, int K, int Kp){
  int i = blockIdx.x*256 + threadIdx.x;     // grid = M*Kp/256
  int r = i / Kp, k = i - r*Kp;
  float a = (k<K) ? A[(size_t)r*K + k] : 0.f;
  u16 h, l; split_bf(a, h, l);
  hi[i]=h; lo[i]=l;
}

// ---------------- transpose + decompose: W[K,Ntot] cols [n0,n0+Nw) -> hi/lo [Nw,Kp] ----------------
__global__ __launch_bounds__(256) void tpd(const float* __restrict__ in, int Ntot, int n0,
    int K, int Kp, u16* __restrict__ outh, u16* __restrict__ outl){
  __shared__ float t[32][33];
  int bx = blockIdx.x*32;   // n in window
  int by = blockIdx.y*32;   // k
  int tx = threadIdx.x & 31, ty = threadIdx.x >> 5;
  for (int i=ty;i<32;i+=8){
    int kk=by+i;
    t[i][tx] = (kk<K) ? in[(size_t)kk*Ntot + n0 + bx + tx] : 0.f;
  }
  __syncthreads();
  for (int i=ty;i<32;i+=8){
    int nn=bx+i, kk=by+tx;
    u16 h, l; split_bf(t[tx][i], h, l);
    outh[(size_t)nn*Kp+kk]=h; outl[(size_t)nn*Kp+kk]=l;
  }
}

// ---------------- split-bf16 MFMA GEMM: C[M,N](fp32) = A[M,K] * Bt[N,K]^T ----------------
// EPI: 0 none, 1 +bias, 3 relu(scale*acc+bias)
#define BM 128
#define BN 128
#define BKP 40
template<int EPI>
__global__ __launch_bounds__(256,2) void mgemm(
    const u16* __restrict__ Ah, const u16* __restrict__ Al, int lda,
    const u16* __restrict__ Bh, const u16* __restrict__ Bl, int ldb,
    float* __restrict__ C, int ldc, int K,
    const float* __restrict__ bias, float scale)
{
  __shared__ u16 Ash[BM*BKP], Asl[BM*BKP], Bsh[BN*BKP], Bsl[BN*BKP];
  int tid = threadIdx.x;
  int bm = blockIdx.y*BM, bn = blockIdx.x*BN;
  int lane = tid & 63, wave = tid >> 6;
  int wr = (wave>>1)*64, wc = (wave&1)*64;
  int m16 = lane & 15, quad = lane >> 4;
  int lr = tid >> 1, lh = (tid & 1) * 16;

  f32x4 acc[4][4] = {};
  for (int k0=0; k0<K; k0+=32){
    const uint4* gah = (const uint4*)(Ah + (size_t)(bm+lr)*lda + k0 + lh);
    uint4 a0 = gah[0], a1 = gah[1];
    const uint4* gal = (const uint4*)(Al + (size_t)(bm+lr)*lda + k0 + lh);
    uint4 a2 = gal[0], a3 = gal[1];
    const uint4* gbh = (const uint4*)(Bh + (size_t)(bn+lr)*ldb + k0 + lh);
    uint4 b0 = gbh[0], b1 = gbh[1];
    const uint4* gbl = (const uint4*)(Bl + (size_t)(bn+lr)*ldb + k0 + lh);
    uint4 b2 = gbl[0], b3 = gbl[1];
    __syncthreads();
    *(uint4*)&Ash[lr*BKP+lh]   = a0; *(uint4*)&Ash[lr*BKP+lh+8] = a1;
    *(uint4*)&Asl[lr*BKP+lh]   = a2; *(uint4*)&Asl[lr*BKP+lh+8] = a3;
    *(uint4*)&Bsh[lr*BKP+lh]   = b0; *(uint4*)&Bsh[lr*BKP+lh+8] = b1;
    *(uint4*)&Bsl[lr*BKP+lh]   = b2; *(uint4*)&Bsl[lr*BKP+lh+8] = b3;
    __syncthreads();
    int kq = quad*8;
    bf16x8 ah[4], al_[4], bh_[4], bl_[4];
    #pragma unroll
    for (int i=0;i<4;i++){
      ah[i]  = *(const bf16x8*)&Ash[(wr+i*16+m16)*BKP + kq];
      al_[i] = *(const bf16x8*)&Asl[(wr+i*16+m16)*BKP + kq];
    }
    #pragma unroll
    for (int j=0;j<4;j++){
      bh_[j] = *(const bf16x8*)&Bsh[(wc+j*16+m16)*BKP + kq];
      bl_[j] = *(const bf16x8*)&Bsl[(wc+j*16+m16)*BKP + kq];
    }
    #pragma unroll
    for (int i=0;i<4;i++)
      #pragma unroll
      for (int j=0;j<4;j++){
        acc[i][j] = __builtin_amdgcn_mfma_f32_16x16x32_bf16(ah[i],  bh_[j], acc[i][j], 0,0,0);
        acc[i][j] = __builtin_amdgcn_mfma_f32_16x16x32_bf16(ah[i],  bl_[j], acc[i][j], 0,0,0);
        acc[i][j] = __builtin_amdgcn_mfma_f32_16x16x32_bf16(al_[i], bh_[j], acc[i][j], 0,0,0);
      }
  }
  #pragma unroll
  for (int i=0;i<4;i++){
    int row0 = bm + wr + i*16 + quad*4;
    #pragma unroll
    for (int j=0;j<4;j++){
      int col = bn + wc + j*16 + m16;
      float bv = (EPI>=1) ? bias[col] : 0.f;
      #pragma unroll
      for (int r=0;r<4;r++){
        float v = acc[i][j][r];
        if (EPI==3) v = fmaxf(v*scale + bv, 0.f);
        else if (EPI==1) v = v + bv;
        C[(size_t)(row0+r)*ldc + col] = v;
      }
    }
  }
}

// ---------------- GAT attention-vector precompute ----------------
__global__ __launch_bounds__(256) void wsvec(const float* __restrict__ W,
    const float* __restrict__ as_, const float* __restrict__ ad_,
    float* __restrict__ ws, float* __restrict__ wd,
    int Kreal, int H, int C)
{
  int wv = blockIdx.x*4 + (threadIdx.x>>6);
  int lane = threadIdx.x & 63;
  int k = wv / H, h = wv - k*H;
  float ps=0.f, pd=0.f;
  if (k < Kreal){
    const float* wr = W + (size_t)k*((size_t)H*C) + (size_t)h*C;
    const float* ar = as_ + (size_t)h*C;
    const float* dr = ad_ + (size_t)h*C;
    for (int c=lane;c<C;c+=64){ float w=wr[c]; ps += w*ar[c]; pd += w*dr[c]; }
  }
  #pragma unroll
  for (int o=32;o;o>>=1){ ps += __shfl_down(ps,o); pd += __shfl_down(pd,o); }
  if (lane==0){ ws[k*H+h]=ps; wd[k*H+h]=pd; }
}
__global__ __launch_bounds__(256) void alk(const float* __restrict__ X,
    const float* __restrict__ ws, const float* __restrict__ wd,
    float* __restrict__ als, float* __restrict__ ald, int Kp)
{
  int n = blockIdx.x, tid = threadIdx.x;
  int hh = tid>>5, l32 = tid&31;
  const float* xr = X + (size_t)n*Kp;
  float ps=0.f, pd=0.f;
  for (int k=l32;k<Kp;k+=32){
    float xv = xr[k];
    ps += xv*ws[k*8+hh];
    pd += xv*wd[k*8+hh];
  }
  #pragma unroll
  for (int o=16;o;o>>=1){ ps += __shfl_down(ps,o,32); pd += __shfl_down(pd,o,32); }
  if (l32==0){ als[n*8+hh]=ps; ald[n*8+hh]=pd; }
}

// ---------------- GAT1 aggregate-first gather ----------------
__global__ __launch_bounds__(256) void gat1_gather(
    const float* __restrict__ xpad, const float* __restrict__ als, const float* __restrict__ ald,
    const int* __restrict__ off, const int* __restrict__ csr, float* __restrict__ y1)
{
  int d = blockIdx.x, tid = threadIdx.x;
  int hh = tid>>5, l32 = tid&31;
  int e0 = off[d], e1 = off[d+1];
  __shared__ float mh[8], lih[8], adh[8];
  __shared__ float wl[32][8];
  __shared__ int sl[32];
  if (tid < 8){
    float ad = ald[d*8+tid]; adh[tid]=ad;
    float m=-1e30f, l=0.f;
    for (int e=e0;e<e1;++e){
      float xv = als[csr[e]*8+tid] + ad;
      xv = xv>0.f?xv:0.2f*xv;
      if (xv>m){ l = l*__expf(m-xv)+1.f; m=xv; } else l += __expf(xv-m);
    }
    mh[tid]=m; lih[tid]=1.f/l;
  }
  __syncthreads();
  float acc0=0.f, acc1=0.f, acc2v=0.f;
  for (int cb=e0; cb<e1; cb+=32){
    int ce = min(32, e1-cb);
    if (tid < ce*8){
      int j = tid>>3, h2 = tid&7;
      int s = csr[cb+j];
      if (h2==0) sl[j]=s;
      float xv = als[s*8+h2] + adh[h2];
      xv = xv>0.f?xv:0.2f*xv;
      wl[j][h2] = __expf(xv-mh[h2])*lih[h2];
    }
    __syncthreads();
    for (int j=0;j<ce;++j){
      float w = wl[j][hh];
      const float* xr = xpad + (size_t)sl[j]*80;
      acc0 += w*xr[l32];
      acc1 += w*xr[l32+32];
      if (l32 < 16) acc2v += w*xr[l32+64];
    }
    __syncthreads();
  }
  float* yr = y1 + (size_t)d*640 + hh*80;
  yr[l32] = acc0; yr[l32+32] = acc1;
  if (l32<16) yr[l32+64] = acc2v;
}

// ---------------- all-head chunk aggregation: accum[d,c] += sum_hh sum_e alpha*h[src, hh*C+c] ----------------
template<int HPC, int C>
__global__ __launch_bounds__(256) void gat_aggN(
    const float* __restrict__ h, const float* __restrict__ als, const float* __restrict__ ald,
    const int* __restrict__ off, const int* __restrict__ csr,
    float* __restrict__ accum, int head0)
{
  constexpr int V = C/256;
  int d = blockIdx.x, tid = threadIdx.x;
  int e0=off[d], e1=off[d+1];
  __shared__ float mh[HPC], lih[HPC], adh[HPC];
  __shared__ float wl[32][HPC];
  __shared__ int sl[32];
  if (tid < HPC){
    float ad = ald[d*8 + head0 + tid]; adh[tid]=ad;
    float m=-1e30f,l=0.f;
    for (int e=e0;e<e1;++e){
      float xv = als[csr[e]*8 + head0 + tid]+ad;
      xv = xv>0.f?xv:0.2f*xv;
      if (xv>m){ l=l*__expf(m-xv)+1.f; m=xv; } else l+=__expf(xv-m);
    }
    mh[tid]=m; lih[tid]=1.f/l;
  }
  __syncthreads();
  float acc[HPC][V];
  #pragma unroll
  for (int a=0;a<HPC;a++)
    #pragma unroll
    for (int v=0;v<V;v++) acc[a][v]=0.f;
  int c0 = tid*V;
  for (int cb=e0;cb<e1;cb+=32){
    int ce = min(32, e1-cb);
    if (tid < ce*HPC){
      int j = tid/HPC, h2 = tid - j*HPC;
      int s = csr[cb+j];
      if (h2==0) sl[j]=s;
      float xv = als[s*8 + head0 + h2] + adh[h2];
      xv = xv>0.f?xv:0.2f*xv;
      wl[j][h2] = __expf(xv-mh[h2])*lih[h2];
    }
    __syncthreads();
    for (int j=0;j<ce;++j){
      const float* hr = h + (size_t)sl[j]*(HPC*C);
      #pragma unroll
      for (int a=0;a<HPC;a++){
        float w = wl[j][a];
        #pragma unroll
        for (int v=0;v<V;v++) acc[a][v] += w*hr[a*C + c0 + v];
      }
    }
    __syncthreads();
  }
  float* ar = accum + (size_t)d*C + c0;
  #pragma unroll
  for (int v=0;v<V;v++){
    float s2 = 0.f;
    #pragma unroll
    for (int a=0;a<HPC;a++) s2 += acc[a][v];
    ar[v] += s2;
  }
}
// x = relu(acc/8 + b[c])
__global__ __launch_bounds__(256) void finishx(const float* __restrict__ accum,
    const float* __restrict__ bias, float* __restrict__ xo, int Cmask){
  int i = blockIdx.x*256 + threadIdx.x;
  int c = i & Cmask;
  xo[i] = fmaxf(accum[i]*0.125f + bias[c], 0.f);
}

// ---------------- pooled GCN aggregation: z[g,c] = (1/32) sum_{d in g} dis[d] sum_e dis[s] x3[s,c] ----------------
__global__ __launch_bounds__(256) void pool_gcn(const float* __restrict__ x3,
    const float* __restrict__ dis, const int* __restrict__ off, const int* __restrict__ csr,
    float* __restrict__ z)
{
  int g = blockIdx.x, tid = threadIdx.x;
  int c0 = tid*2;
  float a0=0.f, a1=0.f;
  for (int dd=0; dd<32; ++dd){
    int d = g*32+dd;
    int e0=off[d], e1=off[d+1];
    float b0=0.f, b1=0.f;
    for (int e=e0;e<e1;++e){
      int s = csr[e]; float ds = dis[s];
      const float* xr = x3 + (size_t)s*512 + c0;
      b0 += ds*xr[0]; b1 += ds*xr[1];
    }
    float dw = dis[d];
    a0 += dw*b0; a1 += dw*b1;
  }
  z[(size_t)g*512+c0]   = a0*(1.f/32.f);
  z[(size_t)g*512+c0+1] = a1*(1.f/32.f);
}

// ---------------- TransformerConv aggregation (qkvs: [4096, 6656] = q|k|v|xs) ----------------
__global__ __launch_bounds__(256) void tr_agg(
  const float* __restrict__ qkvs, const int* __restrict__ off, const int* __restrict__ csr,
  float* __restrict__ xt)
{
  int d = blockIdx.x, tid = threadIdx.x;
  int wv = tid>>6, lane = tid&63;
  int e0=off[d], e1=off[d+1];
  __shared__ float osum[4][512];
  float qf[8];
  const float* qr = qkvs + (size_t)d*6656 + wv*512 + lane*8;
  #pragma unroll
  for (int j=0;j<8;j++) qf[j]=qr[j];
  const float scale = 0.04419417382415922f; // 1/sqrt(512)
  float m=-1e30f,l=0.f;
  for (int e=e0;e<e1;++e){
    const float* kr = qkvs + (size_t)csr[e]*6656 + 2048 + wv*512 + lane*8;
    float p=0.f;
    #pragma unroll
    for (int j=0;j<8;j++) p += qf[j]*kr[j];
    #pragma unroll
    for (int o=32;o;o>>=1) p += __shfl_xor(p,o);
    p *= scale;
    if (p>m){ l=l*__expf(m-p)+1.f; m=p; } else l+=__expf(p-m);
  }
  float li = (e1>e0)?1.f/l:0.f;
  float acc[8]={0.f,0.f,0.f,0.f,0.f,0.f,0.f,0.f};
  for (int e=e0;e<e1;++e){
    int s = csr[e];
    const float* kr = qkvs + (size_t)s*6656 + 2048 + wv*512 + lane*8;
    float p=0.f;
    #pragma unroll
    for (int j=0;j<8;j++) p += qf[j]*kr[j];
    #pragma unroll
    for (int o=32;o;o>>=1) p += __shfl_xor(p,o);
    float w = __expf(p*scale - m)*li;
    const float* vr = qkvs + (size_t)s*6656 + 4096 + wv*512 + lane*8;
    #pragma unroll
    for (int j=0;j<8;j++) acc[j] += w*vr[j];
  }
  #pragma unroll
  for (int j=0;j<8;j++) osum[wv][lane*8+j]=acc[j];
  __syncthreads();
  for (int c=tid;c<512;c+=256){
    float o = (osum[0][c]+osum[1][c]+osum[2][c]+osum[3][c])*0.25f
            + qkvs[(size_t)d*6656 + 6144 + c];
    xt[(size_t)d*512+c] = fmaxf(o,0.f);
  }
}

// ---------------- bias concat for qkv GEMM ----------------
__global__ __launch_bounds__(256) void catb(const float* __restrict__ bq, const float* __restrict__ bk,
    const float* __restrict__ bv, const float* __restrict__ bs, float* __restrict__ o){
  int i = blockIdx.x*256 + threadIdx.x; if (i>=6656) return;
  float v;
  if (i<2048) v=bq[i]; else if (i<4096) v=bk[i-2048];
  else if (i<6144) v=bv[i-4096]; else v=bs[i-6144];
  o[i]=v;
}

// ---------------- fused head: gcn-pool GEMM + xt pool + fp branch + b1..b4 + sigmoid ----------------
__global__ __launch_bounds__(256) void head_k(
  const float* __restrict__ z, const float* __restrict__ xt, const float* __restrict__ fp,
  const float* __restrict__ gcn_w, const float* __restrict__ gcn_b,
  const float* __restrict__ fc1_w, const float* __restrict__ fc1_b,
  const float* __restrict__ fc2_w, const float* __restrict__ fc2_b,
  const float* __restrict__ b1_w, const float* __restrict__ b1_b,
  const float* __restrict__ b2_w, const float* __restrict__ b2_b,
  const float* __restrict__ b3_w, const float* __restrict__ b3_b,
  const float* __restrict__ b4_w, const float* __restrict__ b4_b,
  float* __restrict__ out)
{
  int g = blockIdx.x, tid = threadIdx.x;
  __shared__ float xc[1024];
  __shared__ float sa[1504];
  __shared__ float sb[256];
  __shared__ float scm[256];
  // stage z row
  for (int c=tid;c<512;c+=256) sa[c] = z[(size_t)g*512+c];
  __syncthreads();
  // x_gat part: xc[0..256) = z@Wg + gcn_b
  {
    float acc = gcn_b[tid];
    #pragma unroll 8
    for (int k=0;k<512;k++) acc += sa[k]*gcn_w[k*256+tid];
    xc[tid] = acc;
  }
  // x_trans part: xc[256..768) = mean over 32 nodes of xt
  for (int c=tid;c<512;c+=256){
    float s=0.f;
    for (int i=0;i<32;i++) s += xt[(size_t)(g*32+i)*512 + c];
    xc[256+c] = s*(1.f/32.f);
  }
  __syncthreads();
  // fp branch: stage fp row
  for (int c=tid;c<1489;c+=256) sa[c] = fp[(size_t)g*1489+c];
  __syncthreads();
  { // fc1 (K=1489 -> 128), 2-way k-split
    int n = tid & 127, half = tid >> 7;
    int k0 = half ? 745 : 0, k1 = half ? 1489 : 745;
    float acc = 0.f;
    #pragma unroll 8
    for (int k=k0;k<k1;k++) acc += sa[k]*fc1_w[(size_t)k*128+n];
    sb[tid]=acc;
  }
  __syncthreads();
  if (tid<128) scm[tid] = fmaxf(sb[tid]+sb[tid+128]+fc1_b[tid], 0.f);
  __syncthreads();
  { // fc2 (128 -> 256)
    float acc = fc2_b[tid];
    #pragma unroll 8
    for (int k=0;k<128;k++) acc += scm[k]*fc2_w[k*256+tid];
    xc[768+tid] = fmaxf(acc, 0.f);
  }
  __syncthreads();
  { // b1 (1024 -> 256)
    float acc = b1_b[tid];
    #pragma unroll 8
    for (int k=0;k<1024;k++) acc += xc[k]*b1_w[k*256+tid];
    sa[tid] = fmaxf(acc, 0.f);
  }
  __syncthreads();
  { // b2 (256 -> 128), 2-way k-split
    int n = tid & 127, half = tid >> 7;
    int k0 = half*128;
    float acc = 0.f;
    #pragma unroll 8
    for (int k=k0;k<k0+128;k++) acc += sa[k]*b2_w[k*128+n];
    sb[tid]=acc;
  }
  __syncthreads();
  if (tid<128) scm[tid] = fmaxf(sb[tid]+sb[tid+128]+b2_b[tid], 0.f);
  __syncthreads();
  { // b3 (128 -> 64), 4-way k-split
    int n = tid & 63, part = tid >> 6;
    int k0 = part*32;
    float acc = 0.f;
    #pragma unroll 8
    for (int k=k0;k<k0+32;k++) acc += scm[k]*b3_w[k*64+n];
    sb[tid]=acc;
  }
  __syncthreads();
  if (tid<64) sa[tid] = fmaxf(sb[tid]+sb[tid+64]+sb[tid+128]+sb[tid+192]+b3_b[tid], 0.f);
  __syncthreads();
  if (tid<64){ // b4 (64 -> 1) + sigmoid
    float p = sa[tid]*b4_w[tid];
    #pragma unroll
    for (int o=32;o;o>>=1) p += __shfl_down(p,o);
    if (tid==0) out[g] = 1.f/(1.f+__expf(-(p + b4_b[0])));
  }
}

extern "C" void kernel_launch(void* const* d_in, const int* in_sizes, int n_in,
                              void* d_out, int out_size, void* d_ws, size_t ws_size,
                              hipStream_t stream)
{
  (void)in_sizes; (void)n_in; (void)out_size; (void)ws_size;
  const float* x     = (const float*)d_in[0];
  const float* fp    = (const float*)d_in[1];
  const int*   ei    = (const int*)d_in[2];
  const float* g1_w  = (const float*)d_in[4];
  const float* g1_as = (const float*)d_in[5];
  const float* g1_ad = (const float*)d_in[6];
  const float* g1_b  = (const float*)d_in[7];
  const float* g2_w  = (const float*)d_in[8];
  const float* g2_as = (const float*)d_in[9];
  const float* g2_ad = (const float*)d_in[10];
  const float* g2_b  = (const float*)d_in[11];
  const float* g3_w  = (const float*)d_in[12];
  const float* g3_as = (const float*)d_in[13];
  const float* g3_ad = (const float*)d_in[14];
  const float* g3_b  = (const float*)d_in[15];
  const float* gcn_w = (const float*)d_in[16];
  const float* gcn_b = (const float*)d_in[17];
  const float* t_wq  = (const float*)d_in[18];
  const float* t_wk  = (const float*)d_in[19];
  const float* t_wv  = (const float*)d_in[20];
  const float* t_bq  = (const float*)d_in[21];
  const float* t_bk  = (const float*)d_in[22];
  const float* t_bv  = (const float*)d_in[23];
  const float* t_ws  = (const float*)d_in[24];
  const float* t_bs  = (const float*)d_in[25];
  const float* fc1_w = (const float*)d_in[26];
  const float* fc1_b = (const float*)d_in[27];
  const float* fc2_w = (const float*)d_in[28];
  const float* fc2_b = (const float*)d_in[29];
  const float* b1_w  = (const float*)d_in[30];
  const float* b1_b  = (const float*)d_in[31];
  const float* b2_w  = (const float*)d_in[32];
  const float* b2_b  = (const float*)d_in[33];
  const float* b3_w  = (const float*)d_in[34];
  const float* b3_b  = (const float*)d_in[35];
  const float* b4_w  = (const float*)d_in[36];
  const float* b4_b  = (const float*)d_in[37];

  char* base = (char*)d_ws;
  size_t offb = 0;
  auto alloc = [&](size_t bytes)->void*{
    void* p = base + offb; offb = (offb + bytes + 255) & ~(size_t)255; return p;
  };
  int*   cnt   = (int*)alloc(16384*4);
  int*   off_g = (int*)alloc(4097*4);
  int*   off_t = (int*)alloc(4097*4);
  int*   csr_g = (int*)alloc(12288*4);
  int*   csr_t = (int*)alloc(8192*4);
  float* dis   = (float*)alloc(4096*4);
  float* xpad  = (float*)alloc((size_t)4096*80*4);
  u16*   xph   = (u16*)alloc((size_t)4096*96*2);
  u16*   xpl   = (u16*)alloc((size_t)4096*96*2);
  float* als   = (float*)alloc((size_t)4096*8*4);
  float* ald   = (float*)alloc((size_t)4096*8*4);
  float* wsv   = (float*)alloc((size_t)2048*8*4);
  float* wdv   = (float*)alloc((size_t)2048*8*4);
  float* zbuf  = (float*)alloc((size_t)128*512*4);
  float* cbias = (float*)alloc((size_t)6656*4);
  float* w1r   = (float*)alloc((size_t)640*2048*4);
  char*  big   = (char*)alloc((size_t)144<<20);

  // GAT-phase overlays
  float* x1    = (float*)(big);                         // [0,32) MB
  float* y1    = (float*)(big + ((size_t)32<<20));      // [32,42)
  u16*   y1h   = (u16*)  (big + ((size_t)42<<20));      // [42,47)
  u16*   y1l   = (u16*)  (big + ((size_t)47<<20));      // [47,52)
  u16*   w1rth = (u16*)  (big + ((size_t)52<<20));      // [52,55)
  u16*   w1rtl = (u16*)  (big + ((size_t)55<<20));      // [55,58)
  u16*   x1h   = (u16*)  (big + ((size_t)32<<20));      // [32,48)  (y1 dead)
  u16*   x1l   = (u16*)  (big + ((size_t)48<<20));      // [48,64)
  float* h2    = (float*)(big + ((size_t)64<<20));      // [64,96)
  u16*   w2th  = (u16*)  (big + ((size_t)96<<20));      // [96,104)
  u16*   w2tl  = (u16*)  (big + ((size_t)104<<20));     // [104,112)
  float* acc2  = (float*)(big + ((size_t)112<<20));     // [112,128)
  float* x2    = (float*)(big + ((size_t)128<<20));     // [128,144)
  u16*   x2h   = (u16*)  (big);                         // [0,8)   (x1 dead)
  u16*   x2l   = (u16*)  (big + ((size_t)8<<20));       // [8,16)
  float* h3    = (float*)(big + ((size_t)16<<20));      // [16,48)
  u16*   w3th  = (u16*)  (big + ((size_t)48<<20));      // [48,52)
  u16*   w3tl  = (u16*)  (big + ((size_t)52<<20));      // [52,56)
  float* acc3  = (float*)(big + ((size_t)56<<20));      // [56,64)
  float* x3    = (float*)(big + ((size_t)64<<20));      // [64,72)
  // transformer-phase overlays (GAT stack + pool_gcn done)
  u16*   qkvTh = (u16*)  (big);                         // [0,2)
  u16*   qkvTl = (u16*)  (big + ((size_t)2<<20));       // [2,4)
  float* qkvs  = (float*)(big + ((size_t)8<<20));       // [8,117)
  float* xt    = (float*)(big + ((size_t)120<<20));     // [120,128)

  int* deg_g = cnt;       int* cur_g = cnt+4096;
  int* deg_t = cnt+8192;  int* cur_t = cnt+12288;

  // ---- graph prep ----
  zero_i<<<64,256,0,stream>>>(cnt, 16384);
  hist_k<<<48,256,0,stream>>>(ei, deg_g, deg_t);
  scan4096<<<1,1024,0,stream>>>(deg_g, off_g);
  scan4096<<<1,1024,0,stream>>>(deg_t, off_t);
  scatter_k<<<48,256,0,stream>>>(ei, off_g, cur_g, csr_g, off_t, cur_t, csr_t);
  mkdis<<<16,256,0,stream>>>(deg_g, dis);
  pad_x<<<4096,128,0,stream>>>(x, xpad);
  repack_w1<<<5120,256,0,stream>>>(g1_w, w1r);
  dec<<<1536,256,0,stream>>>(xpad, xph, xpl, 80, 96);

  // ---- GAT1 (aggregate-first) ----
  wsvec<<<160,256,0,stream>>>(g1_w, g1_as, g1_ad, wsv, wdv, 78, 8, 2048);
  alk<<<4096,256,0,stream>>>(xpad, wsv, wdv, als, ald, 80);
  gat1_gather<<<4096,256,0,stream>>>(xpad, als, ald, off_g, csr_g, y1);
  dec<<<10240,256,0,stream>>>(y1, y1h, y1l, 640, 640);
  tpd<<<dim3(64,20),256,0,stream>>>(w1r, 2048, 0, 640, 640, w1rth, w1rtl);
  mgemm<3><<<dim3(16,32),256,0,stream>>>(y1h, y1l, 640, w1rth, w1rtl, 640,
                                         x1, 2048, 640, g1_b, 0.125f);

  // ---- GAT2 (transform-first, 4 chunks x 2 heads) ----
  wsvec<<<4096,256,0,stream>>>(g2_w, g2_as, g2_ad, wsv, wdv, 2048, 8, 1024);
  alk<<<4096,256,0,stream>>>(x1, wsv, wdv, als, ald, 2048);
  dec<<<32768,256,0,stream>>>(x1, x1h, x1l, 2048, 2048);
  hipMemsetAsync(acc2, 0, (size_t)4096*1024*4, stream);
  for (int c=0;c<4;c++){
    tpd<<<dim3(64,64),256,0,stream>>>(g2_w, 8192, c*2048, 2048, 2048, w2th, w2tl);
    mgemm<0><<<dim3(16,32),256,0,stream>>>(x1h, x1l, 2048, w2th, w2tl, 2048,
                                           h2, 2048, 2048, nullptr, 0.f);
    gat_aggN<2,1024><<<4096,256,0,stream>>>(h2, als, ald, off_g, csr_g, acc2, c*2);
  }
  finishx<<<16384,256,0,stream>>>(acc2, g2_b, x2, 1023);

  // ---- GAT3 (2 chunks x 4 heads) ----
  wsvec<<<2048,256,0,stream>>>(g3_w, g3_as, g3_ad, wsv, wdv, 1024, 8, 512);
  alk<<<4096,256,0,stream>>>(x2, wsv, wdv, als, ald, 1024);
  dec<<<16384,256,0,stream>>>(x2, x2h, x2l, 1024, 1024);
  hipMemsetAsync(acc3, 0, (size_t)4096*512*4, stream);
  for (int c=0;c<2;c++){
    tpd<<<dim3(64,32),256,0,stream>>>(g3_w, 4096, c*2048, 1024, 1024, w3th, w3tl);
    mgemm<0><<<dim3(16,32),256,0,stream>>>(x2h, x2l, 1024, w3th, w3tl, 1024,
                                           h3, 2048, 1024, nullptr, 0.f);
    gat_aggN<4,512><<<4096,256,0,stream>>>(h3, als, ald, off_g, csr_g, acc3, c*4);
  }
  finishx<<<8192,256,0,stream>>>(acc3, g3_b, x3, 511);
  pool_gcn<<<128,256,0,stream>>>(x3, dis, off_g, csr_g, zbuf);

  // ---- Transformer branch (fused q|k|v|skip GEMM) ----
  tpd<<<dim3(64,3),256,0,stream>>>(t_wq, 2048, 0, 78, 96, qkvTh,                 qkvTl);
  tpd<<<dim3(64,3),256,0,stream>>>(t_wk, 2048, 0, 78, 96, qkvTh + (size_t)2048*96, qkvTl + (size_t)2048*96);
  tpd<<<dim3(64,3),256,0,stream>>>(t_wv, 2048, 0, 78, 96, qkvTh + (size_t)4096*96, qkvTl + (size_t)4096*96);
  tpd<<<dim3(16,3),256,0,stream>>>(t_ws, 512,  0, 78, 96, qkvTh + (size_t)6144*96, qkvTl + (size_t)6144*96);
  catb<<<26,256,0,stream>>>(t_bq, t_bk, t_bv, t_bs, cbias);
  mgemm<1><<<dim3(52,32),256,0,stream>>>(xph, xpl, 96, qkvTh, qkvTl, 96,
                                         qkvs, 6656, 96, cbias, 0.f);
  tr_agg<<<4096,256,0,stream>>>(qkvs, off_t, csr_t, xt);

  // ---- fused head ----
  head_k<<<128,256,0,stream>>>(zbuf, xt, fp, gcn_w, gcn_b,
                               fc1_w, fc1_b, fc2_w, fc2_b,
                               b1_w, b1_b, b2_w, b2_b, b3_w, b3_b, b4_w, b4_b,
                               (float*)d_out);
}

// Round 4
// 1288.996 us; speedup vs baseline: 4.3191x; 1.3165x over previous
//
#include <hip/hip_runtime.h>

typedef unsigned short u16;
typedef unsigned int   u32;

typedef __bf16 bf16x8 __attribute__((ext_vector_type(8)));
typedef float  f32x4  __attribute__((ext_vector_type(4)));

#define NNODE 4096
#define NEDGE 8192
#define NEG   12288   /* edges incl self-loops */

__device__ __forceinline__ void split_bf(float a, u16& hi, u16& lo){
  u32 u = __float_as_uint(a);
  u32 r = u + 0x7fffu + ((u>>16)&1u);
  hi = (u16)(r>>16);
  float h = __uint_as_float(r & 0xffff0000u);
  float l = a - h;                      // exact (Sterbenz)
  u32 u2 = __float_as_uint(l);
  lo = (u16)((u2 + 0x7fffu + ((u2>>16)&1u)) >> 16);
}
__device__ __forceinline__ u16 hi_bf(float a){
  u32 u = __float_as_uint(a);
  return (u16)((u + 0x7fffu + ((u>>16)&1u)) >> 16);
}

// ---------------- graph prep ----------------
__global__ __launch_bounds__(256) void zero_i(int* p, int n){
  int i = blockIdx.x*256 + threadIdx.x; if (i<n) p[i]=0;
}
__global__ __launch_bounds__(256) void hist_k(const int* __restrict__ ei, int* deg_g, int* deg_t){
  int e = blockIdx.x*256 + threadIdx.x; if (e>=NEG) return;
  int dv = (e<NEDGE) ? ei[NEDGE+e] : e-NEDGE;
  atomicAdd(&deg_g[dv],1);
  if (e<NEDGE) atomicAdd(&deg_t[dv],1);
}
__global__ __launch_bounds__(1024) void scan4096(const int* __restrict__ deg, int* __restrict__ off){
  __shared__ int lds[1024];
  int tid = threadIdx.x;
  int v[4]; int s=0;
  #pragma unroll
  for (int j=0;j<4;j++){ v[j]=deg[tid*4+j]; s+=v[j]; }
  lds[tid]=s; __syncthreads();
  for (int d=1; d<1024; d<<=1){
    int t = (tid>=d) ? lds[tid-d] : 0;
    __syncthreads();
    lds[tid] += t;
    __syncthreads();
  }
  int base = (tid>0) ? lds[tid-1] : 0;
  #pragma unroll
  for (int j=0;j<4;j++){ off[tid*4+j]=base; base+=v[j]; }
  if (tid==1023) off[4096]=base;
}
__global__ __launch_bounds__(256) void scatter_k(const int* __restrict__ ei,
    const int* __restrict__ off_g, int* cur_g, int* csr_g,
    const int* __restrict__ off_t, int* cur_t, int* csr_t){
  int e = blockIdx.x*256 + threadIdx.x; if (e>=NEG) return;
  int s, dv;
  if (e<NEDGE){ s=ei[e]; dv=ei[NEDGE+e]; } else { s=dv=e-NEDGE; }
  int p = atomicAdd(&cur_g[dv],1);
  csr_g[off_g[dv]+p]=s;
  if (e<NEDGE){ int p2 = atomicAdd(&cur_t[dv],1); csr_t[off_t[dv]+p2]=s; }
}
__global__ __launch_bounds__(256) void mkdis(const int* __restrict__ deg, float* dis){
  int i = blockIdx.x*256 + threadIdx.x; if (i>=NNODE) return;
  int d = deg[i]; dis[i] = d>0 ? rsqrtf((float)d) : 0.f;
}
__global__ __launch_bounds__(128) void pad_x(const float* __restrict__ x, float* __restrict__ xp){
  int n = blockIdx.x, c = threadIdx.x;
  if (c<80) xp[(size_t)n*80+c] = (c<78) ? x[(size_t)n*78+c] : 0.f;
}
// W1r[(h*80+k), c] = g1_w[k, h*2048+c], zero-padded k>=78
__global__ __launch_bounds__(256) void repack_w1(const float* __restrict__ g1w, float* __restrict__ w1r){
  int i = blockIdx.x*256 + threadIdx.x;   // 640*2048
  int kk = i >> 11, c = i & 2047;
  int h = kk/80, k2 = kk - h*80;
  w1r[i] = (k2<78) ? g1w[(size_t)k2*16384 + h*2048 + c] : 0.f;
}

// ---------------- fp32 -> bf16 hi/lo decompose (row-major [M,K] -> [M,Kp]) ----------------
__global__ __launch_bounds__(256) void dec(const float* __restrict__ A,
    u16* __restrict__ hi, u16* __restrict__ lo, int K, int Kp){
  int i = blockIdx.x*256 + threadIdx.x;     // grid = M*Kp/256
  int r = i / Kp, k = i - r*Kp;
  float a = (k<K) ? A[(size_t)r*K + k] : 0.f;
  u16 h, l; split_bf(a, h, l);
  hi[i]=h; lo[i]=l;
}

// ---------------- transpose + bf16(hi): W[K,Ntot] cols [n0,n0+Nw) -> hi [Nw,Kp] ----------------
__global__ __launch_bounds__(256) void tpd(const float* __restrict__ in, int Ntot, int n0,
    int K, int Kp, u16* __restrict__ outh){
  __shared__ float t[32][33];
  int bx = blockIdx.x*32;   // n in window
  int by = blockIdx.y*32;   // k
  int tx = threadIdx.x & 31, ty = threadIdx.x >> 5;
  for (int i=ty;i<32;i+=8){
    int kk=by+i;
    t[i][tx] = (kk<K) ? in[(size_t)kk*Ntot + n0 + bx + tx] : 0.f;
  }
  __syncthreads();
  for (int i=ty;i<32;i+=8){
    int nn=bx+i, kk=by+tx;
    outh[(size_t)nn*Kp+kk] = hi_bf(t[tx][i]);
  }
}

// ---------------- split-A bf16 MFMA GEMM: C[M,N](fp32) = (Ah+Al)[M,K] * Bh[N,K]^T ----------------
// EPI: 0 none, 1 +bias, 3 relu(scale*acc+bias)
#define BM 128
#define BN 128
#define BKP 40
template<int EPI>
__global__ __launch_bounds__(256,2) void mgemm(
    const u16* __restrict__ Ah, const u16* __restrict__ Al, int lda,
    const u16* __restrict__ Bh, int ldb,
    float* __restrict__ C, int ldc, int K,
    const float* __restrict__ bias, float scale)
{
  __shared__ u16 Ash[BM*BKP], Asl[BM*BKP], Bsh[BN*BKP];
  int tid = threadIdx.x;
  int bm = blockIdx.y*BM, bn = blockIdx.x*BN;
  int lane = tid & 63, wave = tid >> 6;
  int wr = (wave>>1)*64, wc = (wave&1)*64;
  int m16 = lane & 15, quad = lane >> 4;
  int lr = tid >> 1, lh = (tid & 1) * 16;

  f32x4 acc[4][4] = {};
  for (int k0=0; k0<K; k0+=32){
    const uint4* gah = (const uint4*)(Ah + (size_t)(bm+lr)*lda + k0 + lh);
    uint4 a0 = gah[0], a1 = gah[1];
    const uint4* gal = (const uint4*)(Al + (size_t)(bm+lr)*lda + k0 + lh);
    uint4 a2 = gal[0], a3 = gal[1];
    const uint4* gbh = (const uint4*)(Bh + (size_t)(bn+lr)*ldb + k0 + lh);
    uint4 b0 = gbh[0], b1 = gbh[1];
    __syncthreads();
    *(uint4*)&Ash[lr*BKP+lh]   = a0; *(uint4*)&Ash[lr*BKP+lh+8] = a1;
    *(uint4*)&Asl[lr*BKP+lh]   = a2; *(uint4*)&Asl[lr*BKP+lh+8] = a3;
    *(uint4*)&Bsh[lr*BKP+lh]   = b0; *(uint4*)&Bsh[lr*BKP+lh+8] = b1;
    __syncthreads();
    int kq = quad*8;
    bf16x8 ah[4], al_[4], bh_[4];
    #pragma unroll
    for (int i=0;i<4;i++){
      ah[i]  = *(const bf16x8*)&Ash[(wr+i*16+m16)*BKP + kq];
      al_[i] = *(const bf16x8*)&Asl[(wr+i*16+m16)*BKP + kq];
    }
    #pragma unroll
    for (int j=0;j<4;j++)
      bh_[j] = *(const bf16x8*)&Bsh[(wc+j*16+m16)*BKP + kq];
    #pragma unroll
    for (int i=0;i<4;i++)
      #pragma unroll
      for (int j=0;j<4;j++){
        acc[i][j] = __builtin_amdgcn_mfma_f32_16x16x32_bf16(ah[i],  bh_[j], acc[i][j], 0,0,0);
        acc[i][j] = __builtin_amdgcn_mfma_f32_16x16x32_bf16(al_[i], bh_[j], acc[i][j], 0,0,0);
      }
  }
  #pragma unroll
  for (int i=0;i<4;i++){
    int row0 = bm + wr + i*16 + quad*4;
    #pragma unroll
    for (int j=0;j<4;j++){
      int col = bn + wc + j*16 + m16;
      float bv = (EPI>=1) ? bias[col] : 0.f;
      #pragma unroll
      for (int r=0;r<4;r++){
        float v = acc[i][j][r];
        if (EPI==3) v = fmaxf(v*scale + bv, 0.f);
        else if (EPI==1) v = v + bv;
        C[(size_t)(row0+r)*ldc + col] = v;
      }
    }
  }
}

// ---------------- GAT attention-vector precompute ----------------
__global__ __launch_bounds__(256) void wsvec(const float* __restrict__ W,
    const float* __restrict__ as_, const float* __restrict__ ad_,
    float* __restrict__ ws, float* __restrict__ wd,
    int Kreal, int H, int C)
{
  int wv = blockIdx.x*4 + (threadIdx.x>>6);
  int lane = threadIdx.x & 63;
  int k = wv / H, h = wv - k*H;
  float ps=0.f, pd=0.f;
  if (k < Kreal){
    const float* wr = W + (size_t)k*((size_t)H*C) + (size_t)h*C;
    const float* ar = as_ + (size_t)h*C;
    const float* dr = ad_ + (size_t)h*C;
    for (int c=lane;c<C;c+=64){ float w=wr[c]; ps += w*ar[c]; pd += w*dr[c]; }
  }
  #pragma unroll
  for (int o=32;o;o>>=1){ ps += __shfl_down(ps,o); pd += __shfl_down(pd,o); }
  if (lane==0){ ws[k*H+h]=ps; wd[k*H+h]=pd; }
}
// small-K fallback (GAT1, Kp=80)
__global__ __launch_bounds__(256) void alk(const float* __restrict__ X,
    const float* __restrict__ ws, const float* __restrict__ wd,
    float* __restrict__ als, float* __restrict__ ald, int Kp)
{
  int n = blockIdx.x, tid = threadIdx.x;
  int hh = tid>>5, l32 = tid&31;
  const float* xr = X + (size_t)n*Kp;
  float ps=0.f, pd=0.f;
  for (int k=l32;k<Kp;k+=32){
    float xv = xr[k];
    ps += xv*ws[k*8+hh];
    pd += xv*wd[k*8+hh];
  }
  #pragma unroll
  for (int o=16;o;o>>=1){ ps += __shfl_down(ps,o,32); pd += __shfl_down(pd,o,32); }
  if (l32==0){ als[n*8+hh]=ps; ald[n*8+hh]=pd; }
}
// k-sliced attention logits: thread t owns k in [t*VK, t*VK+VK); X read once, coalesced
template<int VK>
__global__ __launch_bounds__(256) void alk2(const float* __restrict__ X,
    const float* __restrict__ ws, const float* __restrict__ wd,
    float* __restrict__ als, float* __restrict__ ald)
{
  int n = blockIdx.x, tid = threadIdx.x;
  int wv = tid>>6, lane = tid&63;
  const float* xr = X + (size_t)n*(VK*256) + tid*VK;
  float xv[VK];
  #pragma unroll
  for (int v=0; v<VK; v+=4){
    float4 xq = *(const float4*)(xr+v);
    xv[v]=xq.x; xv[v+1]=xq.y; xv[v+2]=xq.z; xv[v+3]=xq.w;
  }
  float ps[8], pd[8];
  #pragma unroll
  for (int h=0;h<8;h++){ ps[h]=0.f; pd[h]=0.f; }
  #pragma unroll
  for (int v=0; v<VK; v++){
    int kk = tid*VK+v;
    const float4* wr4 = (const float4*)(ws + (size_t)kk*8);
    float4 w0 = wr4[0], w1 = wr4[1];
    const float4* dr4 = (const float4*)(wd + (size_t)kk*8);
    float4 d0 = dr4[0], d1 = dr4[1];
    float xvv = xv[v];
    ps[0]+=xvv*w0.x; ps[1]+=xvv*w0.y; ps[2]+=xvv*w0.z; ps[3]+=xvv*w0.w;
    ps[4]+=xvv*w1.x; ps[5]+=xvv*w1.y; ps[6]+=xvv*w1.z; ps[7]+=xvv*w1.w;
    pd[0]+=xvv*d0.x; pd[1]+=xvv*d0.y; pd[2]+=xvv*d0.z; pd[3]+=xvv*d0.w;
    pd[4]+=xvv*d1.x; pd[5]+=xvv*d1.y; pd[6]+=xvv*d1.z; pd[7]+=xvv*d1.w;
  }
  #pragma unroll
  for (int h=0;h<8;h++){
    #pragma unroll
    for (int o=32;o;o>>=1){ ps[h]+=__shfl_down(ps[h],o); pd[h]+=__shfl_down(pd[h],o); }
  }
  __shared__ float red[4][16];
  if (lane==0){
    #pragma unroll
    for (int h=0;h<8;h++){ red[wv][h]=ps[h]; red[wv][8+h]=pd[h]; }
  }
  __syncthreads();
  if (tid<16){
    float s = red[0][tid]+red[1][tid]+red[2][tid]+red[3][tid];
    if (tid<8) als[n*8+tid]=s; else ald[n*8+(tid-8)]=s;
  }
}

// ---------------- GAT1 aggregate-first gather ----------------
__global__ __launch_bounds__(256) void gat1_gather(
    const float* __restrict__ xpad, const float* __restrict__ als, const float* __restrict__ ald,
    const int* __restrict__ off, const int* __restrict__ csr, float* __restrict__ y1)
{
  int d = blockIdx.x, tid = threadIdx.x;
  int hh = tid>>5, l32 = tid&31;
  int e0 = off[d], e1 = off[d+1];
  __shared__ float mh[8], lih[8], adh[8];
  __shared__ float wl[32][8];
  __shared__ int sl[32];
  if (tid < 8){
    float ad = ald[d*8+tid]; adh[tid]=ad;
    float m=-1e30f, l=0.f;
    for (int e=e0;e<e1;++e){
      float xv = als[csr[e]*8+tid] + ad;
      xv = xv>0.f?xv:0.2f*xv;
      if (xv>m){ l = l*__expf(m-xv)+1.f; m=xv; } else l += __expf(xv-m);
    }
    mh[tid]=m; lih[tid]=1.f/l;
  }
  __syncthreads();
  float acc0=0.f, acc1=0.f, acc2v=0.f;
  for (int cb=e0; cb<e1; cb+=32){
    int ce = min(32, e1-cb);
    if (tid < ce*8){
      int j = tid>>3, h2 = tid&7;
      int s = csr[cb+j];
      if (h2==0) sl[j]=s;
      float xv = als[s*8+h2] + adh[h2];
      xv = xv>0.f?xv:0.2f*xv;
      wl[j][h2] = __expf(xv-mh[h2])*lih[h2];
    }
    __syncthreads();
    for (int j=0;j<ce;++j){
      float w = wl[j][hh];
      const float* xr = xpad + (size_t)sl[j]*80;
      acc0 += w*xr[l32];
      acc1 += w*xr[l32+32];
      if (l32 < 16) acc2v += w*xr[l32+64];
    }
    __syncthreads();
  }
  float* yr = y1 + (size_t)d*640 + hh*80;
  yr[l32] = acc0; yr[l32+32] = acc1;
  if (l32<16) yr[l32+64] = acc2v;
}

// ---------------- all-head chunk aggregation ----------------
template<int HPC, int C>
__global__ __launch_bounds__(256) void gat_aggN(
    const float* __restrict__ h, const float* __restrict__ als, const float* __restrict__ ald,
    const int* __restrict__ off, const int* __restrict__ csr,
    float* __restrict__ accum, int head0)
{
  constexpr int V = C/256;
  int d = blockIdx.x, tid = threadIdx.x;
  int e0=off[d], e1=off[d+1];
  __shared__ float mh[HPC], lih[HPC], adh[HPC];
  __shared__ float wl[32][HPC];
  __shared__ int sl[32];
  if (tid < HPC){
    float ad = ald[d*8 + head0 + tid]; adh[tid]=ad;
    float m=-1e30f,l=0.f;
    for (int e=e0;e<e1;++e){
      float xv = als[csr[e]*8 + head0 + tid]+ad;
      xv = xv>0.f?xv:0.2f*xv;
      if (xv>m){ l=l*__expf(m-xv)+1.f; m=xv; } else l+=__expf(xv-m);
    }
    mh[tid]=m; lih[tid]=1.f/l;
  }
  __syncthreads();
  float acc[HPC][V];
  #pragma unroll
  for (int a=0;a<HPC;a++)
    #pragma unroll
    for (int v=0;v<V;v++) acc[a][v]=0.f;
  int c0 = tid*V;
  for (int cb=e0;cb<e1;cb+=32){
    int ce = min(32, e1-cb);
    if (tid < ce*HPC){
      int j = tid/HPC, h2 = tid - j*HPC;
      int s = csr[cb+j];
      if (h2==0) sl[j]=s;
      float xv = als[s*8 + head0 + h2] + adh[h2];
      xv = xv>0.f?xv:0.2f*xv;
      wl[j][h2] = __expf(xv-mh[h2])*lih[h2];
    }
    __syncthreads();
    for (int j=0;j<ce;++j){
      const float* hr = h + (size_t)sl[j]*(HPC*C);
      #pragma unroll
      for (int a=0;a<HPC;a++){
        float w = wl[j][a];
        #pragma unroll
        for (int v=0;v<V;v++) acc[a][v] += w*hr[a*C + c0 + v];
      }
    }
    __syncthreads();
  }
  float* ar = accum + (size_t)d*C + c0;
  #pragma unroll
  for (int v=0;v<V;v++){
    float s2 = 0.f;
    #pragma unroll
    for (int a=0;a<HPC;a++) s2 += acc[a][v];
    ar[v] += s2;
  }
}
// x = relu(acc/8 + b[c])
__global__ __launch_bounds__(256) void finishx(const float* __restrict__ accum,
    const float* __restrict__ bias, float* __restrict__ xo, int Cmask){
  int i = blockIdx.x*256 + threadIdx.x;
  int c = i & Cmask;
  xo[i] = fmaxf(accum[i]*0.125f + bias[c], 0.f);
}

// ---------------- pooled GCN aggregation ----------------
__global__ __launch_bounds__(256) void pool_gcn(const float* __restrict__ x3,
    const float* __restrict__ dis, const int* __restrict__ off, const int* __restrict__ csr,
    float* __restrict__ z)
{
  int g = blockIdx.x, tid = threadIdx.x;
  int c0 = tid*2;
  float a0=0.f, a1=0.f;
  for (int dd=0; dd<32; ++dd){
    int d = g*32+dd;
    int e0=off[d], e1=off[d+1];
    float b0=0.f, b1=0.f;
    for (int e=e0;e<e1;++e){
      int s = csr[e]; float ds = dis[s];
      const float* xr = x3 + (size_t)s*512 + c0;
      b0 += ds*xr[0]; b1 += ds*xr[1];
    }
    float dw = dis[d];
    a0 += dw*b0; a1 += dw*b1;
  }
  z[(size_t)g*512+c0]   = a0*(1.f/32.f);
  z[(size_t)g*512+c0+1] = a1*(1.f/32.f);
}

// ---------------- TransformerConv aggregation (qkvs: [4096, 6656] = q|k|v|xs) ----------------
__global__ __launch_bounds__(256) void tr_agg(
  const float* __restrict__ qkvs, const int* __restrict__ off, const int* __restrict__ csr,
  float* __restrict__ xt)
{
  int d = blockIdx.x, tid = threadIdx.x;
  int wv = tid>>6, lane = tid&63;
  int e0=off[d], e1=off[d+1];
  __shared__ float osum[4][512];
  float qf[8];
  const float* qr = qkvs + (size_t)d*6656 + wv*512 + lane*8;
  #pragma unroll
  for (int j=0;j<8;j++) qf[j]=qr[j];
  const float scale = 0.04419417382415922f; // 1/sqrt(512)
  float m=-1e30f,l=0.f;
  for (int e=e0;e<e1;++e){
    const float* kr = qkvs + (size_t)csr[e]*6656 + 2048 + wv*512 + lane*8;
    float p=0.f;
    #pragma unroll
    for (int j=0;j<8;j++) p += qf[j]*kr[j];
    #pragma unroll
    for (int o=32;o;o>>=1) p += __shfl_xor(p,o);
    p *= scale;
    if (p>m){ l=l*__expf(m-p)+1.f; m=p; } else l+=__expf(p-m);
  }
  float li = (e1>e0)?1.f/l:0.f;
  float acc[8]={0.f,0.f,0.f,0.f,0.f,0.f,0.f,0.f};
  for (int e=e0;e<e1;++e){
    int s = csr[e];
    const float* kr = qkvs + (size_t)s*6656 + 2048 + wv*512 + lane*8;
    float p=0.f;
    #pragma unroll
    for (int j=0;j<8;j++) p += qf[j]*kr[j];
    #pragma unroll
    for (int o=32;o;o>>=1) p += __shfl_xor(p,o);
    float w = __expf(p*scale - m)*li;
    const float* vr = qkvs + (size_t)s*6656 + 4096 + wv*512 + lane*8;
    #pragma unroll
    for (int j=0;j<8;j++) acc[j] += w*vr[j];
  }
  #pragma unroll
  for (int j=0;j<8;j++) osum[wv][lane*8+j]=acc[j];
  __syncthreads();
  for (int c=tid;c<512;c+=256){
    float o = (osum[0][c]+osum[1][c]+osum[2][c]+osum[3][c])*0.25f
            + qkvs[(size_t)d*6656 + 6144 + c];
    xt[(size_t)d*512+c] = fmaxf(o,0.f);
  }
}

// ---------------- bias concat for qkv GEMM ----------------
__global__ __launch_bounds__(256) void catb(const float* __restrict__ bq, const float* __restrict__ bk,
    const float* __restrict__ bv, const float* __restrict__ bs, float* __restrict__ o){
  int i = blockIdx.x*256 + threadIdx.x; if (i>=6656) return;
  float v;
  if (i<2048) v=bq[i]; else if (i<4096) v=bk[i-2048];
  else if (i<6144) v=bv[i-4096]; else v=bs[i-6144];
  o[i]=v;
}

// ---------------- fused head ----------------
__global__ __launch_bounds__(256) void head_k(
  const float* __restrict__ z, const float* __restrict__ xt, const float* __restrict__ fp,
  const float* __restrict__ gcn_w, const float* __restrict__ gcn_b,
  const float* __restrict__ fc1_w, const float* __restrict__ fc1_b,
  const float* __restrict__ fc2_w, const float* __restrict__ fc2_b,
  const float* __restrict__ b1_w, const float* __restrict__ b1_b,
  const float* __restrict__ b2_w, const float* __restrict__ b2_b,
  const float* __restrict__ b3_w, const float* __restrict__ b3_b,
  const float* __restrict__ b4_w, const float* __restrict__ b4_b,
  float* __restrict__ out)
{
  int g = blockIdx.x, tid = threadIdx.x;
  __shared__ float xc[1024];
  __shared__ float sa[1504];
  __shared__ float sb[256];
  __shared__ float scm[256];
  for (int c=tid;c<512;c+=256) sa[c] = z[(size_t)g*512+c];
  __syncthreads();
  {
    float acc = gcn_b[tid];
    #pragma unroll 8
    for (int k=0;k<512;k++) acc += sa[k]*gcn_w[k*256+tid];
    xc[tid] = acc;
  }
  for (int c=tid;c<512;c+=256){
    float s=0.f;
    for (int i=0;i<32;i++) s += xt[(size_t)(g*32+i)*512 + c];
    xc[256+c] = s*(1.f/32.f);
  }
  __syncthreads();
  for (int c=tid;c<1489;c+=256) sa[c] = fp[(size_t)g*1489+c];
  __syncthreads();
  { // fc1 (K=1489 -> 128), 2-way k-split
    int n = tid & 127, half = tid >> 7;
    int k0 = half ? 745 : 0, k1 = half ? 1489 : 745;
    float acc = 0.f;
    #pragma unroll 8
    for (int k=k0;k<k1;k++) acc += sa[k]*fc1_w[(size_t)k*128+n];
    sb[tid]=acc;
  }
  __syncthreads();
  if (tid<128) scm[tid] = fmaxf(sb[tid]+sb[tid+128]+fc1_b[tid], 0.f);
  __syncthreads();
  { // fc2 (128 -> 256)
    float acc = fc2_b[tid];
    #pragma unroll 8
    for (int k=0;k<128;k++) acc += scm[k]*fc2_w[k*256+tid];
    xc[768+tid] = fmaxf(acc, 0.f);
  }
  __syncthreads();
  { // b1 (1024 -> 256)
    float acc = b1_b[tid];
    #pragma unroll 8
    for (int k=0;k<1024;k++) acc += xc[k]*b1_w[k*256+tid];
    sa[tid] = fmaxf(acc, 0.f);
  }
  __syncthreads();
  { // b2 (256 -> 128), 2-way k-split
    int n = tid & 127, half = tid >> 7;
    int k0 = half*128;
    float acc = 0.f;
    #pragma unroll 8
    for (int k=k0;k<k0+128;k++) acc += sa[k]*b2_w[k*128+n];
    sb[tid]=acc;
  }
  __syncthreads();
  if (tid<128) scm[tid] = fmaxf(sb[tid]+sb[tid+128]+b2_b[tid], 0.f);
  __syncthreads();
  { // b3 (128 -> 64), 4-way k-split
    int n = tid & 63, part = tid >> 6;
    int k0 = part*32;
    float acc = 0.f;
    #pragma unroll 8
    for (int k=k0;k<k0+32;k++) acc += scm[k]*b3_w[k*64+n];
    sb[tid]=acc;
  }
  __syncthreads();
  if (tid<64) sa[tid] = fmaxf(sb[tid]+sb[tid+64]+sb[tid+128]+sb[tid+192]+b3_b[tid], 0.f);
  __syncthreads();
  if (tid<64){
    float p = sa[tid]*b4_w[tid];
    #pragma unroll
    for (int o=32;o;o>>=1) p += __shfl_down(p,o);
    if (tid==0) out[g] = 1.f/(1.f+__expf(-(p + b4_b[0])));
  }
}

extern "C" void kernel_launch(void* const* d_in, const int* in_sizes, int n_in,
                              void* d_out, int out_size, void* d_ws, size_t ws_size,
                              hipStream_t stream)
{
  (void)in_sizes; (void)n_in; (void)out_size; (void)ws_size;
  const float* x     = (const float*)d_in[0];
  const float* fp    = (const float*)d_in[1];
  const int*   ei    = (const int*)d_in[2];
  const float* g1_w  = (const float*)d_in[4];
  const float* g1_as = (const float*)d_in[5];
  const float* g1_ad = (const float*)d_in[6];
  const float* g1_b  = (const float*)d_in[7];
  const float* g2_w  = (const float*)d_in[8];
  const float* g2_as = (const float*)d_in[9];
  const float* g2_ad = (const float*)d_in[10];
  const float* g2_b  = (const float*)d_in[11];
  const float* g3_w  = (const float*)d_in[12];
  const float* g3_as = (const float*)d_in[13];
  const float* g3_ad = (const float*)d_in[14];
  const float* g3_b  = (const float*)d_in[15];
  const float* gcn_w = (const float*)d_in[16];
  const float* gcn_b = (const float*)d_in[17];
  const float* t_wq  = (const float*)d_in[18];
  const float* t_wk  = (const float*)d_in[19];
  const float* t_wv  = (const float*)d_in[20];
  const float* t_bq  = (const float*)d_in[21];
  const float* t_bk  = (const float*)d_in[22];
  const float* t_bv  = (const float*)d_in[23];
  const float* t_ws  = (const float*)d_in[24];
  const float* t_bs  = (const float*)d_in[25];
  const float* fc1_w = (const float*)d_in[26];
  const float* fc1_b = (const float*)d_in[27];
  const float* fc2_w = (const float*)d_in[28];
  const float* fc2_b = (const float*)d_in[29];
  const float* b1_w  = (const float*)d_in[30];
  const float* b1_b  = (const float*)d_in[31];
  const float* b2_w  = (const float*)d_in[32];
  const float* b2_b  = (const float*)d_in[33];
  const float* b3_w  = (const float*)d_in[34];
  const float* b3_b  = (const float*)d_in[35];
  const float* b4_w  = (const float*)d_in[36];
  const float* b4_b  = (const float*)d_in[37];

  char* base = (char*)d_ws;
  size_t offb = 0;
  auto alloc = [&](size_t bytes)->void*{
    void* p = base + offb; offb = (offb + bytes + 255) & ~(size_t)255; return p;
  };
  int*   cnt   = (int*)alloc(16384*4);
  int*   off_g = (int*)alloc(4097*4);
  int*   off_t = (int*)alloc(4097*4);
  int*   csr_g = (int*)alloc(12288*4);
  int*   csr_t = (int*)alloc(8192*4);
  float* dis   = (float*)alloc(4096*4);
  float* xpad  = (float*)alloc((size_t)4096*80*4);
  u16*   xph   = (u16*)alloc((size_t)4096*96*2);
  u16*   xpl   = (u16*)alloc((size_t)4096*96*2);
  float* als   = (float*)alloc((size_t)4096*8*4);
  float* ald   = (float*)alloc((size_t)4096*8*4);
  float* wsv   = (float*)alloc((size_t)2048*8*4);
  float* wdv   = (float*)alloc((size_t)2048*8*4);
  float* zbuf  = (float*)alloc((size_t)128*512*4);
  float* cbias = (float*)alloc((size_t)6656*4);
  float* w1r   = (float*)alloc((size_t)640*2048*4);
  char*  big   = (char*)alloc((size_t)144<<20);

  // GAT-phase overlays
  float* x1    = (float*)(big);                         // [0,32) MB
  float* y1    = (float*)(big + ((size_t)32<<20));      // [32,42)
  u16*   y1h   = (u16*)  (big + ((size_t)42<<20));      // [42,47)
  u16*   y1l   = (u16*)  (big + ((size_t)47<<20));      // [47,52)
  u16*   w1rth = (u16*)  (big + ((size_t)52<<20));      // [52,55)
  u16*   x1h   = (u16*)  (big + ((size_t)32<<20));      // [32,48)  (y1 dead)
  u16*   x1l   = (u16*)  (big + ((size_t)48<<20));      // [48,64)
  float* h2    = (float*)(big + ((size_t)64<<20));      // [64,96)
  u16*   w2th  = (u16*)  (big + ((size_t)96<<20));      // [96,104)
  float* acc2  = (float*)(big + ((size_t)112<<20));     // [112,128)
  float* x2    = (float*)(big + ((size_t)128<<20));     // [128,144)
  u16*   x2h   = (u16*)  (big);                         // [0,8)   (x1 dead)
  u16*   x2l   = (u16*)  (big + ((size_t)8<<20));       // [8,16)
  float* h3    = (float*)(big + ((size_t)16<<20));      // [16,48)
  u16*   w3th  = (u16*)  (big + ((size_t)48<<20));      // [48,52)
  float* acc3  = (float*)(big + ((size_t)56<<20));      // [56,64)
  float* x3    = (float*)(big + ((size_t)64<<20));      // [64,72)
  // transformer-phase overlays
  u16*   qkvTh = (u16*)  (big);                         // [0,2)
  float* qkvs  = (float*)(big + ((size_t)8<<20));       // [8,117)
  float* xt    = (float*)(big + ((size_t)120<<20));     // [120,128)

  int* deg_g = cnt;       int* cur_g = cnt+4096;
  int* deg_t = cnt+8192;  int* cur_t = cnt+12288;

  // ---- graph prep ----
  zero_i<<<64,256,0,stream>>>(cnt, 16384);
  hist_k<<<48,256,0,stream>>>(ei, deg_g, deg_t);
  scan4096<<<1,1024,0,stream>>>(deg_g, off_g);
  scan4096<<<1,1024,0,stream>>>(deg_t, off_t);
  scatter_k<<<48,256,0,stream>>>(ei, off_g, cur_g, csr_g, off_t, cur_t, csr_t);
  mkdis<<<16,256,0,stream>>>(deg_g, dis);
  pad_x<<<4096,128,0,stream>>>(x, xpad);
  repack_w1<<<5120,256,0,stream>>>(g1_w, w1r);
  dec<<<1536,256,0,stream>>>(xpad, xph, xpl, 80, 96);

  // ---- GAT1 (aggregate-first) ----
  wsvec<<<160,256,0,stream>>>(g1_w, g1_as, g1_ad, wsv, wdv, 78, 8, 2048);
  alk<<<4096,256,0,stream>>>(xpad, wsv, wdv, als, ald, 80);
  gat1_gather<<<4096,256,0,stream>>>(xpad, als, ald, off_g, csr_g, y1);
  dec<<<10240,256,0,stream>>>(y1, y1h, y1l, 640, 640);
  tpd<<<dim3(64,20),256,0,stream>>>(w1r, 2048, 0, 640, 640, w1rth);
  mgemm<3><<<dim3(16,32),256,0,stream>>>(y1h, y1l, 640, w1rth, 640,
                                         x1, 2048, 640, g1_b, 0.125f);

  // ---- GAT2 (transform-first, 4 chunks x 2 heads) ----
  wsvec<<<4096,256,0,stream>>>(g2_w, g2_as, g2_ad, wsv, wdv, 2048, 8, 1024);
  alk2<8><<<4096,256,0,stream>>>(x1, wsv, wdv, als, ald);
  dec<<<32768,256,0,stream>>>(x1, x1h, x1l, 2048, 2048);
  hipMemsetAsync(acc2, 0, (size_t)4096*1024*4, stream);
  for (int c=0;c<4;c++){
    tpd<<<dim3(64,64),256,0,stream>>>(g2_w, 8192, c*2048, 2048, 2048, w2th);
    mgemm<0><<<dim3(16,32),256,0,stream>>>(x1h, x1l, 2048, w2th, 2048,
                                           h2, 2048, 2048, nullptr, 0.f);
    gat_aggN<2,1024><<<4096,256,0,stream>>>(h2, als, ald, off_g, csr_g, acc2, c*2);
  }
  finishx<<<16384,256,0,stream>>>(acc2, g2_b, x2, 1023);

  // ---- GAT3 (2 chunks x 4 heads) ----
  wsvec<<<2048,256,0,stream>>>(g3_w, g3_as, g3_ad, wsv, wdv, 1024, 8, 512);
  alk2<4><<<4096,256,0,stream>>>(x2, wsv, wdv, als, ald);
  dec<<<16384,256,0,stream>>>(x2, x2h, x2l, 1024, 1024);
  hipMemsetAsync(acc3, 0, (size_t)4096*512*4, stream);
  for (int c=0;c<2;c++){
    tpd<<<dim3(64,32),256,0,stream>>>(g3_w, 4096, c*2048, 1024, 1024, w3th);
    mgemm<0><<<dim3(16,32),256,0,stream>>>(x2h, x2l, 1024, w3th, 1024,
                                           h3, 2048, 1024, nullptr, 0.f);
    gat_aggN<4,512><<<4096,256,0,stream>>>(h3, als, ald, off_g, csr_g, acc3, c*4);
  }
  finishx<<<8192,256,0,stream>>>(acc3, g3_b, x3, 511);
  pool_gcn<<<128,256,0,stream>>>(x3, dis, off_g, csr_g, zbuf);

  // ---- Transformer branch (fused q|k|v|skip GEMM) ----
  tpd<<<dim3(64,3),256,0,stream>>>(t_wq, 2048, 0, 78, 96, qkvTh);
  tpd<<<dim3(64,3),256,0,stream>>>(t_wk, 2048, 0, 78, 96, qkvTh + (size_t)2048*96);
  tpd<<<dim3(64,3),256,0,stream>>>(t_wv, 2048, 0, 78, 96, qkvTh + (size_t)4096*96);
  tpd<<<dim3(16,3),256,0,stream>>>(t_ws, 512,  0, 78, 96, qkvTh + (size_t)6144*96);
  catb<<<26,256,0,stream>>>(t_bq, t_bk, t_bv, t_bs, cbias);
  mgemm<1><<<dim3(52,32),256,0,stream>>>(xph, xpl, 96, qkvTh, 96,
                                         qkvs, 6656, 96, cbias, 0.f);
  tr_agg<<<4096,256,0,stream>>>(qkvs, off_t, csr_t, xt);

  // ---- fused head ----
  head_k<<<128,256,0,stream>>>(zbuf, xt, fp, gcn_w, gcn_b,
                               fc1_w, fc1_b, fc2_w, fc2_b,
                               b1_w, b1_b, b2_w, b2_b, b3_w, b3_b, b4_w, b4_b,
                               (float*)d_out);
}

// Round 5
// 1104.379 us; speedup vs baseline: 5.0411x; 1.1672x over previous
//
#include <hip/hip_runtime.h>

typedef unsigned short u16;
typedef unsigned int   u32;

typedef __bf16 bf16x8 __attribute__((ext_vector_type(8)));
typedef float  f32x4  __attribute__((ext_vector_type(4)));

#define NNODE 4096
#define NEDGE 8192
#define NEG   12288   /* edges incl self-loops */

__device__ __forceinline__ float blo(u32 u){ return __uint_as_float(u<<16); }
__device__ __forceinline__ float bhi(u32 u){ return __uint_as_float(u & 0xffff0000u); }
__device__ __forceinline__ u16 f2b(float f){
  u32 u = __float_as_uint(f);
  u += 0x7fffu + ((u>>16)&1u);
  return (u16)(u>>16);
}
__device__ __forceinline__ void split_bf(float a, u16& hi, u16& lo){
  u32 u = __float_as_uint(a);
  u32 r = u + 0x7fffu + ((u>>16)&1u);
  hi = (u16)(r>>16);
  float h = __uint_as_float(r & 0xffff0000u);
  float l = a - h;
  u32 u2 = __float_as_uint(l);
  lo = (u16)((u2 + 0x7fffu + ((u2>>16)&1u)) >> 16);
}
__device__ __forceinline__ u16 hi_bf(float a){
  u32 u = __float_as_uint(a);
  return (u16)((u + 0x7fffu + ((u>>16)&1u)) >> 16);
}

#define GL2LDS(g,l) __builtin_amdgcn_global_load_lds((const __attribute__((address_space(1))) unsigned int*)(g), (__attribute__((address_space(3))) unsigned int*)(l), 16, 0, 0)

// ---------------- graph prep ----------------
__global__ __launch_bounds__(256) void zero_i(int* p, int n){
  int i = blockIdx.x*256 + threadIdx.x; if (i<n) p[i]=0;
}
__global__ __launch_bounds__(256) void hist_k(const int* __restrict__ ei, int* deg_g, int* deg_t){
  int e = blockIdx.x*256 + threadIdx.x; if (e>=NEG) return;
  int dv = (e<NEDGE) ? ei[NEDGE+e] : e-NEDGE;
  atomicAdd(&deg_g[dv],1);
  if (e<NEDGE) atomicAdd(&deg_t[dv],1);
}
__global__ __launch_bounds__(1024) void scan4096(const int* __restrict__ deg, int* __restrict__ off){
  __shared__ int lds[1024];
  int tid = threadIdx.x;
  int v[4]; int s=0;
  #pragma unroll
  for (int j=0;j<4;j++){ v[j]=deg[tid*4+j]; s+=v[j]; }
  lds[tid]=s; __syncthreads();
  for (int d=1; d<1024; d<<=1){
    int t = (tid>=d) ? lds[tid-d] : 0;
    __syncthreads();
    lds[tid] += t;
    __syncthreads();
  }
  int base = (tid>0) ? lds[tid-1] : 0;
  #pragma unroll
  for (int j=0;j<4;j++){ off[tid*4+j]=base; base+=v[j]; }
  if (tid==1023) off[4096]=base;
}
__global__ __launch_bounds__(256) void scatter_k(const int* __restrict__ ei,
    const int* __restrict__ off_g, int* cur_g, int* csr_g,
    const int* __restrict__ off_t, int* cur_t, int* csr_t){
  int e = blockIdx.x*256 + threadIdx.x; if (e>=NEG) return;
  int s, dv;
  if (e<NEDGE){ s=ei[e]; dv=ei[NEDGE+e]; } else { s=dv=e-NEDGE; }
  int p = atomicAdd(&cur_g[dv],1);
  csr_g[off_g[dv]+p]=s;
  if (e<NEDGE){ int p2 = atomicAdd(&cur_t[dv],1); csr_t[off_t[dv]+p2]=s; }
}
__global__ __launch_bounds__(256) void mkdis(const int* __restrict__ deg, float* dis){
  int i = blockIdx.x*256 + threadIdx.x; if (i>=NNODE) return;
  int d = deg[i]; dis[i] = d>0 ? rsqrtf((float)d) : 0.f;
}
__global__ __launch_bounds__(128) void pad_x(const float* __restrict__ x, float* __restrict__ xp){
  int n = blockIdx.x, c = threadIdx.x;
  if (c<80) xp[(size_t)n*80+c] = (c<78) ? x[(size_t)n*78+c] : 0.f;
}
// W1r[(h*80+k), c] = g1_w[k, h*2048+c], zero-padded k>=78
__global__ __launch_bounds__(256) void repack_w1(const float* __restrict__ g1w, float* __restrict__ w1r){
  int i = blockIdx.x*256 + threadIdx.x;   // 640*2048
  int kk = i >> 11, c = i & 2047;
  int h = kk/80, k2 = kk - h*80;
  w1r[i] = (k2<78) ? g1w[(size_t)k2*16384 + h*2048 + c] : 0.f;
}

// ---------------- fp32 -> bf16 hi/lo decompose (row-major [M,K] -> [M,Kp]) ----------------
__global__ __launch_bounds__(256) void dec(const float* __restrict__ A,
    u16* __restrict__ hi, u16* __restrict__ lo, int K, int Kp){
  int i = blockIdx.x*256 + threadIdx.x;
  int r = i / Kp, k = i - r*Kp;
  float a = (k<K) ? A[(size_t)r*K + k] : 0.f;
  u16 h, l; split_bf(a, h, l);
  hi[i]=h; lo[i]=l;
}

// ---------------- transpose + bf16(hi): W[K,Ntot] cols [n0,n0+Nw) -> hi [Nw,Kp] ----------------
__global__ __launch_bounds__(256) void tpd(const float* __restrict__ in, int Ntot, int n0,
    int K, int Kp, u16* __restrict__ outh){
  __shared__ float t[32][33];
  int bx = blockIdx.x*32;   // n in window
  int by = blockIdx.y*32;   // k
  int tx = threadIdx.x & 31, ty = threadIdx.x >> 5;
  for (int i=ty;i<32;i+=8){
    int kk=by+i;
    t[i][tx] = (kk<K) ? in[(size_t)kk*Ntot + n0 + bx + tx] : 0.f;
  }
  __syncthreads();
  for (int i=ty;i<32;i+=8){
    int nn=bx+i, kk=by+tx;
    if (kk<Kp) outh[(size_t)nn*Kp+kk] = hi_bf(t[tx][i]);
  }
}

// ---------------- split-A bf16 MFMA GEMM, m97-style global_load_lds staging ----------------
// C[M,N] = (Ah+Al)[M,K] * Bh[N,K]^T ; CT = float or u16(bf16)
// EPI: 0 none, 1 +bias, 3 relu(scale*acc+bias) + split hi/lo aux outputs (CT=float)
#define BM 128
#define BN 128
template<int EPI, typename CT>
__global__ __launch_bounds__(256,2) void mgemm(
    const u16* __restrict__ Ah, const u16* __restrict__ Al, int lda,
    const u16* __restrict__ Bh, int ldb,
    CT* __restrict__ C, int ldc, int K,
    const float* __restrict__ bias, float scale,
    u16* __restrict__ Chi, u16* __restrict__ Clo)
{
  __shared__ __align__(16) u16 Ash[128*32];
  __shared__ __align__(16) u16 Asl[128*32];
  __shared__ __align__(16) u16 Bsh[128*32];
  int tid = threadIdx.x;
  int bm = blockIdx.y*BM, bn = blockIdx.x*BN;
  int lane = tid & 63, wave = tid >> 6;
  int wr = (wave>>1)*64, wc = (wave&1)*64;
  int m16 = lane & 15, quad = lane >> 4;
  int srow = lane >> 2;          // row within 16-row group
  int skk  = (lane & 3) * 8;     // u16 offset within 32-elem row

  f32x4 acc[4][4] = {};
  for (int k0=0; k0<K; k0+=32){
    __syncthreads();
    #pragma unroll
    for (int t=0;t<2;t++){
      int g = wave + t*4;                 // group 0..7
      int row = g*16 + srow;
      GL2LDS(Ah + (size_t)(bm+row)*lda + k0 + skk, &Ash[g*512]);
      GL2LDS(Al + (size_t)(bm+row)*lda + k0 + skk, &Asl[g*512]);
      GL2LDS(Bh + (size_t)(bn+row)*ldb + k0 + skk, &Bsh[g*512]);
    }
    __syncthreads();
    int kq = quad*8;
    bf16x8 ah[4], al_[4], bh_[4];
    #pragma unroll
    for (int i=0;i<4;i++){
      ah[i]  = *(const bf16x8*)&Ash[(wr+i*16+m16)*32 + kq];
      al_[i] = *(const bf16x8*)&Asl[(wr+i*16+m16)*32 + kq];
    }
    #pragma unroll
    for (int j=0;j<4;j++)
      bh_[j] = *(const bf16x8*)&Bsh[(wc+j*16+m16)*32 + kq];
    #pragma unroll
    for (int i=0;i<4;i++)
      #pragma unroll
      for (int j=0;j<4;j++){
        acc[i][j] = __builtin_amdgcn_mfma_f32_16x16x32_bf16(ah[i],  bh_[j], acc[i][j], 0,0,0);
        acc[i][j] = __builtin_amdgcn_mfma_f32_16x16x32_bf16(al_[i], bh_[j], acc[i][j], 0,0,0);
      }
  }
  #pragma unroll
  for (int i=0;i<4;i++){
    int row0 = bm + wr + i*16 + quad*4;
    #pragma unroll
    for (int j=0;j<4;j++){
      int col = bn + wc + j*16 + m16;
      float bv = (EPI>=1) ? bias[col] : 0.f;
      #pragma unroll
      for (int r=0;r<4;r++){
        float v = acc[i][j][r];
        size_t idx = (size_t)(row0+r)*ldc + col;
        if (EPI==3){
          v = fmaxf(v*scale + bv, 0.f);
          C[idx] = (CT)v;
          u16 h_, l_; split_bf(v, h_, l_);
          Chi[idx]=h_; Clo[idx]=l_;
        } else {
          if (EPI==1) v = v + bv;
          if constexpr (sizeof(CT)==2) C[idx] = (CT)f2b(v);
          else C[idx] = (CT)v;
        }
      }
    }
  }
}

// ---------------- GAT attention-vector precompute ----------------
__global__ __launch_bounds__(256) void wsvec(const float* __restrict__ W,
    const float* __restrict__ as_, const float* __restrict__ ad_,
    float* __restrict__ ws, float* __restrict__ wd,
    int Kreal, int H, int C)
{
  int wv = blockIdx.x*4 + (threadIdx.x>>6);
  int lane = threadIdx.x & 63;
  int k = wv / H, h = wv - k*H;
  float ps=0.f, pd=0.f;
  if (k < Kreal){
    const float* wr = W + (size_t)k*((size_t)H*C) + (size_t)h*C;
    const float* ar = as_ + (size_t)h*C;
    const float* dr = ad_ + (size_t)h*C;
    for (int c=lane;c<C;c+=64){ float w=wr[c]; ps += w*ar[c]; pd += w*dr[c]; }
  }
  #pragma unroll
  for (int o=32;o;o>>=1){ ps += __shfl_down(ps,o); pd += __shfl_down(pd,o); }
  if (lane==0){ ws[k*H+h]=ps; wd[k*H+h]=pd; }
}
// small-K fallback (GAT1, Kp=80)
__global__ __launch_bounds__(256) void alk(const float* __restrict__ X,
    const float* __restrict__ ws, const float* __restrict__ wd,
    float* __restrict__ als, float* __restrict__ ald, int Kp)
{
  int n = blockIdx.x, tid = threadIdx.x;
  int hh = tid>>5, l32 = tid&31;
  const float* xr = X + (size_t)n*Kp;
  float ps=0.f, pd=0.f;
  for (int k=l32;k<Kp;k+=32){
    float xv = xr[k];
    ps += xv*ws[k*8+hh];
    pd += xv*wd[k*8+hh];
  }
  #pragma unroll
  for (int o=16;o;o>>=1){ ps += __shfl_down(ps,o,32); pd += __shfl_down(pd,o,32); }
  if (l32==0){ als[n*8+hh]=ps; ald[n*8+hh]=pd; }
}
// k-sliced attention logits
template<int VK>
__global__ __launch_bounds__(256) void alk2(const float* __restrict__ X,
    const float* __restrict__ ws, const float* __restrict__ wd,
    float* __restrict__ als, float* __restrict__ ald)
{
  int n = blockIdx.x, tid = threadIdx.x;
  int wv = tid>>6, lane = tid&63;
  const float* xr = X + (size_t)n*(VK*256) + tid*VK;
  float xv[VK];
  #pragma unroll
  for (int v=0; v<VK; v+=4){
    float4 xq = *(const float4*)(xr+v);
    xv[v]=xq.x; xv[v+1]=xq.y; xv[v+2]=xq.z; xv[v+3]=xq.w;
  }
  float ps[8], pd[8];
  #pragma unroll
  for (int h=0;h<8;h++){ ps[h]=0.f; pd[h]=0.f; }
  #pragma unroll
  for (int v=0; v<VK; v++){
    int kk = tid*VK+v;
    const float4* wr4 = (const float4*)(ws + (size_t)kk*8);
    float4 w0 = wr4[0], w1 = wr4[1];
    const float4* dr4 = (const float4*)(wd + (size_t)kk*8);
    float4 d0 = dr4[0], d1 = dr4[1];
    float xvv = xv[v];
    ps[0]+=xvv*w0.x; ps[1]+=xvv*w0.y; ps[2]+=xvv*w0.z; ps[3]+=xvv*w0.w;
    ps[4]+=xvv*w1.x; ps[5]+=xvv*w1.y; ps[6]+=xvv*w1.z; ps[7]+=xvv*w1.w;
    pd[0]+=xvv*d0.x; pd[1]+=xvv*d0.y; pd[2]+=xvv*d0.z; pd[3]+=xvv*d0.w;
    pd[4]+=xvv*d1.x; pd[5]+=xvv*d1.y; pd[6]+=xvv*d1.z; pd[7]+=xvv*d1.w;
  }
  #pragma unroll
  for (int h=0;h<8;h++){
    #pragma unroll
    for (int o=32;o;o>>=1){ ps[h]+=__shfl_down(ps[h],o); pd[h]+=__shfl_down(pd[h],o); }
  }
  __shared__ float red[4][16];
  if (lane==0){
    #pragma unroll
    for (int h=0;h<8;h++){ red[wv][h]=ps[h]; red[wv][8+h]=pd[h]; }
  }
  __syncthreads();
  if (tid<16){
    float s = red[0][tid]+red[1][tid]+red[2][tid]+red[3][tid];
    if (tid<8) als[n*8+tid]=s; else ald[n*8+(tid-8)]=s;
  }
}

// ---------------- GAT1 aggregate-first gather ----------------
__global__ __launch_bounds__(256) void gat1_gather(
    const float* __restrict__ xpad, const float* __restrict__ als, const float* __restrict__ ald,
    const int* __restrict__ off, const int* __restrict__ csr, float* __restrict__ y1)
{
  int d = blockIdx.x, tid = threadIdx.x;
  int hh = tid>>5, l32 = tid&31;
  int e0 = off[d], e1 = off[d+1];
  __shared__ float mh[8], lih[8], adh[8];
  __shared__ float wl[32][8];
  __shared__ int sl[32];
  if (tid < 8){
    float ad = ald[d*8+tid]; adh[tid]=ad;
    float m=-1e30f, l=0.f;
    for (int e=e0;e<e1;++e){
      float xv = als[csr[e]*8+tid] + ad;
      xv = xv>0.f?xv:0.2f*xv;
      if (xv>m){ l = l*__expf(m-xv)+1.f; m=xv; } else l += __expf(xv-m);
    }
    mh[tid]=m; lih[tid]=1.f/l;
  }
  __syncthreads();
  float acc0=0.f, acc1=0.f, acc2v=0.f;
  for (int cb=e0; cb<e1; cb+=32){
    int ce = min(32, e1-cb);
    if (tid < ce*8){
      int j = tid>>3, h2 = tid&7;
      int s = csr[cb+j];
      if (h2==0) sl[j]=s;
      float xv = als[s*8+h2] + adh[h2];
      xv = xv>0.f?xv:0.2f*xv;
      wl[j][h2] = __expf(xv-mh[h2])*lih[h2];
    }
    __syncthreads();
    for (int j=0;j<ce;++j){
      float w = wl[j][hh];
      const float* xr = xpad + (size_t)sl[j]*80;
      acc0 += w*xr[l32];
      acc1 += w*xr[l32+32];
      if (l32 < 16) acc2v += w*xr[l32+64];
    }
    __syncthreads();
  }
  float* yr = y1 + (size_t)d*640 + hh*80;
  yr[l32] = acc0; yr[l32+32] = acc1;
  if (l32<16) yr[l32+64] = acc2v;
}

// ---------------- all-head chunk aggregation (bf16 h) ----------------
template<int HPC, int C>
__global__ __launch_bounds__(256) void gat_aggN(
    const u16* __restrict__ h, const float* __restrict__ als, const float* __restrict__ ald,
    const int* __restrict__ off, const int* __restrict__ csr,
    float* __restrict__ accum, int head0)
{
  constexpr int V = C/256;
  int d = blockIdx.x, tid = threadIdx.x;
  int e0=off[d], e1=off[d+1];
  __shared__ float mh[HPC], lih[HPC], adh[HPC];
  __shared__ float wl[32][HPC];
  __shared__ int sl[32];
  if (tid < HPC){
    float ad = ald[d*8 + head0 + tid]; adh[tid]=ad;
    float m=-1e30f,l=0.f;
    for (int e=e0;e<e1;++e){
      float xv = als[csr[e]*8 + head0 + tid]+ad;
      xv = xv>0.f?xv:0.2f*xv;
      if (xv>m){ l=l*__expf(m-xv)+1.f; m=xv; } else l+=__expf(xv-m);
    }
    mh[tid]=m; lih[tid]=1.f/l;
  }
  __syncthreads();
  float acc[HPC][V];
  #pragma unroll
  for (int a=0;a<HPC;a++)
    #pragma unroll
    for (int v=0;v<V;v++) acc[a][v]=0.f;
  int c0 = tid*V;
  for (int cb=e0;cb<e1;cb+=32){
    int ce = min(32, e1-cb);
    if (tid < ce*HPC){
      int j = tid/HPC, h2 = tid - j*HPC;
      int s = csr[cb+j];
      if (h2==0) sl[j]=s;
      float xv = als[s*8 + head0 + h2] + adh[h2];
      xv = xv>0.f?xv:0.2f*xv;
      wl[j][h2] = __expf(xv-mh[h2])*lih[h2];
    }
    __syncthreads();
    for (int j=0;j<ce;++j){
      const u16* hr = h + (size_t)sl[j]*(HPC*C);
      #pragma unroll
      for (int a=0;a<HPC;a++){
        float w = wl[j][a];
        if constexpr (V==4){
          uint2 u = *(const uint2*)(hr + a*C + c0);
          acc[a][0] += w*blo(u.x); acc[a][1] += w*bhi(u.x);
          acc[a][2] += w*blo(u.y); acc[a][3] += w*bhi(u.y);
        } else {
          u32 u = *(const u32*)(hr + a*C + c0);
          acc[a][0] += w*blo(u); acc[a][1] += w*bhi(u);
        }
      }
    }
    __syncthreads();
  }
  float* ar = accum + (size_t)d*C + c0;
  #pragma unroll
  for (int v=0;v<V;v++){
    float s2 = 0.f;
    #pragma unroll
    for (int a=0;a<HPC;a++) s2 += acc[a][v];
    ar[v] += s2;
  }
}
// x = relu(acc/8 + b[c])
__global__ __launch_bounds__(256) void finishx(const float* __restrict__ accum,
    const float* __restrict__ bias, float* __restrict__ xo, int Cmask){
  int i = blockIdx.x*256 + threadIdx.x;
  int c = i & Cmask;
  xo[i] = fmaxf(accum[i]*0.125f + bias[c], 0.f);
}
__global__ __launch_bounds__(256) void finishx2(const float* __restrict__ accum,
    const float* __restrict__ bias, float* __restrict__ xo,
    u16* __restrict__ xh, u16* __restrict__ xl, int Cmask){
  int i = blockIdx.x*256 + threadIdx.x;
  int c = i & Cmask;
  float v = fmaxf(accum[i]*0.125f + bias[c], 0.f);
  xo[i] = v;
  u16 h_, l_; split_bf(v, h_, l_);
  xh[i]=h_; xl[i]=l_;
}

// ---------------- pooled GCN aggregation ----------------
__global__ __launch_bounds__(256) void pool_gcn(const float* __restrict__ x3,
    const float* __restrict__ dis, const int* __restrict__ off, const int* __restrict__ csr,
    float* __restrict__ z)
{
  int g = blockIdx.x, tid = threadIdx.x;
  int c0 = tid*2;
  float a0=0.f, a1=0.f;
  for (int dd=0; dd<32; ++dd){
    int d = g*32+dd;
    int e0=off[d], e1=off[d+1];
    float b0=0.f, b1=0.f;
    for (int e=e0;e<e1;++e){
      int s = csr[e]; float ds = dis[s];
      const float* xr = x3 + (size_t)s*512 + c0;
      b0 += ds*xr[0]; b1 += ds*xr[1];
    }
    float dw = dis[d];
    a0 += dw*b0; a1 += dw*b1;
  }
  z[(size_t)g*512+c0]   = a0*(1.f/32.f);
  z[(size_t)g*512+c0+1] = a1*(1.f/32.f);
}

// ---------------- TransformerConv aggregation (bf16 qkvs, logit-cache) ----------------
__global__ __launch_bounds__(256) void tr_agg(
  const u16* __restrict__ qkvs, const int* __restrict__ off, const int* __restrict__ csr,
  float* __restrict__ xt)
{
  int d = blockIdx.x, tid = threadIdx.x;
  int wv = tid>>6, lane = tid&63;
  int e0=off[d], e1=off[d+1];
  __shared__ float osum[4][512];
  __shared__ float sp[4][64];
  float qf[8];
  { uint4 u = *(const uint4*)(qkvs + (size_t)d*6656 + wv*512 + lane*8);
    qf[0]=blo(u.x); qf[1]=bhi(u.x); qf[2]=blo(u.y); qf[3]=bhi(u.y);
    qf[4]=blo(u.z); qf[5]=bhi(u.z); qf[6]=blo(u.w); qf[7]=bhi(u.w); }
  const float scale = 0.04419417382415922f; // 1/sqrt(512)
  float m=-1e30f,l=0.f;
  for (int e=e0;e<e1;++e){
    int s = csr[e];
    uint4 u = *(const uint4*)(qkvs + (size_t)s*6656 + 2048 + wv*512 + lane*8);
    float p = qf[0]*blo(u.x)+qf[1]*bhi(u.x)+qf[2]*blo(u.y)+qf[3]*bhi(u.y)
            + qf[4]*blo(u.z)+qf[5]*bhi(u.z)+qf[6]*blo(u.w)+qf[7]*bhi(u.w);
    #pragma unroll
    for (int o=32;o;o>>=1) p += __shfl_xor(p,o);
    p *= scale;
    int idx = e-e0;
    if (lane==0 && idx<64) sp[wv][idx]=p;
    if (p>m){ l=l*__expf(m-p)+1.f; m=p; } else l+=__expf(p-m);
  }
  float li = (e1>e0)?1.f/l:0.f;
  float acc[8]={0.f,0.f,0.f,0.f,0.f,0.f,0.f,0.f};
  for (int e=e0;e<e1;++e){
    int s = csr[e];
    int idx = e-e0;
    float p;
    if (idx<64) p = sp[wv][idx];
    else {
      uint4 u = *(const uint4*)(qkvs + (size_t)s*6656 + 2048 + wv*512 + lane*8);
      p = qf[0]*blo(u.x)+qf[1]*bhi(u.x)+qf[2]*blo(u.y)+qf[3]*bhi(u.y)
        + qf[4]*blo(u.z)+qf[5]*bhi(u.z)+qf[6]*blo(u.w)+qf[7]*bhi(u.w);
      #pragma unroll
      for (int o=32;o;o>>=1) p += __shfl_xor(p,o);
      p *= scale;
    }
    float w = __expf(p - m)*li;
    uint4 u = *(const uint4*)(qkvs + (size_t)s*6656 + 4096 + wv*512 + lane*8);
    acc[0]+=w*blo(u.x); acc[1]+=w*bhi(u.x); acc[2]+=w*blo(u.y); acc[3]+=w*bhi(u.y);
    acc[4]+=w*blo(u.z); acc[5]+=w*bhi(u.z); acc[6]+=w*blo(u.w); acc[7]+=w*bhi(u.w);
  }
  #pragma unroll
  for (int j=0;j<8;j++) osum[wv][lane*8+j]=acc[j];
  __syncthreads();
  for (int c=tid;c<512;c+=256){
    u16 sk = qkvs[(size_t)d*6656 + 6144 + c];
    float o = (osum[0][c]+osum[1][c]+osum[2][c]+osum[3][c])*0.25f + blo((u32)sk);
    xt[(size_t)d*512+c] = fmaxf(o,0.f);
  }
}

// ---------------- bias concat for qkv GEMM ----------------
__global__ __launch_bounds__(256) void catb(const float* __restrict__ bq, const float* __restrict__ bk,
    const float* __restrict__ bv, const float* __restrict__ bs, float* __restrict__ o){
  int i = blockIdx.x*256 + threadIdx.x; if (i>=6656) return;
  float v;
  if (i<2048) v=bq[i]; else if (i<4096) v=bk[i-2048];
  else if (i<6144) v=bv[i-4096]; else v=bs[i-6144];
  o[i]=v;
}

// ---------------- fused head (bf16 [N,K] weights) ----------------
__device__ __forceinline__ float dotb(const u16* __restrict__ w, const float* __restrict__ s,
                                      int k0, int k1){
  float acc=0.f;
  #pragma unroll 4
  for (int k=k0;k<k1;k+=8){
    uint4 u = *(const uint4*)(w+k);
    float4 s0 = *(const float4*)(s+k);
    float4 s1 = *(const float4*)(s+k+4);
    acc += blo(u.x)*s0.x + bhi(u.x)*s0.y + blo(u.y)*s0.z + bhi(u.y)*s0.w
         + blo(u.z)*s1.x + bhi(u.z)*s1.y + blo(u.w)*s1.z + bhi(u.w)*s1.w;
  }
  return acc;
}
__global__ __launch_bounds__(256) void head_k(
  const float* __restrict__ z, const float* __restrict__ xt, const float* __restrict__ fp,
  const u16* __restrict__ gcnT, const float* __restrict__ gcn_b,
  const u16* __restrict__ fc1T, const float* __restrict__ fc1_b,
  const u16* __restrict__ fc2T, const float* __restrict__ fc2_b,
  const u16* __restrict__ b1T, const float* __restrict__ b1_b,
  const u16* __restrict__ b2T, const float* __restrict__ b2_b,
  const u16* __restrict__ b3T, const float* __restrict__ b3_b,
  const float* __restrict__ b4_w, const float* __restrict__ b4_b,
  float* __restrict__ out)
{
  int g = blockIdx.x, tid = threadIdx.x;
  __shared__ __align__(16) float xc[1024];
  __shared__ __align__(16) float sa[1504];
  __shared__ __align__(16) float sb[256];
  __shared__ __align__(16) float scm[256];
  for (int c=tid;c<512;c+=256) sa[c] = z[(size_t)g*512+c];
  __syncthreads();
  float vgcn = gcn_b[tid] + dotb(gcnT + (size_t)tid*512, sa, 0, 512);
  for (int c=tid;c<512;c+=256){
    float s=0.f;
    for (int i=0;i<32;i++) s += xt[(size_t)(g*32+i)*512 + c];
    xc[256+c] = s*(1.f/32.f);
  }
  xc[tid] = vgcn;
  __syncthreads();
  for (int c=tid;c<1496;c+=256) sa[c] = (c<1489) ? fp[(size_t)g*1489+c] : 0.f;
  __syncthreads();
  { // fc1 (1489 -> 128), 2-way k-split at 752
    int n = tid & 127, half = tid >> 7;
    sb[tid] = dotb(fc1T + (size_t)n*1496, sa, half?752:0, half?1496:752);
  }
  __syncthreads();
  if (tid<128) scm[tid] = fmaxf(sb[tid]+sb[tid+128]+fc1_b[tid], 0.f);
  __syncthreads();
  xc[768+tid] = fmaxf(fc2_b[tid] + dotb(fc2T + (size_t)tid*128, scm, 0, 128), 0.f);
  __syncthreads();
  sa[tid] = fmaxf(b1_b[tid] + dotb(b1T + (size_t)tid*1024, xc, 0, 1024), 0.f);
  __syncthreads();
  { // b2 (256 -> 128), 2-way
    int n = tid & 127, half = tid >> 7;
    sb[tid] = dotb(b2T + (size_t)n*256, sa, half*128, half*128+128);
  }
  __syncthreads();
  if (tid<128) scm[tid] = fmaxf(sb[tid]+sb[tid+128]+b2_b[tid], 0.f);
  __syncthreads();
  { // b3 (128 -> 64), 4-way
    int n = tid & 63, part = tid >> 6;
    sb[tid] = dotb(b3T + (size_t)n*128, scm, part*32, part*32+32);
  }
  __syncthreads();
  if (tid<64) sa[tid] = fmaxf(sb[tid]+sb[tid+64]+sb[tid+128]+sb[tid+192]+b3_b[tid], 0.f);
  __syncthreads();
  if (tid<64){
    float p = sa[tid]*b4_w[tid];
    #pragma unroll
    for (int o=32;o;o>>=1) p += __shfl_down(p,o);
    if (tid==0) out[g] = 1.f/(1.f+__expf(-(p + b4_b[0])));
  }
}

extern "C" void kernel_launch(void* const* d_in, const int* in_sizes, int n_in,
                              void* d_out, int out_size, void* d_ws, size_t ws_size,
                              hipStream_t stream)
{
  (void)in_sizes; (void)n_in; (void)out_size; (void)ws_size;
  const float* x     = (const float*)d_in[0];
  const float* fp    = (const float*)d_in[1];
  const int*   ei    = (const int*)d_in[2];
  const float* g1_w  = (const float*)d_in[4];
  const float* g1_as = (const float*)d_in[5];
  const float* g1_ad = (const float*)d_in[6];
  const float* g1_b  = (const float*)d_in[7];
  const float* g2_w  = (const float*)d_in[8];
  const float* g2_as = (const float*)d_in[9];
  const float* g2_ad = (const float*)d_in[10];
  const float* g2_b  = (const float*)d_in[11];
  const float* g3_w  = (const float*)d_in[12];
  const float* g3_as = (const float*)d_in[13];
  const float* g3_ad = (const float*)d_in[14];
  const float* g3_b  = (const float*)d_in[15];
  const float* gcn_w = (const float*)d_in[16];
  const float* gcn_b = (const float*)d_in[17];
  const float* t_wq  = (const float*)d_in[18];
  const float* t_wk  = (const float*)d_in[19];
  const float* t_wv  = (const float*)d_in[20];
  const float* t_bq  = (const float*)d_in[21];
  const float* t_bk  = (const float*)d_in[22];
  const float* t_bv  = (const float*)d_in[23];
  const float* t_ws  = (const float*)d_in[24];
  const float* t_bs  = (const float*)d_in[25];
  const float* fc1_w = (const float*)d_in[26];
  const float* fc1_b = (const float*)d_in[27];
  const float* fc2_w = (const float*)d_in[28];
  const float* fc2_b = (const float*)d_in[29];
  const float* b1_w  = (const float*)d_in[30];
  const float* b1_b  = (const float*)d_in[31];
  const float* b2_w  = (const float*)d_in[32];
  const float* b2_b  = (const float*)d_in[33];
  const float* b3_w  = (const float*)d_in[34];
  const float* b3_b  = (const float*)d_in[35];
  const float* b4_w  = (const float*)d_in[36];
  const float* b4_b  = (const float*)d_in[37];

  char* base = (char*)d_ws;
  size_t offb = 0;
  auto alloc = [&](size_t bytes)->void*{
    void* p = base + offb; offb = (offb + bytes + 255) & ~(size_t)255; return p;
  };
  int*   cnt   = (int*)alloc(16384*4);
  int*   off_g = (int*)alloc(4097*4);
  int*   off_t = (int*)alloc(4097*4);
  int*   csr_g = (int*)alloc(12288*4);
  int*   csr_t = (int*)alloc(8192*4);
  float* dis   = (float*)alloc(4096*4);
  float* xpad  = (float*)alloc((size_t)4096*80*4);
  u16*   xph   = (u16*)alloc((size_t)4096*96*2);
  u16*   xpl   = (u16*)alloc((size_t)4096*96*2);
  float* als   = (float*)alloc((size_t)4096*8*4);
  float* ald   = (float*)alloc((size_t)4096*8*4);
  float* wsv   = (float*)alloc((size_t)2048*8*4);
  float* wdv   = (float*)alloc((size_t)2048*8*4);
  float* zbuf  = (float*)alloc((size_t)128*512*4);
  float* cbias = (float*)alloc((size_t)6656*4);
  float* w1r   = (float*)alloc((size_t)640*2048*4);
  // head weights, bf16 [N,Kp]
  u16*   gcnT  = (u16*)alloc((size_t)256*512*2);
  u16*   fc1T  = (u16*)alloc((size_t)128*1496*2);
  u16*   fc2T  = (u16*)alloc((size_t)256*128*2);
  u16*   b1T   = (u16*)alloc((size_t)256*1024*2);
  u16*   b2T   = (u16*)alloc((size_t)128*256*2);
  u16*   b3T   = (u16*)alloc((size_t)64*128*2);
  char*  big   = (char*)alloc((size_t)144<<20);

  // ---- overlays (MB offsets) ----
  // GAT1 phase
  float* x1    = (float*)(big);                         // [0,32)  fp32 out
  float* y1    = (float*)(big + ((size_t)32<<20));      // [32,42)
  u16*   y1h   = (u16*)  (big + ((size_t)42<<20));      // [42,47)
  u16*   y1l   = (u16*)  (big + ((size_t)47<<20));      // [47,52)
  u16*   w1rth = (u16*)  (big + ((size_t)52<<20));      // [52,56)
  u16*   x1h   = (u16*)  (big + ((size_t)56<<20));      // [56,72)
  u16*   x1l   = (u16*)  (big + ((size_t)72<<20));      // [72,88)
  // GAT2 phase
  u16*   w2th  = (u16*)  (big + ((size_t)88<<20));      // [88,96)
  u16*   h2    = (u16*)  (big + ((size_t)96<<20));      // [96,112) bf16
  float* acc2  = (float*)(big + ((size_t)112<<20));     // [112,128)
  float* x2    = (float*)(big + ((size_t)128<<20));     // [128,144)
  u16*   x2h   = (u16*)  (big);                         // [0,8)  (x1 dead)
  u16*   x2l   = (u16*)  (big + ((size_t)8<<20));       // [8,16)
  // GAT3 phase
  u16*   w3th  = (u16*)  (big + ((size_t)16<<20));      // [16,20)
  u16*   h3    = (u16*)  (big + ((size_t)20<<20));      // [20,36) bf16
  float* acc3  = (float*)(big + ((size_t)40<<20));      // [40,48)
  float* x3    = (float*)(big + ((size_t)48<<20));      // [48,56)
  // transformer phase
  u16*   qkvTh = (u16*)  (big);                         // [0,2)
  u16*   qkvs  = (u16*)  (big + ((size_t)8<<20));       // [8,64)  bf16 [4096][6656]
  float* xt    = (float*)(big + ((size_t)64<<20));      // [64,72)

  int* deg_g = cnt;       int* cur_g = cnt+4096;
  int* deg_t = cnt+8192;  int* cur_t = cnt+12288;

  // ---- graph prep ----
  zero_i<<<64,256,0,stream>>>(cnt, 16384);
  hist_k<<<48,256,0,stream>>>(ei, deg_g, deg_t);
  scan4096<<<1,1024,0,stream>>>(deg_g, off_g);
  scan4096<<<1,1024,0,stream>>>(deg_t, off_t);
  scatter_k<<<48,256,0,stream>>>(ei, off_g, cur_g, csr_g, off_t, cur_t, csr_t);
  mkdis<<<16,256,0,stream>>>(deg_g, dis);
  pad_x<<<4096,128,0,stream>>>(x, xpad);
  repack_w1<<<5120,256,0,stream>>>(g1_w, w1r);
  dec<<<1536,256,0,stream>>>(xpad, xph, xpl, 80, 96);
  // head weight transposes (bf16)
  tpd<<<dim3(8,16),256,0,stream>>>(gcn_w, 256, 0, 512, 512, gcnT);
  tpd<<<dim3(4,47),256,0,stream>>>(fc1_w, 128, 0, 1489, 1496, fc1T);
  tpd<<<dim3(8,4), 256,0,stream>>>(fc2_w, 256, 0, 128, 128, fc2T);
  tpd<<<dim3(8,32),256,0,stream>>>(b1_w,  256, 0, 1024, 1024, b1T);
  tpd<<<dim3(4,8), 256,0,stream>>>(b2_w,  128, 0, 256, 256, b2T);
  tpd<<<dim3(2,4), 256,0,stream>>>(b3_w,  64,  0, 128, 128, b3T);

  // ---- GAT1 (aggregate-first) ----
  wsvec<<<160,256,0,stream>>>(g1_w, g1_as, g1_ad, wsv, wdv, 78, 8, 2048);
  alk<<<4096,256,0,stream>>>(xpad, wsv, wdv, als, ald, 80);
  gat1_gather<<<4096,256,0,stream>>>(xpad, als, ald, off_g, csr_g, y1);
  dec<<<10240,256,0,stream>>>(y1, y1h, y1l, 640, 640);
  tpd<<<dim3(64,20),256,0,stream>>>(w1r, 2048, 0, 640, 640, w1rth);
  mgemm<3,float><<<dim3(16,32),256,0,stream>>>(y1h, y1l, 640, w1rth, 640,
                                         x1, 2048, 640, g1_b, 0.125f, x1h, x1l);

  // ---- GAT2 (transform-first, 4 chunks x 2 heads) ----
  wsvec<<<4096,256,0,stream>>>(g2_w, g2_as, g2_ad, wsv, wdv, 2048, 8, 1024);
  alk2<8><<<4096,256,0,stream>>>(x1, wsv, wdv, als, ald);
  hipMemsetAsync(acc2, 0, (size_t)4096*1024*4, stream);
  for (int c=0;c<4;c++){
    tpd<<<dim3(64,64),256,0,stream>>>(g2_w, 8192, c*2048, 2048, 2048, w2th);
    mgemm<0,u16><<<dim3(16,32),256,0,stream>>>(x1h, x1l, 2048, w2th, 2048,
                                           h2, 2048, 2048, nullptr, 0.f, nullptr, nullptr);
    gat_aggN<2,1024><<<4096,256,0,stream>>>(h2, als, ald, off_g, csr_g, acc2, c*2);
  }
  finishx2<<<16384,256,0,stream>>>(acc2, g2_b, x2, x2h, x2l, 1023);

  // ---- GAT3 (2 chunks x 4 heads) ----
  wsvec<<<2048,256,0,stream>>>(g3_w, g3_as, g3_ad, wsv, wdv, 1024, 8, 512);
  alk2<4><<<4096,256,0,stream>>>(x2, wsv, wdv, als, ald);
  hipMemsetAsync(acc3, 0, (size_t)4096*512*4, stream);
  for (int c=0;c<2;c++){
    tpd<<<dim3(64,32),256,0,stream>>>(g3_w, 4096, c*2048, 1024, 1024, w3th);
    mgemm<0,u16><<<dim3(16,32),256,0,stream>>>(x2h, x2l, 1024, w3th, 1024,
                                           h3, 2048, 1024, nullptr, 0.f, nullptr, nullptr);
    gat_aggN<4,512><<<4096,256,0,stream>>>(h3, als, ald, off_g, csr_g, acc3, c*4);
  }
  finishx<<<8192,256,0,stream>>>(acc3, g3_b, x3, 511);
  pool_gcn<<<128,256,0,stream>>>(x3, dis, off_g, csr_g, zbuf);

  // ---- Transformer branch (fused q|k|v|skip GEMM, bf16 out) ----
  tpd<<<dim3(64,3),256,0,stream>>>(t_wq, 2048, 0, 78, 96, qkvTh);
  tpd<<<dim3(64,3),256,0,stream>>>(t_wk, 2048, 0, 78, 96, qkvTh + (size_t)2048*96);
  tpd<<<dim3(64,3),256,0,stream>>>(t_wv, 2048, 0, 78, 96, qkvTh + (size_t)4096*96);
  tpd<<<dim3(16,3),256,0,stream>>>(t_ws, 512,  0, 78, 96, qkvTh + (size_t)6144*96);
  catb<<<26,256,0,stream>>>(t_bq, t_bk, t_bv, t_bs, cbias);
  mgemm<1,u16><<<dim3(52,32),256,0,stream>>>(xph, xpl, 96, qkvTh, 96,
                                         qkvs, 6656, 96, cbias, 0.f, nullptr, nullptr);
  tr_agg<<<4096,256,0,stream>>>(qkvs, off_t, csr_t, xt);

  // ---- fused head ----
  head_k<<<128,256,0,stream>>>(zbuf, xt, fp, gcnT, gcn_b,
                               fc1T, fc1_b, fc2T, fc2_b,
                               b1T, b1_b, b2T, b2_b, b3T, b3_b, b4_w, b4_b,
                               (float*)d_out);
}

// Round 6
// 947.125 us; speedup vs baseline: 5.8781x; 1.1660x over previous
//
#include <hip/hip_runtime.h>

typedef unsigned short u16;
typedef unsigned int   u32;

typedef __bf16 bf16x8 __attribute__((ext_vector_type(8)));
typedef float  f32x4  __attribute__((ext_vector_type(4)));

#define NNODE 4096
#define NEDGE 8192
#define NEG   12288   /* edges incl self-loops */

__device__ __forceinline__ float blo(u32 u){ return __uint_as_float(u<<16); }
__device__ __forceinline__ float bhi(u32 u){ return __uint_as_float(u & 0xffff0000u); }
__device__ __forceinline__ u16 f2b(float f){
  u32 u = __float_as_uint(f);
  u += 0x7fffu + ((u>>16)&1u);
  return (u16)(u>>16);
}
__device__ __forceinline__ void split_bf(float a, u16& hi, u16& lo){
  u32 u = __float_as_uint(a);
  u32 r = u + 0x7fffu + ((u>>16)&1u);
  hi = (u16)(r>>16);
  float h = __uint_as_float(r & 0xffff0000u);
  float l = a - h;
  u32 u2 = __float_as_uint(l);
  lo = (u16)((u2 + 0x7fffu + ((u2>>16)&1u)) >> 16);
}
__device__ __forceinline__ u16 hi_bf(float a){
  u32 u = __float_as_uint(a);
  return (u16)((u + 0x7fffu + ((u>>16)&1u)) >> 16);
}

#define GL2LDS(g,l) __builtin_amdgcn_global_load_lds((const __attribute__((address_space(1))) unsigned int*)(g), (__attribute__((address_space(3))) unsigned int*)(l), 16, 0, 0)

// ---------------- graph prep ----------------
__global__ __launch_bounds__(256) void zero_i(int* p, int n){
  int i = blockIdx.x*256 + threadIdx.x; if (i<n) p[i]=0;
}
__global__ __launch_bounds__(256) void hist_k(const int* __restrict__ ei, int* deg_g, int* deg_t){
  int e = blockIdx.x*256 + threadIdx.x; if (e>=NEG) return;
  int dv = (e<NEDGE) ? ei[NEDGE+e] : e-NEDGE;
  atomicAdd(&deg_g[dv],1);
  if (e<NEDGE) atomicAdd(&deg_t[dv],1);
}
__global__ __launch_bounds__(1024) void scan4096(const int* __restrict__ deg, int* __restrict__ off){
  __shared__ int lds[1024];
  int tid = threadIdx.x;
  int v[4]; int s=0;
  #pragma unroll
  for (int j=0;j<4;j++){ v[j]=deg[tid*4+j]; s+=v[j]; }
  lds[tid]=s; __syncthreads();
  for (int d=1; d<1024; d<<=1){
    int t = (tid>=d) ? lds[tid-d] : 0;
    __syncthreads();
    lds[tid] += t;
    __syncthreads();
  }
  int base = (tid>0) ? lds[tid-1] : 0;
  #pragma unroll
  for (int j=0;j<4;j++){ off[tid*4+j]=base; base+=v[j]; }
  if (tid==1023) off[4096]=base;
}
__global__ __launch_bounds__(256) void scatter_k(const int* __restrict__ ei,
    const int* __restrict__ off_g, int* cur_g, int* csr_g,
    const int* __restrict__ off_t, int* cur_t, int* csr_t){
  int e = blockIdx.x*256 + threadIdx.x; if (e>=NEG) return;
  int s, dv;
  if (e<NEDGE){ s=ei[e]; dv=ei[NEDGE+e]; } else { s=dv=e-NEDGE; }
  int p = atomicAdd(&cur_g[dv],1);
  csr_g[off_g[dv]+p]=s;
  if (e<NEDGE){ int p2 = atomicAdd(&cur_t[dv],1); csr_t[off_t[dv]+p2]=s; }
}
__global__ __launch_bounds__(256) void mkdis(const int* __restrict__ deg, float* dis){
  int i = blockIdx.x*256 + threadIdx.x; if (i>=NNODE) return;
  int d = deg[i]; dis[i] = d>0 ? rsqrtf((float)d) : 0.f;
}
// xpad fp32 [n][80] + xph bf16-hi [n][96]
__global__ __launch_bounds__(128) void pad_x(const float* __restrict__ x, float* __restrict__ xp,
                                             u16* __restrict__ xh){
  int n = blockIdx.x, c = threadIdx.x;
  if (c<96){
    float v = (c<78) ? x[(size_t)n*78+c] : 0.f;
    if (c<80) xp[(size_t)n*80+c] = v;
    xh[(size_t)n*96+c] = hi_bf(v);
  }
}
// W1r[(h*80+k), c] = g1_w[k, h*2048+c], zero-padded k>=78
__global__ __launch_bounds__(256) void repack_w1(const float* __restrict__ g1w, float* __restrict__ w1r){
  int i = blockIdx.x*256 + threadIdx.x;   // 640*2048
  int kk = i >> 11, c = i & 2047;
  int h = kk/80, k2 = kk - h*80;
  w1r[i] = (k2<78) ? g1w[(size_t)k2*16384 + h*2048 + c] : 0.f;
}

// ---------------- transpose + bf16(hi): W[K,Ntot] cols [n0,n0+Nw) -> hi [Nw,Kp] ----------------
__global__ __launch_bounds__(256) void tpd(const float* __restrict__ in, int Ntot, int n0,
    int K, int Kp, u16* __restrict__ outh){
  __shared__ float t[32][33];
  int bx = blockIdx.x*32;   // n in window
  int by = blockIdx.y*32;   // k
  int tx = threadIdx.x & 31, ty = threadIdx.x >> 5;
  for (int i=ty;i<32;i+=8){
    int kk=by+i;
    t[i][tx] = (kk<K) ? in[(size_t)kk*Ntot + n0 + bx + tx] : 0.f;
  }
  __syncthreads();
  for (int i=ty;i<32;i+=8){
    int nn=bx+i, kk=by+tx;
    if (kk<Kp) outh[(size_t)nn*Kp+kk] = hi_bf(t[tx][i]);
  }
}

// ---------------- attention-table pack: rows 0..7 = ws heads, 8..15 = wd heads, rest 0 ----------------
__global__ __launch_bounds__(256) void mk_wsT(const float* __restrict__ wsv, const float* __restrict__ wdv,
    u16* __restrict__ th, u16* __restrict__ tl, int Kp){
  int i = blockIdx.x*256 + threadIdx.x;   // over 128*Kp
  int r = i / Kp, k = i - r*Kp;
  float v = 0.f;
  if (r<8) v = wsv[k*8+r];
  else if (r<16) v = wdv[k*8+(r-8)];
  u16 h,l; split_bf(v,h,l);
  th[i]=h; tl[i]=l;
}

// ---------------- MFMA GEMM (m97 staging): C = (Ah[+Al]) * (Bh[+Bl])^T ----------------
// EPI: 0 plain CT store, 1 +bias CT store, 4 logits -> C[row*16+col] fp32 (col<16),
//      5 relu(scale*acc+bias) -> split hi/lo only
#define BM 128
#define BN 128
template<int EPI, int SA, int SB, typename CT>
__global__ __launch_bounds__(256,2) void mgemm(
    const u16* __restrict__ Ah, const u16* __restrict__ Al, int lda,
    const u16* __restrict__ Bh, const u16* __restrict__ Bl, int ldb,
    CT* __restrict__ C, int ldc, int K,
    const float* __restrict__ bias, float scale,
    u16* __restrict__ Chi, u16* __restrict__ Clo)
{
  __shared__ __align__(16) u16 Ash[128*32];
  __shared__ __align__(16) u16 Bsh[128*32];
  __shared__ __align__(16) u16 Asl[SA?128*32:16];
  __shared__ __align__(16) u16 Bsl[SB?128*32:16];
  int tid = threadIdx.x;
  int bm = blockIdx.y*BM, bn = blockIdx.x*BN;
  int lane = tid & 63, wave = tid >> 6;
  int wr = (wave>>1)*64, wc = (wave&1)*64;
  int m16 = lane & 15, quad = lane >> 4;
  int srow = lane >> 2;
  int skk  = (lane & 3) * 8;

  f32x4 acc[4][4] = {};
  for (int k0=0; k0<K; k0+=32){
    __syncthreads();
    #pragma unroll
    for (int t=0;t<2;t++){
      int g = wave + t*4;
      int row = g*16 + srow;
      GL2LDS(Ah + (size_t)(bm+row)*lda + k0 + skk, &Ash[g*512]);
      if (SA) GL2LDS(Al + (size_t)(bm+row)*lda + k0 + skk, &Asl[g*512]);
      GL2LDS(Bh + (size_t)(bn+row)*ldb + k0 + skk, &Bsh[g*512]);
      if (SB) GL2LDS(Bl + (size_t)(bn+row)*ldb + k0 + skk, &Bsl[g*512]);
    }
    __syncthreads();
    int kq = quad*8;
    bf16x8 ah[4], al_[4], bh_[4], bl_[4];
    #pragma unroll
    for (int i=0;i<4;i++){
      ah[i]  = *(const bf16x8*)&Ash[(wr+i*16+m16)*32 + kq];
      if (SA) al_[i] = *(const bf16x8*)&Asl[(wr+i*16+m16)*32 + kq];
    }
    #pragma unroll
    for (int j=0;j<4;j++){
      bh_[j] = *(const bf16x8*)&Bsh[(wc+j*16+m16)*32 + kq];
      if (SB) bl_[j] = *(const bf16x8*)&Bsl[(wc+j*16+m16)*32 + kq];
    }
    #pragma unroll
    for (int i=0;i<4;i++)
      #pragma unroll
      for (int j=0;j<4;j++){
        acc[i][j] = __builtin_amdgcn_mfma_f32_16x16x32_bf16(ah[i], bh_[j], acc[i][j], 0,0,0);
        if (SA) acc[i][j] = __builtin_amdgcn_mfma_f32_16x16x32_bf16(al_[i], bh_[j], acc[i][j], 0,0,0);
        if (SB) acc[i][j] = __builtin_amdgcn_mfma_f32_16x16x32_bf16(ah[i], bl_[j], acc[i][j], 0,0,0);
      }
  }
  #pragma unroll
  for (int i=0;i<4;i++){
    int row0 = bm + wr + i*16 + quad*4;
    #pragma unroll
    for (int j=0;j<4;j++){
      int col = bn + wc + j*16 + m16;
      float bv = (EPI==1||EPI==5) ? bias[col] : 0.f;
      #pragma unroll
      for (int r=0;r<4;r++){
        float v = acc[i][j][r];
        if constexpr (EPI==5){
          v = fmaxf(v*scale + bv, 0.f);
          size_t idx = (size_t)(row0+r)*ldc + col;
          u16 h_, l_; split_bf(v, h_, l_);
          Chi[idx]=h_; Clo[idx]=l_;
        } else if constexpr (EPI==4){
          if (col < 16) C[(size_t)(row0+r)*16 + col] = v;
        } else {
          if (EPI==1) v += bv;
          size_t idx = (size_t)(row0+r)*ldc + col;
          if constexpr (sizeof(CT)==2) C[idx] = (CT)f2b(v);
          else C[idx] = (CT)v;
        }
      }
    }
  }
}

// ---------------- GAT attention-vector precompute ----------------
__global__ __launch_bounds__(256) void wsvec(const float* __restrict__ W,
    const float* __restrict__ as_, const float* __restrict__ ad_,
    float* __restrict__ ws, float* __restrict__ wd,
    int Kreal, int H, int C)
{
  int wv = blockIdx.x*4 + (threadIdx.x>>6);
  int lane = threadIdx.x & 63;
  int k = wv / H, h = wv - k*H;
  float ps=0.f, pd=0.f;
  if (k < Kreal){
    const float* wr = W + (size_t)k*((size_t)H*C) + (size_t)h*C;
    const float* ar = as_ + (size_t)h*C;
    const float* dr = ad_ + (size_t)h*C;
    for (int c=lane;c<C;c+=64){ float w=wr[c]; ps += w*ar[c]; pd += w*dr[c]; }
  }
  #pragma unroll
  for (int o=32;o;o>>=1){ ps += __shfl_down(ps,o); pd += __shfl_down(pd,o); }
  if (lane==0){ ws[k*H+h]=ps; wd[k*H+h]=pd; }
}
// GAT1 logits (Kp=80), writes alsd[n][16] = [als(8) | ald(8)]
__global__ __launch_bounds__(256) void alk(const float* __restrict__ X,
    const float* __restrict__ ws, const float* __restrict__ wd,
    float* __restrict__ alsd, int Kp)
{
  int n = blockIdx.x, tid = threadIdx.x;
  int hh = tid>>5, l32 = tid&31;
  const float* xr = X + (size_t)n*Kp;
  float ps=0.f, pd=0.f;
  for (int k=l32;k<Kp;k+=32){
    float xv = xr[k];
    ps += xv*ws[k*8+hh];
    pd += xv*wd[k*8+hh];
  }
  #pragma unroll
  for (int o=16;o;o>>=1){ ps += __shfl_down(ps,o,32); pd += __shfl_down(pd,o,32); }
  if (l32==0){ alsd[n*16+hh]=ps; alsd[n*16+8+hh]=pd; }
}

// ---------------- GAT1 aggregate-first gather (emits hi/lo) ----------------
__global__ __launch_bounds__(256) void gat1_gather(
    const float* __restrict__ xpad, const float* __restrict__ alsd,
    const int* __restrict__ off, const int* __restrict__ csr,
    u16* __restrict__ y1h, u16* __restrict__ y1l)
{
  int d = blockIdx.x, tid = threadIdx.x;
  int hh = tid>>5, l32 = tid&31;
  int e0 = off[d], e1 = off[d+1];
  __shared__ float mh[8], lih[8], adh[8];
  __shared__ float wl[32][8];
  __shared__ int sl[32];
  if (tid < 8){
    float ad = alsd[d*16+8+tid]; adh[tid]=ad;
    float m=-1e30f, l=0.f;
    for (int e=e0;e<e1;++e){
      float xv = alsd[csr[e]*16+tid] + ad;
      xv = xv>0.f?xv:0.2f*xv;
      if (xv>m){ l = l*__expf(m-xv)+1.f; m=xv; } else l += __expf(xv-m);
    }
    mh[tid]=m; lih[tid]=1.f/l;
  }
  __syncthreads();
  float acc0=0.f, acc1=0.f, acc2v=0.f;
  for (int cb=e0; cb<e1; cb+=32){
    int ce = min(32, e1-cb);
    if (tid < ce*8){
      int j = tid>>3, h2 = tid&7;
      int s = csr[cb+j];
      if (h2==0) sl[j]=s;
      float xv = alsd[s*16+h2] + adh[h2];
      xv = xv>0.f?xv:0.2f*xv;
      wl[j][h2] = __expf(xv-mh[h2])*lih[h2];
    }
    __syncthreads();
    for (int j=0;j<ce;++j){
      float w = wl[j][hh];
      const float* xr = xpad + (size_t)sl[j]*80;
      acc0 += w*xr[l32];
      acc1 += w*xr[l32+32];
      if (l32 < 16) acc2v += w*xr[l32+64];
    }
    __syncthreads();
  }
  size_t base = (size_t)d*640 + hh*80;
  u16 h_, l_;
  split_bf(acc0, h_, l_); y1h[base+l32]=h_;    y1l[base+l32]=l_;
  split_bf(acc1, h_, l_); y1h[base+l32+32]=h_; y1l[base+l32+32]=l_;
  if (l32<16){ split_bf(acc2v, h_, l_); y1h[base+l32+64]=h_; y1l[base+l32+64]=l_; }
}

// ---------------- all-head chunk aggregation (bf16 h, alsd layout) ----------------
template<int HPC, int C>
__global__ __launch_bounds__(256) void gat_aggN(
    const u16* __restrict__ h, const float* __restrict__ alsd,
    const int* __restrict__ off, const int* __restrict__ csr,
    float* __restrict__ accum, int head0)
{
  constexpr int V = C/256;
  int d = blockIdx.x, tid = threadIdx.x;
  int e0=off[d], e1=off[d+1];
  __shared__ float mh[HPC], lih[HPC], adh[HPC];
  __shared__ float wl[32][HPC];
  __shared__ int sl[32];
  if (tid < HPC){
    float ad = alsd[d*16 + 8 + head0 + tid]; adh[tid]=ad;
    float m=-1e30f,l=0.f;
    for (int e=e0;e<e1;++e){
      float xv = alsd[csr[e]*16 + head0 + tid]+ad;
      xv = xv>0.f?xv:0.2f*xv;
      if (xv>m){ l=l*__expf(m-xv)+1.f; m=xv; } else l+=__expf(xv-m);
    }
    mh[tid]=m; lih[tid]=1.f/l;
  }
  __syncthreads();
  float acc[HPC][V];
  #pragma unroll
  for (int a=0;a<HPC;a++)
    #pragma unroll
    for (int v=0;v<V;v++) acc[a][v]=0.f;
  int c0 = tid*V;
  for (int cb=e0;cb<e1;cb+=32){
    int ce = min(32, e1-cb);
    if (tid < ce*HPC){
      int j = tid/HPC, h2 = tid - j*HPC;
      int s = csr[cb+j];
      if (h2==0) sl[j]=s;
      float xv = alsd[s*16 + head0 + h2] + adh[h2];
      xv = xv>0.f?xv:0.2f*xv;
      wl[j][h2] = __expf(xv-mh[h2])*lih[h2];
    }
    __syncthreads();
    for (int j=0;j<ce;++j){
      const u16* hr = h + (size_t)sl[j]*(HPC*C);
      #pragma unroll
      for (int a=0;a<HPC;a++){
        float w = wl[j][a];
        if constexpr (V==4){
          uint2 u = *(const uint2*)(hr + a*C + c0);
          acc[a][0] += w*blo(u.x); acc[a][1] += w*bhi(u.x);
          acc[a][2] += w*blo(u.y); acc[a][3] += w*bhi(u.y);
        } else {
          u32 u = *(const u32*)(hr + a*C + c0);
          acc[a][0] += w*blo(u); acc[a][1] += w*bhi(u);
        }
      }
    }
    __syncthreads();
  }
  float* ar = accum + (size_t)d*C + c0;
  #pragma unroll
  for (int v=0;v<V;v++){
    float s2 = 0.f;
    #pragma unroll
    for (int a=0;a<HPC;a++) s2 += acc[a][v];
    ar[v] += s2;
  }
}
// x3 = relu(acc/8 + b[c])  (fp32 out, GAT3)
__global__ __launch_bounds__(256) void finishx(const float* __restrict__ accum,
    const float* __restrict__ bias, float* __restrict__ xo, int Cmask){
  int i = blockIdx.x*256 + threadIdx.x;
  int c = i & Cmask;
  xo[i] = fmaxf(accum[i]*0.125f + bias[c], 0.f);
}
// x2 = relu(acc/8 + b[c]) -> hi/lo only (GAT2)
__global__ __launch_bounds__(256) void finishx2(const float* __restrict__ accum,
    const float* __restrict__ bias,
    u16* __restrict__ xh, u16* __restrict__ xl, int Cmask){
  int i = blockIdx.x*256 + threadIdx.x;
  int c = i & Cmask;
  float v = fmaxf(accum[i]*0.125f + bias[c], 0.f);
  u16 h_, l_; split_bf(v, h_, l_);
  xh[i]=h_; xl[i]=l_;
}

// ---------------- pooled GCN aggregation ----------------
__global__ __launch_bounds__(256) void pool_gcn(const float* __restrict__ x3,
    const float* __restrict__ dis, const int* __restrict__ off, const int* __restrict__ csr,
    float* __restrict__ z)
{
  int g = blockIdx.x, tid = threadIdx.x;
  int c0 = tid*2;
  float a0=0.f, a1=0.f;
  for (int dd=0; dd<32; ++dd){
    int d = g*32+dd;
    int e0=off[d], e1=off[d+1];
    float b0=0.f, b1=0.f;
    for (int e=e0;e<e1;++e){
      int s = csr[e]; float ds = dis[s];
      const float* xr = x3 + (size_t)s*512 + c0;
      b0 += ds*xr[0]; b1 += ds*xr[1];
    }
    float dw = dis[d];
    a0 += dw*b0; a1 += dw*b1;
  }
  z[(size_t)g*512+c0]   = a0*(1.f/32.f);
  z[(size_t)g*512+c0+1] = a1*(1.f/32.f);
}

// ---------------- TransformerConv aggregation (bf16 qkvs, logit-cache) ----------------
__global__ __launch_bounds__(256) void tr_agg(
  const u16* __restrict__ qkvs, const int* __restrict__ off, const int* __restrict__ csr,
  float* __restrict__ xt)
{
  int d = blockIdx.x, tid = threadIdx.x;
  int wv = tid>>6, lane = tid&63;
  int e0=off[d], e1=off[d+1];
  __shared__ float osum[4][512];
  __shared__ float sp[4][64];
  float qf[8];
  { uint4 u = *(const uint4*)(qkvs + (size_t)d*6656 + wv*512 + lane*8);
    qf[0]=blo(u.x); qf[1]=bhi(u.x); qf[2]=blo(u.y); qf[3]=bhi(u.y);
    qf[4]=blo(u.z); qf[5]=bhi(u.z); qf[6]=blo(u.w); qf[7]=bhi(u.w); }
  const float scale = 0.04419417382415922f; // 1/sqrt(512)
  float m=-1e30f,l=0.f;
  for (int e=e0;e<e1;++e){
    int s = csr[e];
    uint4 u = *(const uint4*)(qkvs + (size_t)s*6656 + 2048 + wv*512 + lane*8);
    float p = qf[0]*blo(u.x)+qf[1]*bhi(u.x)+qf[2]*blo(u.y)+qf[3]*bhi(u.y)
            + qf[4]*blo(u.z)+qf[5]*bhi(u.z)+qf[6]*blo(u.w)+qf[7]*bhi(u.w);
    #pragma unroll
    for (int o=32;o;o>>=1) p += __shfl_xor(p,o);
    p *= scale;
    int idx = e-e0;
    if (lane==0 && idx<64) sp[wv][idx]=p;
    if (p>m){ l=l*__expf(m-p)+1.f; m=p; } else l+=__expf(p-m);
  }
  float li = (e1>e0)?1.f/l:0.f;
  float acc[8]={0.f,0.f,0.f,0.f,0.f,0.f,0.f,0.f};
  for (int e=e0;e<e1;++e){
    int s = csr[e];
    int idx = e-e0;
    float p;
    if (idx<64) p = sp[wv][idx];
    else {
      uint4 u = *(const uint4*)(qkvs + (size_t)s*6656 + 2048 + wv*512 + lane*8);
      p = qf[0]*blo(u.x)+qf[1]*bhi(u.x)+qf[2]*blo(u.y)+qf[3]*bhi(u.y)
        + qf[4]*blo(u.z)+qf[5]*bhi(u.z)+qf[6]*blo(u.w)+qf[7]*bhi(u.w);
      #pragma unroll
      for (int o=32;o;o>>=1) p += __shfl_xor(p,o);
      p *= scale;
    }
    float w = __expf(p - m)*li;
    uint4 u = *(const uint4*)(qkvs + (size_t)s*6656 + 4096 + wv*512 + lane*8);
    acc[0]+=w*blo(u.x); acc[1]+=w*bhi(u.x); acc[2]+=w*blo(u.y); acc[3]+=w*bhi(u.y);
    acc[4]+=w*blo(u.z); acc[5]+=w*bhi(u.z); acc[6]+=w*blo(u.w); acc[7]+=w*bhi(u.w);
  }
  #pragma unroll
  for (int j=0;j<8;j++) osum[wv][lane*8+j]=acc[j];
  __syncthreads();
  for (int c=tid;c<512;c+=256){
    u16 sk = qkvs[(size_t)d*6656 + 6144 + c];
    float o = (osum[0][c]+osum[1][c]+osum[2][c]+osum[3][c])*0.25f + blo((u32)sk);
    xt[(size_t)d*512+c] = fmaxf(o,0.f);
  }
}

// ---------------- bias concat for qkv GEMM ----------------
__global__ __launch_bounds__(256) void catb(const float* __restrict__ bq, const float* __restrict__ bk,
    const float* __restrict__ bv, const float* __restrict__ bs, float* __restrict__ o){
  int i = blockIdx.x*256 + threadIdx.x; if (i>=6656) return;
  float v;
  if (i<2048) v=bq[i]; else if (i<4096) v=bk[i-2048];
  else if (i<6144) v=bv[i-4096]; else v=bs[i-6144];
  o[i]=v;
}

// ---------------- fused head (bf16 [N,K] weights) ----------------
__device__ __forceinline__ float dotb(const u16* __restrict__ w, const float* __restrict__ s,
                                      int k0, int k1){
  float acc=0.f;
  #pragma unroll 4
  for (int k=k0;k<k1;k+=8){
    uint4 u = *(const uint4*)(w+k);
    float4 s0 = *(const float4*)(s+k);
    float4 s1 = *(const float4*)(s+k+4);
    acc += blo(u.x)*s0.x + bhi(u.x)*s0.y + blo(u.y)*s0.z + bhi(u.y)*s0.w
         + blo(u.z)*s1.x + bhi(u.z)*s1.y + blo(u.w)*s1.z + bhi(u.w)*s1.w;
  }
  return acc;
}
__global__ __launch_bounds__(256) void head_k(
  const float* __restrict__ z, const float* __restrict__ xt, const float* __restrict__ fp,
  const u16* __restrict__ gcnT, const float* __restrict__ gcn_b,
  const u16* __restrict__ fc1T, const float* __restrict__ fc1_b,
  const u16* __restrict__ fc2T, const float* __restrict__ fc2_b,
  const u16* __restrict__ b1T, const float* __restrict__ b1_b,
  const u16* __restrict__ b2T, const float* __restrict__ b2_b,
  const u16* __restrict__ b3T, const float* __restrict__ b3_b,
  const float* __restrict__ b4_w, const float* __restrict__ b4_b,
  float* __restrict__ out)
{
  int g = blockIdx.x, tid = threadIdx.x;
  __shared__ __align__(16) float xc[1024];
  __shared__ __align__(16) float sa[1504];
  __shared__ __align__(16) float sb[256];
  __shared__ __align__(16) float scm[256];
  for (int c=tid;c<512;c+=256) sa[c] = z[(size_t)g*512+c];
  __syncthreads();
  float vgcn = gcn_b[tid] + dotb(gcnT + (size_t)tid*512, sa, 0, 512);
  for (int c=tid;c<512;c+=256){
    float s=0.f;
    for (int i=0;i<32;i++) s += xt[(size_t)(g*32+i)*512 + c];
    xc[256+c] = s*(1.f/32.f);
  }
  xc[tid] = vgcn;
  __syncthreads();
  for (int c=tid;c<1496;c+=256) sa[c] = (c<1489) ? fp[(size_t)g*1489+c] : 0.f;
  __syncthreads();
  { int n = tid & 127, half = tid >> 7;
    sb[tid] = dotb(fc1T + (size_t)n*1496, sa, half?752:0, half?1496:752); }
  __syncthreads();
  if (tid<128) scm[tid] = fmaxf(sb[tid]+sb[tid+128]+fc1_b[tid], 0.f);
  __syncthreads();
  xc[768+tid] = fmaxf(fc2_b[tid] + dotb(fc2T + (size_t)tid*128, scm, 0, 128), 0.f);
  __syncthreads();
  sa[tid] = fmaxf(b1_b[tid] + dotb(b1T + (size_t)tid*1024, xc, 0, 1024), 0.f);
  __syncthreads();
  { int n = tid & 127, half = tid >> 7;
    sb[tid] = dotb(b2T + (size_t)n*256, sa, half*128, half*128+128); }
  __syncthreads();
  if (tid<128) scm[tid] = fmaxf(sb[tid]+sb[tid+128]+b2_b[tid], 0.f);
  __syncthreads();
  { int n = tid & 63, part = tid >> 6;
    sb[tid] = dotb(b3T + (size_t)n*128, scm, part*32, part*32+32); }
  __syncthreads();
  if (tid<64) sa[tid] = fmaxf(sb[tid]+sb[tid+64]+sb[tid+128]+sb[tid+192]+b3_b[tid], 0.f);
  __syncthreads();
  if (tid<64){
    float p = sa[tid]*b4_w[tid];
    #pragma unroll
    for (int o=32;o;o>>=1) p += __shfl_down(p,o);
    if (tid==0) out[g] = 1.f/(1.f+__expf(-(p + b4_b[0])));
  }
}

extern "C" void kernel_launch(void* const* d_in, const int* in_sizes, int n_in,
                              void* d_out, int out_size, void* d_ws, size_t ws_size,
                              hipStream_t stream)
{
  (void)in_sizes; (void)n_in; (void)out_size; (void)ws_size;
  const float* x     = (const float*)d_in[0];
  const float* fp    = (const float*)d_in[1];
  const int*   ei    = (const int*)d_in[2];
  const float* g1_w  = (const float*)d_in[4];
  const float* g1_as = (const float*)d_in[5];
  const float* g1_ad = (const float*)d_in[6];
  const float* g1_b  = (const float*)d_in[7];
  const float* g2_w  = (const float*)d_in[8];
  const float* g2_as = (const float*)d_in[9];
  const float* g2_ad = (const float*)d_in[10];
  const float* g2_b  = (const float*)d_in[11];
  const float* g3_w  = (const float*)d_in[12];
  const float* g3_as = (const float*)d_in[13];
  const float* g3_ad = (const float*)d_in[14];
  const float* g3_b  = (const float*)d_in[15];
  const float* gcn_w = (const float*)d_in[16];
  const float* gcn_b = (const float*)d_in[17];
  const float* t_wq  = (const float*)d_in[18];
  const float* t_wk  = (const float*)d_in[19];
  const float* t_wv  = (const float*)d_in[20];
  const float* t_bq  = (const float*)d_in[21];
  const float* t_bk  = (const float*)d_in[22];
  const float* t_bv  = (const float*)d_in[23];
  const float* t_ws  = (const float*)d_in[24];
  const float* t_bs  = (const float*)d_in[25];
  const float* fc1_w = (const float*)d_in[26];
  const float* fc1_b = (const float*)d_in[27];
  const float* fc2_w = (const float*)d_in[28];
  const float* fc2_b = (const float*)d_in[29];
  const float* b1_w  = (const float*)d_in[30];
  const float* b1_b  = (const float*)d_in[31];
  const float* b2_w  = (const float*)d_in[32];
  const float* b2_b  = (const float*)d_in[33];
  const float* b3_w  = (const float*)d_in[34];
  const float* b3_b  = (const float*)d_in[35];
  const float* b4_w  = (const float*)d_in[36];
  const float* b4_b  = (const float*)d_in[37];

  char* base = (char*)d_ws;
  size_t offb = 0;
  auto alloc = [&](size_t bytes)->void*{
    void* p = base + offb; offb = (offb + bytes + 255) & ~(size_t)255; return p;
  };
  int*   cnt   = (int*)alloc(16384*4);
  int*   off_g = (int*)alloc(4097*4);
  int*   off_t = (int*)alloc(4097*4);
  int*   csr_g = (int*)alloc(12288*4);
  int*   csr_t = (int*)alloc(8192*4);
  float* dis   = (float*)alloc(4096*4);
  float* xpad  = (float*)alloc((size_t)4096*80*4);
  u16*   xph   = (u16*)alloc((size_t)4096*96*2);
  float* alsd  = (float*)alloc((size_t)4096*16*4);
  float* wsv   = (float*)alloc((size_t)2048*8*4);
  float* wdv   = (float*)alloc((size_t)2048*8*4);
  u16*   wsTh  = (u16*)alloc((size_t)128*2048*2);
  u16*   wsTl  = (u16*)alloc((size_t)128*2048*2);
  float* zbuf  = (float*)alloc((size_t)128*512*4);
  float* cbias = (float*)alloc((size_t)6656*4);
  float* w1r   = (float*)alloc((size_t)640*2048*4);
  u16*   gcnT  = (u16*)alloc((size_t)256*512*2);
  u16*   fc1T  = (u16*)alloc((size_t)128*1496*2);
  u16*   fc2T  = (u16*)alloc((size_t)256*128*2);
  u16*   b1T   = (u16*)alloc((size_t)256*1024*2);
  u16*   b2T   = (u16*)alloc((size_t)128*256*2);
  u16*   b3T   = (u16*)alloc((size_t)64*128*2);
  char*  big   = (char*)alloc((size_t)140<<20);

  // ---- overlays (MB offsets in big) ----
  // GAT1
  u16*   y1h   = (u16*)  (big);                         // [0,5)
  u16*   y1l   = (u16*)  (big + ((size_t)5<<20));       // [5,10)
  u16*   w1rth = (u16*)  (big + ((size_t)10<<20));      // [10,13)
  u16*   x1h   = (u16*)  (big + ((size_t)16<<20));      // [16,32)
  u16*   x1l   = (u16*)  (big + ((size_t)32<<20));      // [32,48)
  // GAT2
  u16*   w2th  = (u16*)  (big + ((size_t)48<<20));      // [48,56)
  u16*   h2    = (u16*)  (big + ((size_t)56<<20));      // [56,72)
  float* acc2  = (float*)(big + ((size_t)72<<20));      // [72,88)
  u16*   x2h   = (u16*)  (big + ((size_t)88<<20));      // [88,96)
  u16*   x2l   = (u16*)  (big + ((size_t)96<<20));      // [96,104)
  // GAT3
  u16*   w3th  = (u16*)  (big + ((size_t)104<<20));     // [104,108)
  u16*   h3    = (u16*)  (big + ((size_t)108<<20));     // [108,124)
  float* acc3  = (float*)(big + ((size_t)124<<20));     // [124,132)
  float* x3    = (float*)(big + ((size_t)132<<20));     // [132,140)
  // TR phase (GAT regions [0,88) dead)
  u16*   qkvTh = (u16*)  (big);                         // [0,2)
  u16*   qkvs  = (u16*)  (big + ((size_t)8<<20));       // [8,64)  bf16 [4096][6656]
  float* xt    = (float*)(big + ((size_t)64<<20));      // [64,72)

  int* deg_g = cnt;       int* cur_g = cnt+4096;
  int* deg_t = cnt+8192;  int* cur_t = cnt+12288;

  // ---- graph prep ----
  zero_i<<<64,256,0,stream>>>(cnt, 16384);
  hist_k<<<48,256,0,stream>>>(ei, deg_g, deg_t);
  scan4096<<<1,1024,0,stream>>>(deg_g, off_g);
  scan4096<<<1,1024,0,stream>>>(deg_t, off_t);
  scatter_k<<<48,256,0,stream>>>(ei, off_g, cur_g, csr_g, off_t, cur_t, csr_t);
  mkdis<<<16,256,0,stream>>>(deg_g, dis);
  pad_x<<<4096,128,0,stream>>>(x, xpad, xph);
  repack_w1<<<5120,256,0,stream>>>(g1_w, w1r);
  // head weight transposes (bf16)
  tpd<<<dim3(8,16),256,0,stream>>>(gcn_w, 256, 0, 512, 512, gcnT);
  tpd<<<dim3(4,47),256,0,stream>>>(fc1_w, 128, 0, 1489, 1496, fc1T);
  tpd<<<dim3(8,4), 256,0,stream>>>(fc2_w, 256, 0, 128, 128, fc2T);
  tpd<<<dim3(8,32),256,0,stream>>>(b1_w,  256, 0, 1024, 1024, b1T);
  tpd<<<dim3(4,8), 256,0,stream>>>(b2_w,  128, 0, 256, 256, b2T);
  tpd<<<dim3(2,4), 256,0,stream>>>(b3_w,  64,  0, 128, 128, b3T);

  // ---- GAT1 (aggregate-first) ----
  wsvec<<<160,256,0,stream>>>(g1_w, g1_as, g1_ad, wsv, wdv, 78, 8, 2048);
  alk<<<4096,256,0,stream>>>(xpad, wsv, wdv, alsd, 80);
  gat1_gather<<<4096,256,0,stream>>>(xpad, alsd, off_g, csr_g, y1h, y1l);
  tpd<<<dim3(64,20),256,0,stream>>>(w1r, 2048, 0, 640, 640, w1rth);
  mgemm<5,1,0,float><<<dim3(16,32),256,0,stream>>>(y1h, y1l, 640, w1rth, nullptr, 640,
                                         nullptr, 2048, 640, g1_b, 0.125f, x1h, x1l);

  // ---- GAT2 ----
  wsvec<<<4096,256,0,stream>>>(g2_w, g2_as, g2_ad, wsv, wdv, 2048, 8, 1024);
  mk_wsT<<<1024,256,0,stream>>>(wsv, wdv, wsTh, wsTl, 2048);
  mgemm<4,1,1,float><<<dim3(1,32),256,0,stream>>>(x1h, x1l, 2048, wsTh, wsTl, 2048,
                                         alsd, 0, 2048, nullptr, 0.f, nullptr, nullptr);
  hipMemsetAsync(acc2, 0, (size_t)4096*1024*4, stream);
  for (int c=0;c<4;c++){
    tpd<<<dim3(64,64),256,0,stream>>>(g2_w, 8192, c*2048, 2048, 2048, w2th);
    mgemm<0,0,0,u16><<<dim3(16,32),256,0,stream>>>(x1h, nullptr, 2048, w2th, nullptr, 2048,
                                           h2, 2048, 2048, nullptr, 0.f, nullptr, nullptr);
    gat_aggN<2,1024><<<4096,256,0,stream>>>(h2, alsd, off_g, csr_g, acc2, c*2);
  }
  finishx2<<<16384,256,0,stream>>>(acc2, g2_b, x2h, x2l, 1023);

  // ---- GAT3 ----
  wsvec<<<2048,256,0,stream>>>(g3_w, g3_as, g3_ad, wsv, wdv, 1024, 8, 512);
  mk_wsT<<<512,256,0,stream>>>(wsv, wdv, wsTh, wsTl, 1024);
  mgemm<4,1,1,float><<<dim3(1,32),256,0,stream>>>(x2h, x2l, 1024, wsTh, wsTl, 1024,
                                         alsd, 0, 1024, nullptr, 0.f, nullptr, nullptr);
  hipMemsetAsync(acc3, 0, (size_t)4096*512*4, stream);
  for (int c=0;c<2;c++){
    tpd<<<dim3(64,32),256,0,stream>>>(g3_w, 4096, c*2048, 1024, 1024, w3th);
    mgemm<0,0,0,u16><<<dim3(16,32),256,0,stream>>>(x2h, nullptr, 1024, w3th, nullptr, 1024,
                                           h3, 2048, 1024, nullptr, 0.f, nullptr, nullptr);
    gat_aggN<4,512><<<4096,256,0,stream>>>(h3, alsd, off_g, csr_g, acc3, c*4);
  }
  finishx<<<8192,256,0,stream>>>(acc3, g3_b, x3, 511);
  pool_gcn<<<128,256,0,stream>>>(x3, dis, off_g, csr_g, zbuf);

  // ---- Transformer branch ----
  tpd<<<dim3(64,3),256,0,stream>>>(t_wq, 2048, 0, 78, 96, qkvTh);
  tpd<<<dim3(64,3),256,0,stream>>>(t_wk, 2048, 0, 78, 96, qkvTh + (size_t)2048*96);
  tpd<<<dim3(64,3),256,0,stream>>>(t_wv, 2048, 0, 78, 96, qkvTh + (size_t)4096*96);
  tpd<<<dim3(16,3),256,0,stream>>>(t_ws, 512,  0, 78, 96, qkvTh + (size_t)6144*96);
  catb<<<26,256,0,stream>>>(t_bq, t_bk, t_bv, t_bs, cbias);
  mgemm<1,0,0,u16><<<dim3(52,32),256,0,stream>>>(xph, nullptr, 96, qkvTh, nullptr, 96,
                                         qkvs, 6656, 96, cbias, 0.f, nullptr, nullptr);
  tr_agg<<<4096,256,0,stream>>>(qkvs, off_t, csr_t, xt);

  // ---- fused head ----
  head_k<<<128,256,0,stream>>>(zbuf, xt, fp, gcnT, gcn_b,
                               fc1T, fc1_b, fc2T, fc2_b,
                               b1T, b1_b, b2T, b2_b, b3T, b3_b, b4_w, b4_b,
                               (float*)d_out);
}

// Round 7
// 784.812 us; speedup vs baseline: 7.0938x; 1.2068x over previous
//
#include <hip/hip_runtime.h>

typedef unsigned short u16;
typedef unsigned int   u32;

typedef __bf16 bf16x8 __attribute__((ext_vector_type(8)));
typedef float  f32x4  __attribute__((ext_vector_type(4)));

#define NNODE 4096
#define NEDGE 8192
#define NEG   12288   /* edges incl self-loops */

__device__ __forceinline__ float blo(u32 u){ return __uint_as_float(u<<16); }
__device__ __forceinline__ float bhi(u32 u){ return __uint_as_float(u & 0xffff0000u); }
__device__ __forceinline__ u16 f2b(float f){
  u32 u = __float_as_uint(f);
  u += 0x7fffu + ((u>>16)&1u);
  return (u16)(u>>16);
}
__device__ __forceinline__ void split_bf(float a, u16& hi, u16& lo){
  u32 u = __float_as_uint(a);
  u32 r = u + 0x7fffu + ((u>>16)&1u);
  hi = (u16)(r>>16);
  float h = __uint_as_float(r & 0xffff0000u);
  float l = a - h;
  u32 u2 = __float_as_uint(l);
  lo = (u16)((u2 + 0x7fffu + ((u2>>16)&1u)) >> 16);
}
__device__ __forceinline__ u16 hi_bf(float a){
  u32 u = __float_as_uint(a);
  return (u16)((u + 0x7fffu + ((u>>16)&1u)) >> 16);
}

#define GL2LDS(g,l) __builtin_amdgcn_global_load_lds((const __attribute__((address_space(1))) unsigned int*)(g), (__attribute__((address_space(3))) unsigned int*)(l), 16, 0, 0)

// ---------------- graph prep ----------------
__global__ __launch_bounds__(256) void zero_i(int* p, int n){
  int i = blockIdx.x*256 + threadIdx.x; if (i<n) p[i]=0;
}
__global__ __launch_bounds__(256) void hist_k(const int* __restrict__ ei, int* deg_g, int* deg_t){
  int e = blockIdx.x*256 + threadIdx.x; if (e>=NEG) return;
  int dv = (e<NEDGE) ? ei[NEDGE+e] : e-NEDGE;
  atomicAdd(&deg_g[dv],1);
  if (e<NEDGE) atomicAdd(&deg_t[dv],1);
}
__global__ __launch_bounds__(1024) void scan4096(const int* __restrict__ deg, int* __restrict__ off){
  __shared__ int lds[1024];
  int tid = threadIdx.x;
  int v[4]; int s=0;
  #pragma unroll
  for (int j=0;j<4;j++){ v[j]=deg[tid*4+j]; s+=v[j]; }
  lds[tid]=s; __syncthreads();
  for (int d=1; d<1024; d<<=1){
    int t = (tid>=d) ? lds[tid-d] : 0;
    __syncthreads();
    lds[tid] += t;
    __syncthreads();
  }
  int base = (tid>0) ? lds[tid-1] : 0;
  #pragma unroll
  for (int j=0;j<4;j++){ off[tid*4+j]=base; base+=v[j]; }
  if (tid==1023) off[4096]=base;
}
__global__ __launch_bounds__(256) void scatter_k(const int* __restrict__ ei,
    const int* __restrict__ off_g, int* cur_g, int* csr_g,
    const int* __restrict__ off_t, int* cur_t, int* csr_t){
  int e = blockIdx.x*256 + threadIdx.x; if (e>=NEG) return;
  int s, dv;
  if (e<NEDGE){ s=ei[e]; dv=ei[NEDGE+e]; } else { s=dv=e-NEDGE; }
  int p = atomicAdd(&cur_g[dv],1);
  csr_g[off_g[dv]+p]=s;
  if (e<NEDGE){ int p2 = atomicAdd(&cur_t[dv],1); csr_t[off_t[dv]+p2]=s; }
}
__global__ __launch_bounds__(256) void mkdis(const int* __restrict__ deg, float* dis){
  int i = blockIdx.x*256 + threadIdx.x; if (i>=NNODE) return;
  int d = deg[i]; dis[i] = d>0 ? rsqrtf((float)d) : 0.f;
}
// xpad fp32 [n][80] + xph bf16-hi [n][96]
__global__ __launch_bounds__(128) void pad_x(const float* __restrict__ x, float* __restrict__ xp,
                                             u16* __restrict__ xh){
  int n = blockIdx.x, c = threadIdx.x;
  if (c<96){
    float v = (c<78) ? x[(size_t)n*78+c] : 0.f;
    if (c<80) xp[(size_t)n*80+c] = v;
    xh[(size_t)n*96+c] = hi_bf(v);
  }
}
// W1r[(h*80+k), c] = g1_w[k, h*2048+c], zero-padded k>=78
__global__ __launch_bounds__(256) void repack_w1(const float* __restrict__ g1w, float* __restrict__ w1r){
  int i = blockIdx.x*256 + threadIdx.x;   // 640*2048
  int kk = i >> 11, c = i & 2047;
  int h = kk/80, k2 = kk - h*80;
  w1r[i] = (k2<78) ? g1w[(size_t)k2*16384 + h*2048 + c] : 0.f;
}

// ---------------- transpose + bf16(hi): W[K,Ntot] cols [n0,n0+Nw) -> hi [Nw,Kp] ----------------
__global__ __launch_bounds__(256) void tpd(const float* __restrict__ in, int Ntot, int n0,
    int K, int Kp, u16* __restrict__ outh){
  __shared__ float t[32][33];
  int bx = blockIdx.x*32;   // n in window
  int by = blockIdx.y*32;   // k
  int tx = threadIdx.x & 31, ty = threadIdx.x >> 5;
  for (int i=ty;i<32;i+=8){
    int kk=by+i;
    t[i][tx] = (kk<K) ? in[(size_t)kk*Ntot + n0 + bx + tx] : 0.f;
  }
  __syncthreads();
  for (int i=ty;i<32;i+=8){
    int nn=bx+i, kk=by+tx;
    if (kk<Kp) outh[(size_t)nn*Kp+kk] = hi_bf(t[tx][i]);
  }
}

// ---------------- attention-table pack: [16][Kp] rows 0..7 = ws heads, 8..15 = wd ----------------
__global__ __launch_bounds__(256) void mk_wsT(const float* __restrict__ wsv, const float* __restrict__ wdv,
    u16* __restrict__ th, u16* __restrict__ tl, int Kp){
  int i = blockIdx.x*256 + threadIdx.x;   // over 16*Kp
  if (i >= 16*Kp) return;
  int r = i / Kp, k = i - r*Kp;
  float v = (r<8) ? wsv[k*8+r] : wdv[k*8+(r-8)];
  u16 h,l; split_bf(v,h,l);
  th[i]=h; tl[i]=l;
}

// ---------------- K-split logits GEMM: alsd[4096][16] += (Ah+Al) * (Bh+Bl)^T ----------------
template<int KS>
__global__ __launch_bounds__(256,2) void alk_mm(
    const u16* __restrict__ Ah, const u16* __restrict__ Al, int lda,
    const u16* __restrict__ Bh, const u16* __restrict__ Bl,
    float* __restrict__ alsd, int K)
{
  __shared__ __align__(16) u16 Ash[128*32], Asl[128*32], Bsh[16*32], Bsl[16*32];
  int tid = threadIdx.x, lane = tid & 63, wave = tid >> 6;
  int bm = blockIdx.y*128;
  int kb = blockIdx.x*(K/KS), ke = kb + K/KS;
  int m16 = lane & 15, quad = lane >> 4;
  int srow = lane >> 2, skk = (lane & 3) * 8;
  f32x4 acc[2] = {};
  for (int k0=kb; k0<ke; k0+=32){
    __syncthreads();
    #pragma unroll
    for (int t=0;t<2;t++){
      int g = wave + t*4; int row = g*16 + srow;
      GL2LDS(Ah + (size_t)(bm+row)*lda + k0 + skk, &Ash[g*512]);
      GL2LDS(Al + (size_t)(bm+row)*lda + k0 + skk, &Asl[g*512]);
    }
    if (wave==0) GL2LDS(Bh + (size_t)srow*lda + k0 + skk, &Bsh[0]);
    if (wave==1) GL2LDS(Bl + (size_t)srow*lda + k0 + skk, &Bsl[0]);
    __syncthreads();
    int kq = quad*8;
    bf16x8 bh = *(const bf16x8*)&Bsh[m16*32+kq];
    bf16x8 bl = *(const bf16x8*)&Bsl[m16*32+kq];
    #pragma unroll
    for (int i=0;i<2;i++){
      bf16x8 ah = *(const bf16x8*)&Ash[(wave*32+i*16+m16)*32+kq];
      bf16x8 al = *(const bf16x8*)&Asl[(wave*32+i*16+m16)*32+kq];
      acc[i] = __builtin_amdgcn_mfma_f32_16x16x32_bf16(ah, bh, acc[i],0,0,0);
      acc[i] = __builtin_amdgcn_mfma_f32_16x16x32_bf16(al, bh, acc[i],0,0,0);
      acc[i] = __builtin_amdgcn_mfma_f32_16x16x32_bf16(ah, bl, acc[i],0,0,0);
    }
  }
  #pragma unroll
  for (int i=0;i<2;i++){
    int row0 = bm + wave*32 + i*16 + quad*4;
    #pragma unroll
    for (int r=0;r<4;r++)
      atomicAdd(&alsd[(size_t)(row0+r)*16 + m16], acc[i][r]);
  }
}

// ---------------- MFMA GEMM (m97 staging): C = (Ah[+Al]) * Bh^T ----------------
// EPI: 0 plain CT store, 1 +bias CT store, 5 relu(scale*acc+bias) -> split hi/lo only
#define BM 128
#define BN 128
template<int EPI, int SA, typename CT>
__global__ __launch_bounds__(256,2) void mgemm(
    const u16* __restrict__ Ah, const u16* __restrict__ Al, int lda,
    const u16* __restrict__ Bh, int ldb,
    CT* __restrict__ C, int ldc, int K,
    const float* __restrict__ bias, float scale,
    u16* __restrict__ Chi, u16* __restrict__ Clo)
{
  __shared__ __align__(16) u16 Ash[128*32];
  __shared__ __align__(16) u16 Bsh[128*32];
  __shared__ __align__(16) u16 Asl[SA?128*32:16];
  int tid = threadIdx.x;
  int bm = blockIdx.y*BM, bn = blockIdx.x*BN;
  int lane = tid & 63, wave = tid >> 6;
  int wr = (wave>>1)*64, wc = (wave&1)*64;
  int m16 = lane & 15, quad = lane >> 4;
  int srow = lane >> 2;
  int skk  = (lane & 3) * 8;

  f32x4 acc[4][4] = {};
  for (int k0=0; k0<K; k0+=32){
    __syncthreads();
    #pragma unroll
    for (int t=0;t<2;t++){
      int g = wave + t*4;
      int row = g*16 + srow;
      GL2LDS(Ah + (size_t)(bm+row)*lda + k0 + skk, &Ash[g*512]);
      if (SA) GL2LDS(Al + (size_t)(bm+row)*lda + k0 + skk, &Asl[g*512]);
      GL2LDS(Bh + (size_t)(bn+row)*ldb + k0 + skk, &Bsh[g*512]);
    }
    __syncthreads();
    int kq = quad*8;
    bf16x8 ah[4], al_[4], bh_[4];
    #pragma unroll
    for (int i=0;i<4;i++){
      ah[i]  = *(const bf16x8*)&Ash[(wr+i*16+m16)*32 + kq];
      if (SA) al_[i] = *(const bf16x8*)&Asl[(wr+i*16+m16)*32 + kq];
    }
    #pragma unroll
    for (int j=0;j<4;j++)
      bh_[j] = *(const bf16x8*)&Bsh[(wc+j*16+m16)*32 + kq];
    #pragma unroll
    for (int i=0;i<4;i++)
      #pragma unroll
      for (int j=0;j<4;j++){
        acc[i][j] = __builtin_amdgcn_mfma_f32_16x16x32_bf16(ah[i], bh_[j], acc[i][j], 0,0,0);
        if (SA) acc[i][j] = __builtin_amdgcn_mfma_f32_16x16x32_bf16(al_[i], bh_[j], acc[i][j], 0,0,0);
      }
  }
  #pragma unroll
  for (int i=0;i<4;i++){
    int row0 = bm + wr + i*16 + quad*4;
    #pragma unroll
    for (int j=0;j<4;j++){
      int col = bn + wc + j*16 + m16;
      float bv = (EPI==1||EPI==5) ? bias[col] : 0.f;
      #pragma unroll
      for (int r=0;r<4;r++){
        float v = acc[i][j][r];
        if constexpr (EPI==5){
          v = fmaxf(v*scale + bv, 0.f);
          size_t idx = (size_t)(row0+r)*ldc + col;
          u16 h_, l_; split_bf(v, h_, l_);
          Chi[idx]=h_; Clo[idx]=l_;
        } else {
          if (EPI==1) v += bv;
          size_t idx = (size_t)(row0+r)*ldc + col;
          if constexpr (sizeof(CT)==2) C[idx] = (CT)f2b(v);
          else C[idx] = (CT)v;
        }
      }
    }
  }
}

// ---------------- GAT attention-vector precompute ----------------
__global__ __launch_bounds__(256) void wsvec(const float* __restrict__ W,
    const float* __restrict__ as_, const float* __restrict__ ad_,
    float* __restrict__ ws, float* __restrict__ wd,
    int Kreal, int H, int C)
{
  int wv = blockIdx.x*4 + (threadIdx.x>>6);
  int lane = threadIdx.x & 63;
  int k = wv / H, h = wv - k*H;
  float ps=0.f, pd=0.f;
  if (k < Kreal){
    const float* wr = W + (size_t)k*((size_t)H*C) + (size_t)h*C;
    const float* ar = as_ + (size_t)h*C;
    const float* dr = ad_ + (size_t)h*C;
    for (int c=lane;c<C;c+=64){ float w=wr[c]; ps += w*ar[c]; pd += w*dr[c]; }
  }
  #pragma unroll
  for (int o=32;o;o>>=1){ ps += __shfl_down(ps,o); pd += __shfl_down(pd,o); }
  if (lane==0){ ws[k*H+h]=ps; wd[k*H+h]=pd; }
}
// GAT1 logits (Kp=80), writes alsd[n][16] = [als(8) | ald(8)]
__global__ __launch_bounds__(256) void alk(const float* __restrict__ X,
    const float* __restrict__ ws, const float* __restrict__ wd,
    float* __restrict__ alsd, int Kp)
{
  int n = blockIdx.x, tid = threadIdx.x;
  int hh = tid>>5, l32 = tid&31;
  const float* xr = X + (size_t)n*Kp;
  float ps=0.f, pd=0.f;
  for (int k=l32;k<Kp;k+=32){
    float xv = xr[k];
    ps += xv*ws[k*8+hh];
    pd += xv*wd[k*8+hh];
  }
  #pragma unroll
  for (int o=16;o;o>>=1){ ps += __shfl_down(ps,o,32); pd += __shfl_down(pd,o,32); }
  if (l32==0){ alsd[n*16+hh]=ps; alsd[n*16+8+hh]=pd; }
}

// ---------------- GAT1 aggregate-first gather (emits hi/lo) ----------------
__global__ __launch_bounds__(256) void gat1_gather(
    const float* __restrict__ xpad, const float* __restrict__ alsd,
    const int* __restrict__ off, const int* __restrict__ csr,
    u16* __restrict__ y1h, u16* __restrict__ y1l)
{
  int d = blockIdx.x, tid = threadIdx.x;
  int hh = tid>>5, l32 = tid&31;
  int e0 = off[d], e1 = off[d+1];
  __shared__ float mh[8], lih[8], adh[8];
  __shared__ float wl[32][8];
  __shared__ int sl[32];
  if (tid < 8){
    float ad = alsd[d*16+8+tid]; adh[tid]=ad;
    float m=-1e30f, l=0.f;
    for (int e=e0;e<e1;++e){
      float xv = alsd[csr[e]*16+tid] + ad;
      xv = xv>0.f?xv:0.2f*xv;
      if (xv>m){ l = l*__expf(m-xv)+1.f; m=xv; } else l += __expf(xv-m);
    }
    mh[tid]=m; lih[tid]=1.f/l;
  }
  __syncthreads();
  float acc0=0.f, acc1=0.f, acc2v=0.f;
  for (int cb=e0; cb<e1; cb+=32){
    int ce = min(32, e1-cb);
    if (tid < ce*8){
      int j = tid>>3, h2 = tid&7;
      int s = csr[cb+j];
      if (h2==0) sl[j]=s;
      float xv = alsd[s*16+h2] + adh[h2];
      xv = xv>0.f?xv:0.2f*xv;
      wl[j][h2] = __expf(xv-mh[h2])*lih[h2];
    }
    __syncthreads();
    for (int j=0;j<ce;++j){
      float w = wl[j][hh];
      const float* xr = xpad + (size_t)sl[j]*80;
      acc0 += w*xr[l32];
      acc1 += w*xr[l32+32];
      if (l32 < 16) acc2v += w*xr[l32+64];
    }
    __syncthreads();
  }
  size_t base = (size_t)d*640 + hh*80;
  u16 h_, l_;
  split_bf(acc0, h_, l_); y1h[base+l32]=h_;    y1l[base+l32]=l_;
  split_bf(acc1, h_, l_); y1h[base+l32+32]=h_; y1l[base+l32+32]=l_;
  if (l32<16){ split_bf(acc2v, h_, l_); y1h[base+l32+64]=h_; y1l[base+l32+64]=l_; }
}

// ---------------- all-head chunk aggregation (bf16 h, alsd layout) ----------------
template<int HPC, int C>
__global__ __launch_bounds__(256) void gat_aggN(
    const u16* __restrict__ h, const float* __restrict__ alsd,
    const int* __restrict__ off, const int* __restrict__ csr,
    float* __restrict__ accum, int head0)
{
  constexpr int V = C/256;
  int d = blockIdx.x, tid = threadIdx.x;
  int e0=off[d], e1=off[d+1];
  __shared__ float mh[HPC], lih[HPC], adh[HPC];
  __shared__ float wl[32][HPC];
  __shared__ int sl[32];
  if (tid < HPC){
    float ad = alsd[d*16 + 8 + head0 + tid]; adh[tid]=ad;
    float m=-1e30f,l=0.f;
    for (int e=e0;e<e1;++e){
      float xv = alsd[csr[e]*16 + head0 + tid]+ad;
      xv = xv>0.f?xv:0.2f*xv;
      if (xv>m){ l=l*__expf(m-xv)+1.f; m=xv; } else l+=__expf(xv-m);
    }
    mh[tid]=m; lih[tid]=1.f/l;
  }
  __syncthreads();
  float acc[HPC][V];
  #pragma unroll
  for (int a=0;a<HPC;a++)
    #pragma unroll
    for (int v=0;v<V;v++) acc[a][v]=0.f;
  int c0 = tid*V;
  for (int cb=e0;cb<e1;cb+=32){
    int ce = min(32, e1-cb);
    if (tid < ce*HPC){
      int j = tid/HPC, h2 = tid - j*HPC;
      int s = csr[cb+j];
      if (h2==0) sl[j]=s;
      float xv = alsd[s*16 + head0 + h2] + adh[h2];
      xv = xv>0.f?xv:0.2f*xv;
      wl[j][h2] = __expf(xv-mh[h2])*lih[h2];
    }
    __syncthreads();
    for (int j=0;j<ce;++j){
      const u16* hr = h + (size_t)sl[j]*(HPC*C);
      #pragma unroll
      for (int a=0;a<HPC;a++){
        float w = wl[j][a];
        if constexpr (V==4){
          uint2 u = *(const uint2*)(hr + a*C + c0);
          acc[a][0] += w*blo(u.x); acc[a][1] += w*bhi(u.x);
          acc[a][2] += w*blo(u.y); acc[a][3] += w*bhi(u.y);
        } else {
          u32 u = *(const u32*)(hr + a*C + c0);
          acc[a][0] += w*blo(u); acc[a][1] += w*bhi(u);
        }
      }
    }
    __syncthreads();
  }
  float* ar = accum + (size_t)d*C + c0;
  #pragma unroll
  for (int v=0;v<V;v++){
    float s2 = 0.f;
    #pragma unroll
    for (int a=0;a<HPC;a++) s2 += acc[a][v];
    ar[v] += s2;
  }
}
// x3 = relu(acc/8 + b[c])  (fp32 out, GAT3)
__global__ __launch_bounds__(256) void finishx(const float* __restrict__ accum,
    const float* __restrict__ bias, float* __restrict__ xo, int Cmask){
  int i = blockIdx.x*256 + threadIdx.x;
  int c = i & Cmask;
  xo[i] = fmaxf(accum[i]*0.125f + bias[c], 0.f);
}
// x2 = relu(acc/8 + b[c]) -> hi/lo only (GAT2)
__global__ __launch_bounds__(256) void finishx2(const float* __restrict__ accum,
    const float* __restrict__ bias,
    u16* __restrict__ xh, u16* __restrict__ xl, int Cmask){
  int i = blockIdx.x*256 + threadIdx.x;
  int c = i & Cmask;
  float v = fmaxf(accum[i]*0.125f + bias[c], 0.f);
  u16 h_, l_; split_bf(v, h_, l_);
  xh[i]=h_; xl[i]=l_;
}

// ---------------- pooled GCN aggregation ----------------
__global__ __launch_bounds__(256) void pool_gcn(const float* __restrict__ x3,
    const float* __restrict__ dis, const int* __restrict__ off, const int* __restrict__ csr,
    float* __restrict__ z)
{
  int g = blockIdx.x, tid = threadIdx.x;
  int c0 = tid*2;
  float a0=0.f, a1=0.f;
  for (int dd=0; dd<32; ++dd){
    int d = g*32+dd;
    int e0=off[d], e1=off[d+1];
    float b0=0.f, b1=0.f;
    for (int e=e0;e<e1;++e){
      int s = csr[e]; float ds = dis[s];
      const float* xr = x3 + (size_t)s*512 + c0;
      b0 += ds*xr[0]; b1 += ds*xr[1];
    }
    float dw = dis[d];
    a0 += dw*b0; a1 += dw*b1;
  }
  z[(size_t)g*512+c0]   = a0*(1.f/32.f);
  z[(size_t)g*512+c0+1] = a1*(1.f/32.f);
}

// ---------------- TransformerConv aggregation (bf16 qkvs, logit-cache) ----------------
__global__ __launch_bounds__(256) void tr_agg(
  const u16* __restrict__ qkvs, const int* __restrict__ off, const int* __restrict__ csr,
  float* __restrict__ xt)
{
  int d = blockIdx.x, tid = threadIdx.x;
  int wv = tid>>6, lane = tid&63;
  int e0=off[d], e1=off[d+1];
  __shared__ float osum[4][512];
  __shared__ float sp[4][64];
  float qf[8];
  { uint4 u = *(const uint4*)(qkvs + (size_t)d*6656 + wv*512 + lane*8);
    qf[0]=blo(u.x); qf[1]=bhi(u.x); qf[2]=blo(u.y); qf[3]=bhi(u.y);
    qf[4]=blo(u.z); qf[5]=bhi(u.z); qf[6]=blo(u.w); qf[7]=bhi(u.w); }
  const float scale = 0.04419417382415922f; // 1/sqrt(512)
  float m=-1e30f,l=0.f;
  for (int e=e0;e<e1;++e){
    int s = csr[e];
    uint4 u = *(const uint4*)(qkvs + (size_t)s*6656 + 2048 + wv*512 + lane*8);
    float p = qf[0]*blo(u.x)+qf[1]*bhi(u.x)+qf[2]*blo(u.y)+qf[3]*bhi(u.y)
            + qf[4]*blo(u.z)+qf[5]*bhi(u.z)+qf[6]*blo(u.w)+qf[7]*bhi(u.w);
    #pragma unroll
    for (int o=32;o;o>>=1) p += __shfl_xor(p,o);
    p *= scale;
    int idx = e-e0;
    if (lane==0 && idx<64) sp[wv][idx]=p;
    if (p>m){ l=l*__expf(m-p)+1.f; m=p; } else l+=__expf(p-m);
  }
  float li = (e1>e0)?1.f/l:0.f;
  float acc[8]={0.f,0.f,0.f,0.f,0.f,0.f,0.f,0.f};
  for (int e=e0;e<e1;++e){
    int s = csr[e];
    int idx = e-e0;
    float p;
    if (idx<64) p = sp[wv][idx];
    else {
      uint4 u = *(const uint4*)(qkvs + (size_t)s*6656 + 2048 + wv*512 + lane*8);
      p = qf[0]*blo(u.x)+qf[1]*bhi(u.x)+qf[2]*blo(u.y)+qf[3]*bhi(u.y)
        + qf[4]*blo(u.z)+qf[5]*bhi(u.z)+qf[6]*blo(u.w)+qf[7]*bhi(u.w);
      #pragma unroll
      for (int o=32;o;o>>=1) p += __shfl_xor(p,o);
      p *= scale;
    }
    float w = __expf(p - m)*li;
    uint4 u = *(const uint4*)(qkvs + (size_t)s*6656 + 4096 + wv*512 + lane*8);
    acc[0]+=w*blo(u.x); acc[1]+=w*bhi(u.x); acc[2]+=w*blo(u.y); acc[3]+=w*bhi(u.y);
    acc[4]+=w*blo(u.z); acc[5]+=w*bhi(u.z); acc[6]+=w*blo(u.w); acc[7]+=w*bhi(u.w);
  }
  #pragma unroll
  for (int j=0;j<8;j++) osum[wv][lane*8+j]=acc[j];
  __syncthreads();
  for (int c=tid;c<512;c+=256){
    u16 sk = qkvs[(size_t)d*6656 + 6144 + c];
    float o = (osum[0][c]+osum[1][c]+osum[2][c]+osum[3][c])*0.25f + blo((u32)sk);
    xt[(size_t)d*512+c] = fmaxf(o,0.f);
  }
}

// ---------------- bias concat for qkv GEMM ----------------
__global__ __launch_bounds__(256) void catb(const float* __restrict__ bq, const float* __restrict__ bk,
    const float* __restrict__ bv, const float* __restrict__ bs, float* __restrict__ o){
  int i = blockIdx.x*256 + threadIdx.x; if (i>=6656) return;
  float v;
  if (i<2048) v=bq[i]; else if (i<4096) v=bk[i-2048];
  else if (i<6144) v=bv[i-4096]; else v=bs[i-6144];
  o[i]=v;
}

// ---------------- fused head (bf16 [N,K] weights) ----------------
__device__ __forceinline__ float dotb(const u16* __restrict__ w, const float* __restrict__ s,
                                      int k0, int k1){
  float acc=0.f;
  #pragma unroll 4
  for (int k=k0;k<k1;k+=8){
    uint4 u = *(const uint4*)(w+k);
    float4 s0 = *(const float4*)(s+k);
    float4 s1 = *(const float4*)(s+k+4);
    acc += blo(u.x)*s0.x + bhi(u.x)*s0.y + blo(u.y)*s0.z + bhi(u.y)*s0.w
         + blo(u.z)*s1.x + bhi(u.z)*s1.y + blo(u.w)*s1.z + bhi(u.w)*s1.w;
  }
  return acc;
}
__global__ __launch_bounds__(256) void head_k(
  const float* __restrict__ z, const float* __restrict__ xt, const float* __restrict__ fp,
  const u16* __restrict__ gcnT, const float* __restrict__ gcn_b,
  const u16* __restrict__ fc1T, const float* __restrict__ fc1_b,
  const u16* __restrict__ fc2T, const float* __restrict__ fc2_b,
  const u16* __restrict__ b1T, const float* __restrict__ b1_b,
  const u16* __restrict__ b2T, const float* __restrict__ b2_b,
  const u16* __restrict__ b3T, const float* __restrict__ b3_b,
  const float* __restrict__ b4_w, const float* __restrict__ b4_b,
  float* __restrict__ out)
{
  int g = blockIdx.x, tid = threadIdx.x;
  __shared__ __align__(16) float xc[1024];
  __shared__ __align__(16) float sa[1504];
  __shared__ __align__(16) float sb[256];
  __shared__ __align__(16) float scm[256];
  for (int c=tid;c<512;c+=256) sa[c] = z[(size_t)g*512+c];
  __syncthreads();
  float vgcn = gcn_b[tid] + dotb(gcnT + (size_t)tid*512, sa, 0, 512);
  for (int c=tid;c<512;c+=256){
    float s=0.f;
    for (int i=0;i<32;i++) s += xt[(size_t)(g*32+i)*512 + c];
    xc[256+c] = s*(1.f/32.f);
  }
  xc[tid] = vgcn;
  __syncthreads();
  for (int c=tid;c<1496;c+=256) sa[c] = (c<1489) ? fp[(size_t)g*1489+c] : 0.f;
  __syncthreads();
  { int n = tid & 127, half = tid >> 7;
    sb[tid] = dotb(fc1T + (size_t)n*1496, sa, half?752:0, half?1496:752); }
  __syncthreads();
  if (tid<128) scm[tid] = fmaxf(sb[tid]+sb[tid+128]+fc1_b[tid], 0.f);
  __syncthreads();
  xc[768+tid] = fmaxf(fc2_b[tid] + dotb(fc2T + (size_t)tid*128, scm, 0, 128), 0.f);
  __syncthreads();
  sa[tid] = fmaxf(b1_b[tid] + dotb(b1T + (size_t)tid*1024, xc, 0, 1024), 0.f);
  __syncthreads();
  { int n = tid & 127, half = tid >> 7;
    sb[tid] = dotb(b2T + (size_t)n*256, sa, half*128, half*128+128); }
  __syncthreads();
  if (tid<128) scm[tid] = fmaxf(sb[tid]+sb[tid+128]+b2_b[tid], 0.f);
  __syncthreads();
  { int n = tid & 63, part = tid >> 6;
    sb[tid] = dotb(b3T + (size_t)n*128, scm, part*32, part*32+32); }
  __syncthreads();
  if (tid<64) sa[tid] = fmaxf(sb[tid]+sb[tid+64]+sb[tid+128]+sb[tid+192]+b3_b[tid], 0.f);
  __syncthreads();
  if (tid<64){
    float p = sa[tid]*b4_w[tid];
    #pragma unroll
    for (int o=32;o;o>>=1) p += __shfl_down(p,o);
    if (tid==0) out[g] = 1.f/(1.f+__expf(-(p + b4_b[0])));
  }
}

extern "C" void kernel_launch(void* const* d_in, const int* in_sizes, int n_in,
                              void* d_out, int out_size, void* d_ws, size_t ws_size,
                              hipStream_t stream)
{
  (void)in_sizes; (void)n_in; (void)out_size; (void)ws_size;
  const float* x     = (const float*)d_in[0];
  const float* fp    = (const float*)d_in[1];
  const int*   ei    = (const int*)d_in[2];
  const float* g1_w  = (const float*)d_in[4];
  const float* g1_as = (const float*)d_in[5];
  const float* g1_ad = (const float*)d_in[6];
  const float* g1_b  = (const float*)d_in[7];
  const float* g2_w  = (const float*)d_in[8];
  const float* g2_as = (const float*)d_in[9];
  const float* g2_ad = (const float*)d_in[10];
  const float* g2_b  = (const float*)d_in[11];
  const float* g3_w  = (const float*)d_in[12];
  const float* g3_as = (const float*)d_in[13];
  const float* g3_ad = (const float*)d_in[14];
  const float* g3_b  = (const float*)d_in[15];
  const float* gcn_w = (const float*)d_in[16];
  const float* gcn_b = (const float*)d_in[17];
  const float* t_wq  = (const float*)d_in[18];
  const float* t_wk  = (const float*)d_in[19];
  const float* t_wv  = (const float*)d_in[20];
  const float* t_bq  = (const float*)d_in[21];
  const float* t_bk  = (const float*)d_in[22];
  const float* t_bv  = (const float*)d_in[23];
  const float* t_ws  = (const float*)d_in[24];
  const float* t_bs  = (const float*)d_in[25];
  const float* fc1_w = (const float*)d_in[26];
  const float* fc1_b = (const float*)d_in[27];
  const float* fc2_w = (const float*)d_in[28];
  const float* fc2_b = (const float*)d_in[29];
  const float* b1_w  = (const float*)d_in[30];
  const float* b1_b  = (const float*)d_in[31];
  const float* b2_w  = (const float*)d_in[32];
  const float* b2_b  = (const float*)d_in[33];
  const float* b3_w  = (const float*)d_in[34];
  const float* b3_b  = (const float*)d_in[35];
  const float* b4_w  = (const float*)d_in[36];
  const float* b4_b  = (const float*)d_in[37];

  char* base = (char*)d_ws;
  size_t offb = 0;
  auto alloc = [&](size_t bytes)->void*{
    void* p = base + offb; offb = (offb + bytes + 255) & ~(size_t)255; return p;
  };
  int*   cnt   = (int*)alloc(16384*4);
  int*   off_g = (int*)alloc(4097*4);
  int*   off_t = (int*)alloc(4097*4);
  int*   csr_g = (int*)alloc(12288*4);
  int*   csr_t = (int*)alloc(8192*4);
  float* dis   = (float*)alloc(4096*4);
  float* xpad  = (float*)alloc((size_t)4096*80*4);
  u16*   xph   = (u16*)alloc((size_t)4096*96*2);
  float* alsd  = (float*)alloc((size_t)4096*16*4);
  float* wsv   = (float*)alloc((size_t)2048*8*4);
  float* wdv   = (float*)alloc((size_t)2048*8*4);
  u16*   wsTh  = (u16*)alloc((size_t)16*2048*2);
  u16*   wsTl  = (u16*)alloc((size_t)16*2048*2);
  float* zbuf  = (float*)alloc((size_t)128*512*4);
  float* cbias = (float*)alloc((size_t)6656*4);
  float* w1r   = (float*)alloc((size_t)640*2048*4);
  u16*   gcnT  = (u16*)alloc((size_t)256*512*2);
  u16*   fc1T  = (u16*)alloc((size_t)128*1496*2);
  u16*   fc2T  = (u16*)alloc((size_t)256*128*2);
  u16*   b1T   = (u16*)alloc((size_t)256*1024*2);
  u16*   b2T   = (u16*)alloc((size_t)128*256*2);
  u16*   b3T   = (u16*)alloc((size_t)64*128*2);
  char*  big   = (char*)alloc((size_t)140<<20);

  // ---- overlays (MB offsets in big) ----
  // GAT1
  u16*   y1h   = (u16*)  (big);                         // [0,5)
  u16*   y1l   = (u16*)  (big + ((size_t)5<<20));       // [5,10)
  u16*   w1rth = (u16*)  (big + ((size_t)10<<20));      // [10,13)
  u16*   x1h   = (u16*)  (big + ((size_t)16<<20));      // [16,32)
  u16*   x1l   = (u16*)  (big + ((size_t)32<<20));      // [32,48)
  // GAT2
  u16*   w2th  = (u16*)  (big + ((size_t)48<<20));      // [48,64)  [4096][2048] bf16
  u16*   h2    = (u16*)  (big + ((size_t)64<<20));      // [64,96)  [4096][4096] bf16
  float* acc2  = (float*)(big + ((size_t)96<<20));      // [96,112)
  u16*   x2h   = (u16*)  (big + ((size_t)112<<20));     // [112,120)
  u16*   x2l   = (u16*)  (big + ((size_t)120<<20));     // [120,128)
  // GAT3 (GAT1/x1 regions dead)
  u16*   w3th  = (u16*)  (big);                         // [0,8)   [4096][1024] bf16
  u16*   h3    = (u16*)  (big + ((size_t)8<<20));       // [8,40)  [4096][4096] bf16
  float* acc3  = (float*)(big + ((size_t)40<<20));      // [40,48)
  float* x3    = (float*)(big + ((size_t)48<<20));      // [48,56)
  // TR phase
  u16*   qkvTh = (u16*)  (big);                         // [0,2)   (w3th dead)
  u16*   qkvs  = (u16*)  (big + ((size_t)8<<20));       // [8,64)  bf16 [4096][6656]
  float* xt    = (float*)(big + ((size_t)64<<20));      // [64,72) (h2 dead)

  int* deg_g = cnt;       int* cur_g = cnt+4096;
  int* deg_t = cnt+8192;  int* cur_t = cnt+12288;

  // ---- graph prep ----
  zero_i<<<64,256,0,stream>>>(cnt, 16384);
  hist_k<<<48,256,0,stream>>>(ei, deg_g, deg_t);
  scan4096<<<1,1024,0,stream>>>(deg_g, off_g);
  scan4096<<<1,1024,0,stream>>>(deg_t, off_t);
  scatter_k<<<48,256,0,stream>>>(ei, off_g, cur_g, csr_g, off_t, cur_t, csr_t);
  mkdis<<<16,256,0,stream>>>(deg_g, dis);
  pad_x<<<4096,128,0,stream>>>(x, xpad, xph);
  repack_w1<<<5120,256,0,stream>>>(g1_w, w1r);
  // head weight transposes (bf16)
  tpd<<<dim3(8,16),256,0,stream>>>(gcn_w, 256, 0, 512, 512, gcnT);
  tpd<<<dim3(4,47),256,0,stream>>>(fc1_w, 128, 0, 1489, 1496, fc1T);
  tpd<<<dim3(8,4), 256,0,stream>>>(fc2_w, 256, 0, 128, 128, fc2T);
  tpd<<<dim3(8,32),256,0,stream>>>(b1_w,  256, 0, 1024, 1024, b1T);
  tpd<<<dim3(4,8), 256,0,stream>>>(b2_w,  128, 0, 256, 256, b2T);
  tpd<<<dim3(2,4), 256,0,stream>>>(b3_w,  64,  0, 128, 128, b3T);

  // ---- GAT1 (aggregate-first) ----
  wsvec<<<160,256,0,stream>>>(g1_w, g1_as, g1_ad, wsv, wdv, 78, 8, 2048);
  alk<<<4096,256,0,stream>>>(xpad, wsv, wdv, alsd, 80);
  gat1_gather<<<4096,256,0,stream>>>(xpad, alsd, off_g, csr_g, y1h, y1l);
  tpd<<<dim3(64,20),256,0,stream>>>(w1r, 2048, 0, 640, 640, w1rth);
  mgemm<5,1,float><<<dim3(16,32),256,0,stream>>>(y1h, y1l, 640, w1rth, 640,
                                         nullptr, 2048, 640, g1_b, 0.125f, x1h, x1l);

  // ---- GAT2 ----
  wsvec<<<4096,256,0,stream>>>(g2_w, g2_as, g2_ad, wsv, wdv, 2048, 8, 1024);
  mk_wsT<<<128,256,0,stream>>>(wsv, wdv, wsTh, wsTl, 2048);
  hipMemsetAsync(alsd, 0, (size_t)4096*16*4, stream);
  alk_mm<8><<<dim3(8,32),256,0,stream>>>(x1h, x1l, 2048, wsTh, wsTl, alsd, 2048);
  hipMemsetAsync(acc2, 0, (size_t)4096*1024*4, stream);
  for (int c=0;c<2;c++){
    tpd<<<dim3(128,64),256,0,stream>>>(g2_w, 8192, c*4096, 2048, 2048, w2th);
    mgemm<0,0,u16><<<dim3(32,32),256,0,stream>>>(x1h, nullptr, 2048, w2th, 2048,
                                           h2, 4096, 2048, nullptr, 0.f, nullptr, nullptr);
    gat_aggN<4,1024><<<4096,256,0,stream>>>(h2, alsd, off_g, csr_g, acc2, c*4);
  }
  finishx2<<<16384,256,0,stream>>>(acc2, g2_b, x2h, x2l, 1023);

  // ---- GAT3 ----
  wsvec<<<2048,256,0,stream>>>(g3_w, g3_as, g3_ad, wsv, wdv, 1024, 8, 512);
  mk_wsT<<<64,256,0,stream>>>(wsv, wdv, wsTh, wsTl, 1024);
  hipMemsetAsync(alsd, 0, (size_t)4096*16*4, stream);
  alk_mm<8><<<dim3(8,32),256,0,stream>>>(x2h, x2l, 1024, wsTh, wsTl, alsd, 1024);
  hipMemsetAsync(acc3, 0, (size_t)4096*512*4, stream);
  tpd<<<dim3(128,32),256,0,stream>>>(g3_w, 4096, 0, 1024, 1024, w3th);
  mgemm<0,0,u16><<<dim3(32,32),256,0,stream>>>(x2h, nullptr, 1024, w3th, 1024,
                                         h3, 4096, 1024, nullptr, 0.f, nullptr, nullptr);
  gat_aggN<8,512><<<4096,256,0,stream>>>(h3, alsd, off_g, csr_g, acc3, 0);
  finishx<<<8192,256,0,stream>>>(acc3, g3_b, x3, 511);
  pool_gcn<<<128,256,0,stream>>>(x3, dis, off_g, csr_g, zbuf);

  // ---- Transformer branch ----
  tpd<<<dim3(64,3),256,0,stream>>>(t_wq, 2048, 0, 78, 96, qkvTh);
  tpd<<<dim3(64,3),256,0,stream>>>(t_wk, 2048, 0, 78, 96, qkvTh + (size_t)2048*96);
  tpd<<<dim3(64,3),256,0,stream>>>(t_wv, 2048, 0, 78, 96, qkvTh + (size_t)4096*96);
  tpd<<<dim3(16,3),256,0,stream>>>(t_ws, 512,  0, 78, 96, qkvTh + (size_t)6144*96);
  catb<<<26,256,0,stream>>>(t_bq, t_bk, t_bv, t_bs, cbias);
  mgemm<1,0,u16><<<dim3(52,32),256,0,stream>>>(xph, nullptr, 96, qkvTh, 96,
                                         qkvs, 6656, 96, cbias, 0.f, nullptr, nullptr);
  tr_agg<<<4096,256,0,stream>>>(qkvs, off_t, csr_t, xt);

  // ---- fused head ----
  head_k<<<128,256,0,stream>>>(zbuf, xt, fp, gcnT, gcn_b,
                               fc1T, fc1_b, fc2T, fc2_b,
                               b1T, b1_b, b2T, b2_b, b3T, b3_b, b4_w, b4_b,
                               (float*)d_out);
}

// Round 8
// 782.338 us; speedup vs baseline: 7.1162x; 1.0032x over previous
//
#include <hip/hip_runtime.h>

typedef unsigned short u16;
typedef unsigned int   u32;

typedef __bf16 bf16x8 __attribute__((ext_vector_type(8)));
typedef float  f32x4  __attribute__((ext_vector_type(4)));

#define NNODE 4096
#define NEDGE 8192
#define NEG   12288   /* edges incl self-loops */

__device__ __forceinline__ float blo(u32 u){ return __uint_as_float(u<<16); }
__device__ __forceinline__ float bhi(u32 u){ return __uint_as_float(u & 0xffff0000u); }
__device__ __forceinline__ u16 f2b(float f){
  u32 u = __float_as_uint(f);
  u += 0x7fffu + ((u>>16)&1u);
  return (u16)(u>>16);
}
__device__ __forceinline__ void split_bf(float a, u16& hi, u16& lo){
  u32 u = __float_as_uint(a);
  u32 r = u + 0x7fffu + ((u>>16)&1u);
  hi = (u16)(r>>16);
  float h = __uint_as_float(r & 0xffff0000u);
  float l = a - h;
  u32 u2 = __float_as_uint(l);
  lo = (u16)((u2 + 0x7fffu + ((u2>>16)&1u)) >> 16);
}
__device__ __forceinline__ u16 hi_bf(float a){
  u32 u = __float_as_uint(a);
  return (u16)((u + 0x7fffu + ((u>>16)&1u)) >> 16);
}

#define GL2LDS(g,l) __builtin_amdgcn_global_load_lds((const __attribute__((address_space(1))) unsigned int*)(g), (__attribute__((address_space(3))) unsigned int*)(l), 16, 0, 0)

// ---------------- graph prep ----------------
__global__ __launch_bounds__(256) void zero_i(int* p, int n){
  int i = blockIdx.x*256 + threadIdx.x; if (i<n) p[i]=0;
}
__global__ __launch_bounds__(256) void hist_k(const int* __restrict__ ei, int* deg_g, int* deg_t){
  int e = blockIdx.x*256 + threadIdx.x; if (e>=NEG) return;
  int dv = (e<NEDGE) ? ei[NEDGE+e] : e-NEDGE;
  atomicAdd(&deg_g[dv],1);
  if (e<NEDGE) atomicAdd(&deg_t[dv],1);
}
__global__ __launch_bounds__(1024) void scan4096(const int* __restrict__ deg, int* __restrict__ off){
  __shared__ int lds[1024];
  int tid = threadIdx.x;
  int v[4]; int s=0;
  #pragma unroll
  for (int j=0;j<4;j++){ v[j]=deg[tid*4+j]; s+=v[j]; }
  lds[tid]=s; __syncthreads();
  for (int d=1; d<1024; d<<=1){
    int t = (tid>=d) ? lds[tid-d] : 0;
    __syncthreads();
    lds[tid] += t;
    __syncthreads();
  }
  int base = (tid>0) ? lds[tid-1] : 0;
  #pragma unroll
  for (int j=0;j<4;j++){ off[tid*4+j]=base; base+=v[j]; }
  if (tid==1023) off[4096]=base;
}
__global__ __launch_bounds__(256) void scatter_k(const int* __restrict__ ei,
    const int* __restrict__ off_g, int* cur_g, int* csr_g,
    const int* __restrict__ off_t, int* cur_t, int* csr_t){
  int e = blockIdx.x*256 + threadIdx.x; if (e>=NEG) return;
  int s, dv;
  if (e<NEDGE){ s=ei[e]; dv=ei[NEDGE+e]; } else { s=dv=e-NEDGE; }
  int p = atomicAdd(&cur_g[dv],1);
  csr_g[off_g[dv]+p]=s;
  if (e<NEDGE){ int p2 = atomicAdd(&cur_t[dv],1); csr_t[off_t[dv]+p2]=s; }
}
__global__ __launch_bounds__(256) void mkdis(const int* __restrict__ deg, float* dis){
  int i = blockIdx.x*256 + threadIdx.x; if (i>=NNODE) return;
  int d = deg[i]; dis[i] = d>0 ? rsqrtf((float)d) : 0.f;
}
// xpad fp32 [n][80] + xph bf16-hi [n][96]
__global__ __launch_bounds__(128) void pad_x(const float* __restrict__ x, float* __restrict__ xp,
                                             u16* __restrict__ xh){
  int n = blockIdx.x, c = threadIdx.x;
  if (c<96){
    float v = (c<78) ? x[(size_t)n*78+c] : 0.f;
    if (c<80) xp[(size_t)n*80+c] = v;
    xh[(size_t)n*96+c] = hi_bf(v);
  }
}
// W1r[(h*80+k), c] = g1_w[k, h*2048+c], zero-padded k>=78
__global__ __launch_bounds__(256) void repack_w1(const float* __restrict__ g1w, float* __restrict__ w1r){
  int i = blockIdx.x*256 + threadIdx.x;   // 640*2048
  int kk = i >> 11, c = i & 2047;
  int h = kk/80, k2 = kk - h*80;
  w1r[i] = (k2<78) ? g1w[(size_t)k2*16384 + h*2048 + c] : 0.f;
}

// ---------------- transpose + bf16(hi): W[K,Ntot] cols [n0,n0+Nw) -> hi [Nw,Kp] ----------------
__global__ __launch_bounds__(256) void tpd(const float* __restrict__ in, int Ntot, int n0,
    int K, int Kp, u16* __restrict__ outh){
  __shared__ float t[32][33];
  int bx = blockIdx.x*32;   // n in window
  int by = blockIdx.y*32;   // k
  int tx = threadIdx.x & 31, ty = threadIdx.x >> 5;
  for (int i=ty;i<32;i+=8){
    int kk=by+i;
    t[i][tx] = (kk<K) ? in[(size_t)kk*Ntot + n0 + bx + tx] : 0.f;
  }
  __syncthreads();
  for (int i=ty;i<32;i+=8){
    int nn=bx+i, kk=by+tx;
    if (kk<Kp) outh[(size_t)nn*Kp+kk] = hi_bf(t[tx][i]);
  }
}

// ---------------- attention-table pack: [16][Kp] rows 0..7 = ws heads, 8..15 = wd ----------------
__global__ __launch_bounds__(256) void mk_wsT(const float* __restrict__ wsv, const float* __restrict__ wdv,
    u16* __restrict__ th, u16* __restrict__ tl, int Kp){
  int i = blockIdx.x*256 + threadIdx.x;   // over 16*Kp
  if (i >= 16*Kp) return;
  int r = i / Kp, k = i - r*Kp;
  float v = (r<8) ? wsv[k*8+r] : wdv[k*8+(r-8)];
  u16 h,l; split_bf(v,h,l);
  th[i]=h; tl[i]=l;
}

// LDS bank-conflict-free swizzle for [16-row][4x16B] groups staged via global_load_lds:
//   write: lane L fetches logical 16B-col jl = ((L&3) - (L>>3)) & 3  (row = L>>2)
//   read : row rig, logical col q lives at physical slot jp = (q + (rig>>1)) & 3

// ---------------- K-split logits GEMM: alsd[4096][16] += (Ah+Al) * (Bh+Bl)^T ----------------
template<int KS>
__global__ __launch_bounds__(256,4) void alk_mm(
    const u16* __restrict__ Ah, const u16* __restrict__ Al, int lda,
    const u16* __restrict__ Bh, const u16* __restrict__ Bl,
    float* __restrict__ alsd, int K)
{
  __shared__ __align__(16) u16 Ash[128*32], Asl[128*32], Bsh[16*32], Bsl[16*32];
  int tid = threadIdx.x, lane = tid & 63, wave = tid >> 6;
  int bm = blockIdx.y*128;
  int kb = blockIdx.x*(K/KS), ke = kb + K/KS;
  int m16 = lane & 15, quad = lane >> 4;
  int srow = lane >> 2;
  int skk = (((lane & 3) - (srow >> 1)) & 3) * 8;   // swizzled logical col
  int kq  = (((quad + (m16 >> 1)) & 3)) * 8;        // swizzled read slot
  f32x4 acc[2] = {};
  for (int k0=kb; k0<ke; k0+=32){
    __syncthreads();
    #pragma unroll
    for (int t=0;t<2;t++){
      int g = wave + t*4; int row = g*16 + srow;
      GL2LDS(Ah + (size_t)(bm+row)*lda + k0 + skk, &Ash[g*512]);
      GL2LDS(Al + (size_t)(bm+row)*lda + k0 + skk, &Asl[g*512]);
    }
    if (wave==0) GL2LDS(Bh + (size_t)srow*lda + k0 + skk, &Bsh[0]);
    if (wave==1) GL2LDS(Bl + (size_t)srow*lda + k0 + skk, &Bsl[0]);
    __syncthreads();
    bf16x8 bh = *(const bf16x8*)&Bsh[m16*32+kq];
    bf16x8 bl = *(const bf16x8*)&Bsl[m16*32+kq];
    #pragma unroll
    for (int i=0;i<2;i++){
      bf16x8 ah = *(const bf16x8*)&Ash[(wave*32+i*16+m16)*32+kq];
      bf16x8 al = *(const bf16x8*)&Asl[(wave*32+i*16+m16)*32+kq];
      acc[i] = __builtin_amdgcn_mfma_f32_16x16x32_bf16(ah, bh, acc[i],0,0,0);
      acc[i] = __builtin_amdgcn_mfma_f32_16x16x32_bf16(al, bh, acc[i],0,0,0);
      acc[i] = __builtin_amdgcn_mfma_f32_16x16x32_bf16(ah, bl, acc[i],0,0,0);
    }
  }
  #pragma unroll
  for (int i=0;i<2;i++){
    int row0 = bm + wave*32 + i*16 + quad*4;
    #pragma unroll
    for (int r=0;r<4;r++)
      atomicAdd(&alsd[(size_t)(row0+r)*16 + m16], acc[i][r]);
  }
}

// ---------------- MFMA GEMM (m97 staging + swizzle): C = (Ah[+Al]) * Bh^T ----------------
// EPI: 0 plain CT store, 1 +bias CT store, 5 relu(scale*acc+bias) -> split hi/lo only
#define BM 128
#define BN 128
template<int EPI, int SA, typename CT>
__global__ __launch_bounds__(256,4) void mgemm(
    const u16* __restrict__ Ah, const u16* __restrict__ Al, int lda,
    const u16* __restrict__ Bh, int ldb,
    CT* __restrict__ C, int ldc, int K,
    const float* __restrict__ bias, float scale,
    u16* __restrict__ Chi, u16* __restrict__ Clo)
{
  __shared__ __align__(16) u16 Ash[128*32];
  __shared__ __align__(16) u16 Bsh[128*32];
  __shared__ __align__(16) u16 Asl[SA?128*32:16];
  int tid = threadIdx.x;
  int bm = blockIdx.y*BM, bn = blockIdx.x*BN;
  int lane = tid & 63, wave = tid >> 6;
  int wr = (wave>>1)*64, wc = (wave&1)*64;
  int m16 = lane & 15, quad = lane >> 4;
  int srow = lane >> 2;
  int skk = (((lane & 3) - (srow >> 1)) & 3) * 8;   // swizzled fetch col
  int kq  = (((quad + (m16 >> 1)) & 3)) * 8;        // swizzled read slot

  f32x4 acc[4][4] = {};
  for (int k0=0; k0<K; k0+=32){
    __syncthreads();
    #pragma unroll
    for (int t=0;t<2;t++){
      int g = wave + t*4;
      int row = g*16 + srow;
      GL2LDS(Ah + (size_t)(bm+row)*lda + k0 + skk, &Ash[g*512]);
      if (SA) GL2LDS(Al + (size_t)(bm+row)*lda + k0 + skk, &Asl[g*512]);
      GL2LDS(Bh + (size_t)(bn+row)*ldb + k0 + skk, &Bsh[g*512]);
    }
    __syncthreads();
    bf16x8 ah[4], al_[4], bh_[4];
    #pragma unroll
    for (int i=0;i<4;i++){
      ah[i]  = *(const bf16x8*)&Ash[(wr+i*16+m16)*32 + kq];
      if (SA) al_[i] = *(const bf16x8*)&Asl[(wr+i*16+m16)*32 + kq];
    }
    #pragma unroll
    for (int j=0;j<4;j++)
      bh_[j] = *(const bf16x8*)&Bsh[(wc+j*16+m16)*32 + kq];
    #pragma unroll
    for (int i=0;i<4;i++)
      #pragma unroll
      for (int j=0;j<4;j++){
        acc[i][j] = __builtin_amdgcn_mfma_f32_16x16x32_bf16(ah[i], bh_[j], acc[i][j], 0,0,0);
        if (SA) acc[i][j] = __builtin_amdgcn_mfma_f32_16x16x32_bf16(al_[i], bh_[j], acc[i][j], 0,0,0);
      }
  }
  #pragma unroll
  for (int i=0;i<4;i++){
    int row0 = bm + wr + i*16 + quad*4;
    #pragma unroll
    for (int j=0;j<4;j++){
      int col = bn + wc + j*16 + m16;
      float bv = (EPI==1||EPI==5) ? bias[col] : 0.f;
      #pragma unroll
      for (int r=0;r<4;r++){
        float v = acc[i][j][r];
        if constexpr (EPI==5){
          v = fmaxf(v*scale + bv, 0.f);
          size_t idx = (size_t)(row0+r)*ldc + col;
          u16 h_, l_; split_bf(v, h_, l_);
          Chi[idx]=h_; Clo[idx]=l_;
        } else {
          if (EPI==1) v += bv;
          size_t idx = (size_t)(row0+r)*ldc + col;
          if constexpr (sizeof(CT)==2) C[idx] = (CT)f2b(v);
          else C[idx] = (CT)v;
        }
      }
    }
  }
}

// ---------------- GAT attention-vector precompute ----------------
__global__ __launch_bounds__(256) void wsvec(const float* __restrict__ W,
    const float* __restrict__ as_, const float* __restrict__ ad_,
    float* __restrict__ ws, float* __restrict__ wd,
    int Kreal, int H, int C)
{
  int wv = blockIdx.x*4 + (threadIdx.x>>6);
  int lane = threadIdx.x & 63;
  int k = wv / H, h = wv - k*H;
  float ps=0.f, pd=0.f;
  if (k < Kreal){
    const float* wr = W + (size_t)k*((size_t)H*C) + (size_t)h*C;
    const float* ar = as_ + (size_t)h*C;
    const float* dr = ad_ + (size_t)h*C;
    for (int c=lane;c<C;c+=64){ float w=wr[c]; ps += w*ar[c]; pd += w*dr[c]; }
  }
  #pragma unroll
  for (int o=32;o;o>>=1){ ps += __shfl_down(ps,o); pd += __shfl_down(pd,o); }
  if (lane==0){ ws[k*H+h]=ps; wd[k*H+h]=pd; }
}
// GAT1 logits (Kp=80), writes alsd[n][16] = [als(8) | ald(8)]
__global__ __launch_bounds__(256) void alk(const float* __restrict__ X,
    const float* __restrict__ ws, const float* __restrict__ wd,
    float* __restrict__ alsd, int Kp)
{
  int n = blockIdx.x, tid = threadIdx.x;
  int hh = tid>>5, l32 = tid&31;
  const float* xr = X + (size_t)n*Kp;
  float ps=0.f, pd=0.f;
  for (int k=l32;k<Kp;k+=32){
    float xv = xr[k];
    ps += xv*ws[k*8+hh];
    pd += xv*wd[k*8+hh];
  }
  #pragma unroll
  for (int o=16;o;o>>=1){ ps += __shfl_down(ps,o,32); pd += __shfl_down(pd,o,32); }
  if (l32==0){ alsd[n*16+hh]=ps; alsd[n*16+8+hh]=pd; }
}

// ---------------- GAT1 aggregate-first gather (emits hi/lo) ----------------
__global__ __launch_bounds__(256) void gat1_gather(
    const float* __restrict__ xpad, const float* __restrict__ alsd,
    const int* __restrict__ off, const int* __restrict__ csr,
    u16* __restrict__ y1h, u16* __restrict__ y1l)
{
  int d = blockIdx.x, tid = threadIdx.x;
  int hh = tid>>5, l32 = tid&31;
  int e0 = off[d], e1 = off[d+1];
  __shared__ float mh[8], lih[8], adh[8];
  __shared__ float wl[32][8];
  __shared__ int sl[32];
  if (tid < 8){
    float ad = alsd[d*16+8+tid]; adh[tid]=ad;
    float m=-1e30f, l=0.f;
    for (int e=e0;e<e1;++e){
      float xv = alsd[csr[e]*16+tid] + ad;
      xv = xv>0.f?xv:0.2f*xv;
      if (xv>m){ l = l*__expf(m-xv)+1.f; m=xv; } else l += __expf(xv-m);
    }
    mh[tid]=m; lih[tid]=1.f/l;
  }
  __syncthreads();
  float acc0=0.f, acc1=0.f, acc2v=0.f;
  for (int cb=e0; cb<e1; cb+=32){
    int ce = min(32, e1-cb);
    if (tid < ce*8){
      int j = tid>>3, h2 = tid&7;
      int s = csr[cb+j];
      if (h2==0) sl[j]=s;
      float xv = alsd[s*16+h2] + adh[h2];
      xv = xv>0.f?xv:0.2f*xv;
      wl[j][h2] = __expf(xv-mh[h2])*lih[h2];
    }
    __syncthreads();
    for (int j=0;j<ce;++j){
      float w = wl[j][hh];
      const float* xr = xpad + (size_t)sl[j]*80;
      acc0 += w*xr[l32];
      acc1 += w*xr[l32+32];
      if (l32 < 16) acc2v += w*xr[l32+64];
    }
    __syncthreads();
  }
  size_t base = (size_t)d*640 + hh*80;
  u16 h_, l_;
  split_bf(acc0, h_, l_); y1h[base+l32]=h_;    y1l[base+l32]=l_;
  split_bf(acc1, h_, l_); y1h[base+l32+32]=h_; y1l[base+l32+32]=l_;
  if (l32<16){ split_bf(acc2v, h_, l_); y1h[base+l32+64]=h_; y1l[base+l32+64]=l_; }
}

// ---------------- all-head chunk aggregation (bf16 h, alsd layout) ----------------
template<int HPC, int C>
__global__ __launch_bounds__(256) void gat_aggN(
    const u16* __restrict__ h, const float* __restrict__ alsd,
    const int* __restrict__ off, const int* __restrict__ csr,
    float* __restrict__ accum, int head0)
{
  constexpr int V = C/256;
  int d = blockIdx.x, tid = threadIdx.x;
  int e0=off[d], e1=off[d+1];
  __shared__ float mh[HPC], lih[HPC], adh[HPC];
  __shared__ float wl[32][HPC];
  __shared__ int sl[32];
  if (tid < HPC){
    float ad = alsd[d*16 + 8 + head0 + tid]; adh[tid]=ad;
    float m=-1e30f,l=0.f;
    for (int e=e0;e<e1;++e){
      float xv = alsd[csr[e]*16 + head0 + tid]+ad;
      xv = xv>0.f?xv:0.2f*xv;
      if (xv>m){ l=l*__expf(m-xv)+1.f; m=xv; } else l+=__expf(xv-m);
    }
    mh[tid]=m; lih[tid]=1.f/l;
  }
  __syncthreads();
  float acc[HPC][V];
  #pragma unroll
  for (int a=0;a<HPC;a++)
    #pragma unroll
    for (int v=0;v<V;v++) acc[a][v]=0.f;
  int c0 = tid*V;
  for (int cb=e0;cb<e1;cb+=32){
    int ce = min(32, e1-cb);
    if (tid < ce*HPC){
      int j = tid/HPC, h2 = tid - j*HPC;
      int s = csr[cb+j];
      if (h2==0) sl[j]=s;
      float xv = alsd[s*16 + head0 + h2] + adh[h2];
      xv = xv>0.f?xv:0.2f*xv;
      wl[j][h2] = __expf(xv-mh[h2])*lih[h2];
    }
    __syncthreads();
    for (int j=0;j<ce;++j){
      const u16* hr = h + (size_t)sl[j]*(HPC*C);
      #pragma unroll
      for (int a=0;a<HPC;a++){
        float w = wl[j][a];
        if constexpr (V==4){
          uint2 u = *(const uint2*)(hr + a*C + c0);
          acc[a][0] += w*blo(u.x); acc[a][1] += w*bhi(u.x);
          acc[a][2] += w*blo(u.y); acc[a][3] += w*bhi(u.y);
        } else {
          u32 u = *(const u32*)(hr + a*C + c0);
          acc[a][0] += w*blo(u); acc[a][1] += w*bhi(u);
        }
      }
    }
    __syncthreads();
  }
  float* ar = accum + (size_t)d*C + c0;
  #pragma unroll
  for (int v=0;v<V;v++){
    float s2 = 0.f;
    #pragma unroll
    for (int a=0;a<HPC;a++) s2 += acc[a][v];
    ar[v] += s2;
  }
}
// x3 = relu(acc/8 + b[c])  (fp32 out, GAT3)
__global__ __launch_bounds__(256) void finishx(const float* __restrict__ accum,
    const float* __restrict__ bias, float* __restrict__ xo, int Cmask){
  int i = blockIdx.x*256 + threadIdx.x;
  int c = i & Cmask;
  xo[i] = fmaxf(accum[i]*0.125f + bias[c], 0.f);
}
// x2 = relu(acc/8 + b[c]) -> hi/lo only (GAT2)
__global__ __launch_bounds__(256) void finishx2(const float* __restrict__ accum,
    const float* __restrict__ bias,
    u16* __restrict__ xh, u16* __restrict__ xl, int Cmask){
  int i = blockIdx.x*256 + threadIdx.x;
  int c = i & Cmask;
  float v = fmaxf(accum[i]*0.125f + bias[c], 0.f);
  u16 h_, l_; split_bf(v, h_, l_);
  xh[i]=h_; xl[i]=l_;
}

// ---------------- pooled GCN aggregation ----------------
__global__ __launch_bounds__(256) void pool_gcn(const float* __restrict__ x3,
    const float* __restrict__ dis, const int* __restrict__ off, const int* __restrict__ csr,
    float* __restrict__ z)
{
  int g = blockIdx.x, tid = threadIdx.x;
  int c0 = tid*2;
  float a0=0.f, a1=0.f;
  for (int dd=0; dd<32; ++dd){
    int d = g*32+dd;
    int e0=off[d], e1=off[d+1];
    float b0=0.f, b1=0.f;
    for (int e=e0;e<e1;++e){
      int s = csr[e]; float ds = dis[s];
      const float* xr = x3 + (size_t)s*512 + c0;
      b0 += ds*xr[0]; b1 += ds*xr[1];
    }
    float dw = dis[d];
    a0 += dw*b0; a1 += dw*b1;
  }
  z[(size_t)g*512+c0]   = a0*(1.f/32.f);
  z[(size_t)g*512+c0+1] = a1*(1.f/32.f);
}

// ---------------- TransformerConv aggregation (bf16 qkvs, logit-cache) ----------------
__global__ __launch_bounds__(256) void tr_agg(
  const u16* __restrict__ qkvs, const int* __restrict__ off, const int* __restrict__ csr,
  float* __restrict__ xt)
{
  int d = blockIdx.x, tid = threadIdx.x;
  int wv = tid>>6, lane = tid&63;
  int e0=off[d], e1=off[d+1];
  __shared__ float osum[4][512];
  __shared__ float sp[4][64];
  float qf[8];
  { uint4 u = *(const uint4*)(qkvs + (size_t)d*6656 + wv*512 + lane*8);
    qf[0]=blo(u.x); qf[1]=bhi(u.x); qf[2]=blo(u.y); qf[3]=bhi(u.y);
    qf[4]=blo(u.z); qf[5]=bhi(u.z); qf[6]=blo(u.w); qf[7]=bhi(u.w); }
  const float scale = 0.04419417382415922f; // 1/sqrt(512)
  float m=-1e30f,l=0.f;
  for (int e=e0;e<e1;++e){
    int s = csr[e];
    uint4 u = *(const uint4*)(qkvs + (size_t)s*6656 + 2048 + wv*512 + lane*8);
    float p = qf[0]*blo(u.x)+qf[1]*bhi(u.x)+qf[2]*blo(u.y)+qf[3]*bhi(u.y)
            + qf[4]*blo(u.z)+qf[5]*bhi(u.z)+qf[6]*blo(u.w)+qf[7]*bhi(u.w);
    #pragma unroll
    for (int o=32;o;o>>=1) p += __shfl_xor(p,o);
    p *= scale;
    int idx = e-e0;
    if (lane==0 && idx<64) sp[wv][idx]=p;
    if (p>m){ l=l*__expf(m-p)+1.f; m=p; } else l+=__expf(p-m);
  }
  float li = (e1>e0)?1.f/l:0.f;
  float acc[8]={0.f,0.f,0.f,0.f,0.f,0.f,0.f,0.f};
  for (int e=e0;e<e1;++e){
    int s = csr[e];
    int idx = e-e0;
    float p;
    if (idx<64) p = sp[wv][idx];
    else {
      uint4 u = *(const uint4*)(qkvs + (size_t)s*6656 + 2048 + wv*512 + lane*8);
      p = qf[0]*blo(u.x)+qf[1]*bhi(u.x)+qf[2]*blo(u.y)+qf[3]*bhi(u.y)
        + qf[4]*blo(u.z)+qf[5]*bhi(u.z)+qf[6]*blo(u.w)+qf[7]*bhi(u.w);
      #pragma unroll
      for (int o=32;o;o>>=1) p += __shfl_xor(p,o);
      p *= scale;
    }
    float w = __expf(p - m)*li;
    uint4 u = *(const uint4*)(qkvs + (size_t)s*6656 + 4096 + wv*512 + lane*8);
    acc[0]+=w*blo(u.x); acc[1]+=w*bhi(u.x); acc[2]+=w*blo(u.y); acc[3]+=w*bhi(u.y);
    acc[4]+=w*blo(u.z); acc[5]+=w*bhi(u.z); acc[6]+=w*blo(u.w); acc[7]+=w*bhi(u.w);
  }
  #pragma unroll
  for (int j=0;j<8;j++) osum[wv][lane*8+j]=acc[j];
  __syncthreads();
  for (int c=tid;c<512;c+=256){
    u16 sk = qkvs[(size_t)d*6656 + 6144 + c];
    float o = (osum[0][c]+osum[1][c]+osum[2][c]+osum[3][c])*0.25f + blo((u32)sk);
    xt[(size_t)d*512+c] = fmaxf(o,0.f);
  }
}

// ---------------- bias concat for qkv GEMM ----------------
__global__ __launch_bounds__(256) void catb(const float* __restrict__ bq, const float* __restrict__ bk,
    const float* __restrict__ bv, const float* __restrict__ bs, float* __restrict__ o){
  int i = blockIdx.x*256 + threadIdx.x; if (i>=6656) return;
  float v;
  if (i<2048) v=bq[i]; else if (i<4096) v=bk[i-2048];
  else if (i<6144) v=bv[i-4096]; else v=bs[i-6144];
  o[i]=v;
}

// ---------------- fused head (bf16 [N,K] weights) ----------------
__device__ __forceinline__ float dotb(const u16* __restrict__ w, const float* __restrict__ s,
                                      int k0, int k1){
  float acc=0.f;
  #pragma unroll 4
  for (int k=k0;k<k1;k+=8){
    uint4 u = *(const uint4*)(w+k);
    float4 s0 = *(const float4*)(s+k);
    float4 s1 = *(const float4*)(s+k+4);
    acc += blo(u.x)*s0.x + bhi(u.x)*s0.y + blo(u.y)*s0.z + bhi(u.y)*s0.w
         + blo(u.z)*s1.x + bhi(u.z)*s1.y + blo(u.w)*s1.z + bhi(u.w)*s1.w;
  }
  return acc;
}
__global__ __launch_bounds__(256) void head_k(
  const float* __restrict__ z, const float* __restrict__ xt, const float* __restrict__ fp,
  const u16* __restrict__ gcnT, const float* __restrict__ gcn_b,
  const u16* __restrict__ fc1T, const float* __restrict__ fc1_b,
  const u16* __restrict__ fc2T, const float* __restrict__ fc2_b,
  const u16* __restrict__ b1T, const float* __restrict__ b1_b,
  const u16* __restrict__ b2T, const float* __restrict__ b2_b,
  const u16* __restrict__ b3T, const float* __restrict__ b3_b,
  const float* __restrict__ b4_w, const float* __restrict__ b4_b,
  float* __restrict__ out)
{
  int g = blockIdx.x, tid = threadIdx.x;
  __shared__ __align__(16) float xc[1024];
  __shared__ __align__(16) float sa[1504];
  __shared__ __align__(16) float sb[256];
  __shared__ __align__(16) float scm[256];
  for (int c=tid;c<512;c+=256) sa[c] = z[(size_t)g*512+c];
  __syncthreads();
  float vgcn = gcn_b[tid] + dotb(gcnT + (size_t)tid*512, sa, 0, 512);
  for (int c=tid;c<512;c+=256){
    float s=0.f;
    for (int i=0;i<32;i++) s += xt[(size_t)(g*32+i)*512 + c];
    xc[256+c] = s*(1.f/32.f);
  }
  xc[tid] = vgcn;
  __syncthreads();
  for (int c=tid;c<1496;c+=256) sa[c] = (c<1489) ? fp[(size_t)g*1489+c] : 0.f;
  __syncthreads();
  { int n = tid & 127, half = tid >> 7;
    sb[tid] = dotb(fc1T + (size_t)n*1496, sa, half?752:0, half?1496:752); }
  __syncthreads();
  if (tid<128) scm[tid] = fmaxf(sb[tid]+sb[tid+128]+fc1_b[tid], 0.f);
  __syncthreads();
  xc[768+tid] = fmaxf(fc2_b[tid] + dotb(fc2T + (size_t)tid*128, scm, 0, 128), 0.f);
  __syncthreads();
  sa[tid] = fmaxf(b1_b[tid] + dotb(b1T + (size_t)tid*1024, xc, 0, 1024), 0.f);
  __syncthreads();
  { int n = tid & 127, half = tid >> 7;
    sb[tid] = dotb(b2T + (size_t)n*256, sa, half*128, half*128+128); }
  __syncthreads();
  if (tid<128) scm[tid] = fmaxf(sb[tid]+sb[tid+128]+b2_b[tid], 0.f);
  __syncthreads();
  { int n = tid & 63, part = tid >> 6;
    sb[tid] = dotb(b3T + (size_t)n*128, scm, part*32, part*32+32); }
  __syncthreads();
  if (tid<64) sa[tid] = fmaxf(sb[tid]+sb[tid+64]+sb[tid+128]+sb[tid+192]+b3_b[tid], 0.f);
  __syncthreads();
  if (tid<64){
    float p = sa[tid]*b4_w[tid];
    #pragma unroll
    for (int o=32;o;o>>=1) p += __shfl_down(p,o);
    if (tid==0) out[g] = 1.f/(1.f+__expf(-(p + b4_b[0])));
  }
}

extern "C" void kernel_launch(void* const* d_in, const int* in_sizes, int n_in,
                              void* d_out, int out_size, void* d_ws, size_t ws_size,
                              hipStream_t stream)
{
  (void)in_sizes; (void)n_in; (void)out_size; (void)ws_size;
  const float* x     = (const float*)d_in[0];
  const float* fp    = (const float*)d_in[1];
  const int*   ei    = (const int*)d_in[2];
  const float* g1_w  = (const float*)d_in[4];
  const float* g1_as = (const float*)d_in[5];
  const float* g1_ad = (const float*)d_in[6];
  const float* g1_b  = (const float*)d_in[7];
  const float* g2_w  = (const float*)d_in[8];
  const float* g2_as = (const float*)d_in[9];
  const float* g2_ad = (const float*)d_in[10];
  const float* g2_b  = (const float*)d_in[11];
  const float* g3_w  = (const float*)d_in[12];
  const float* g3_as = (const float*)d_in[13];
  const float* g3_ad = (const float*)d_in[14];
  const float* g3_b  = (const float*)d_in[15];
  const float* gcn_w = (const float*)d_in[16];
  const float* gcn_b = (const float*)d_in[17];
  const float* t_wq  = (const float*)d_in[18];
  const float* t_wk  = (const float*)d_in[19];
  const float* t_wv  = (const float*)d_in[20];
  const float* t_bq  = (const float*)d_in[21];
  const float* t_bk  = (const float*)d_in[22];
  const float* t_bv  = (const float*)d_in[23];
  const float* t_ws  = (const float*)d_in[24];
  const float* t_bs  = (const float*)d_in[25];
  const float* fc1_w = (const float*)d_in[26];
  const float* fc1_b = (const float*)d_in[27];
  const float* fc2_w = (const float*)d_in[28];
  const float* fc2_b = (const float*)d_in[29];
  const float* b1_w  = (const float*)d_in[30];
  const float* b1_b  = (const float*)d_in[31];
  const float* b2_w  = (const float*)d_in[32];
  const float* b2_b  = (const float*)d_in[33];
  const float* b3_w  = (const float*)d_in[34];
  const float* b3_b  = (const float*)d_in[35];
  const float* b4_w  = (const float*)d_in[36];
  const float* b4_b  = (const float*)d_in[37];

  char* base = (char*)d_ws;
  size_t offb = 0;
  auto alloc = [&](size_t bytes)->void*{
    void* p = base + offb; offb = (offb + bytes + 255) & ~(size_t)255; return p;
  };
  int*   cnt   = (int*)alloc(16384*4);
  int*   off_g = (int*)alloc(4097*4);
  int*   off_t = (int*)alloc(4097*4);
  int*   csr_g = (int*)alloc(12288*4);
  int*   csr_t = (int*)alloc(8192*4);
  float* dis   = (float*)alloc(4096*4);
  float* xpad  = (float*)alloc((size_t)4096*80*4);
  u16*   xph   = (u16*)alloc((size_t)4096*96*2);
  float* alsd  = (float*)alloc((size_t)4096*16*4);
  float* wsv   = (float*)alloc((size_t)2048*8*4);
  float* wdv   = (float*)alloc((size_t)2048*8*4);
  u16*   wsTh  = (u16*)alloc((size_t)16*2048*2);
  u16*   wsTl  = (u16*)alloc((size_t)16*2048*2);
  float* zbuf  = (float*)alloc((size_t)128*512*4);
  float* cbias = (float*)alloc((size_t)6656*4);
  float* w1r   = (float*)alloc((size_t)640*2048*4);
  u16*   gcnT  = (u16*)alloc((size_t)256*512*2);
  u16*   fc1T  = (u16*)alloc((size_t)128*1496*2);
  u16*   fc2T  = (u16*)alloc((size_t)256*128*2);
  u16*   b1T   = (u16*)alloc((size_t)256*1024*2);
  u16*   b2T   = (u16*)alloc((size_t)128*256*2);
  u16*   b3T   = (u16*)alloc((size_t)64*128*2);
  char*  big   = (char*)alloc((size_t)140<<20);

  // ---- overlays (MB offsets in big) ----
  // GAT1
  u16*   y1h   = (u16*)  (big);                         // [0,5)
  u16*   y1l   = (u16*)  (big + ((size_t)5<<20));       // [5,10)
  u16*   w1rth = (u16*)  (big + ((size_t)10<<20));      // [10,13)
  u16*   x1h   = (u16*)  (big + ((size_t)16<<20));      // [16,32)
  u16*   x1l   = (u16*)  (big + ((size_t)32<<20));      // [32,48)
  // GAT2
  u16*   w2th  = (u16*)  (big + ((size_t)48<<20));      // [48,64)  [4096][2048] bf16
  u16*   h2    = (u16*)  (big + ((size_t)64<<20));      // [64,96)  [4096][4096] bf16
  float* acc2  = (float*)(big + ((size_t)96<<20));      // [96,112)
  u16*   x2h   = (u16*)  (big + ((size_t)112<<20));     // [112,120)
  u16*   x2l   = (u16*)  (big + ((size_t)120<<20));     // [120,128)
  // GAT3 (GAT1/x1 regions dead)
  u16*   w3th  = (u16*)  (big);                         // [0,8)   [4096][1024] bf16
  u16*   h3    = (u16*)  (big + ((size_t)8<<20));       // [8,40)  [4096][4096] bf16
  float* acc3  = (float*)(big + ((size_t)40<<20));      // [40,48)
  float* x3    = (float*)(big + ((size_t)48<<20));      // [48,56)
  // TR phase
  u16*   qkvTh = (u16*)  (big);                         // [0,2)   (w3th dead)
  u16*   qkvs  = (u16*)  (big + ((size_t)8<<20));       // [8,64)  bf16 [4096][6656]
  float* xt    = (float*)(big + ((size_t)64<<20));      // [64,72) (h2 dead)

  int* deg_g = cnt;       int* cur_g = cnt+4096;
  int* deg_t = cnt+8192;  int* cur_t = cnt+12288;

  // ---- graph prep ----
  zero_i<<<64,256,0,stream>>>(cnt, 16384);
  hist_k<<<48,256,0,stream>>>(ei, deg_g, deg_t);
  scan4096<<<1,1024,0,stream>>>(deg_g, off_g);
  scan4096<<<1,1024,0,stream>>>(deg_t, off_t);
  scatter_k<<<48,256,0,stream>>>(ei, off_g, cur_g, csr_g, off_t, cur_t, csr_t);
  mkdis<<<16,256,0,stream>>>(deg_g, dis);
  pad_x<<<4096,128,0,stream>>>(x, xpad, xph);
  repack_w1<<<5120,256,0,stream>>>(g1_w, w1r);
  // head weight transposes (bf16)
  tpd<<<dim3(8,16),256,0,stream>>>(gcn_w, 256, 0, 512, 512, gcnT);
  tpd<<<dim3(4,47),256,0,stream>>>(fc1_w, 128, 0, 1489, 1496, fc1T);
  tpd<<<dim3(8,4), 256,0,stream>>>(fc2_w, 256, 0, 128, 128, fc2T);
  tpd<<<dim3(8,32),256,0,stream>>>(b1_w,  256, 0, 1024, 1024, b1T);
  tpd<<<dim3(4,8), 256,0,stream>>>(b2_w,  128, 0, 256, 256, b2T);
  tpd<<<dim3(2,4), 256,0,stream>>>(b3_w,  64,  0, 128, 128, b3T);

  // ---- GAT1 (aggregate-first) ----
  wsvec<<<160,256,0,stream>>>(g1_w, g1_as, g1_ad, wsv, wdv, 78, 8, 2048);
  alk<<<4096,256,0,stream>>>(xpad, wsv, wdv, alsd, 80);
  gat1_gather<<<4096,256,0,stream>>>(xpad, alsd, off_g, csr_g, y1h, y1l);
  tpd<<<dim3(64,20),256,0,stream>>>(w1r, 2048, 0, 640, 640, w1rth);
  mgemm<5,1,float><<<dim3(16,32),256,0,stream>>>(y1h, y1l, 640, w1rth, 640,
                                         nullptr, 2048, 640, g1_b, 0.125f, x1h, x1l);

  // ---- GAT2 ----
  wsvec<<<4096,256,0,stream>>>(g2_w, g2_as, g2_ad, wsv, wdv, 2048, 8, 1024);
  mk_wsT<<<128,256,0,stream>>>(wsv, wdv, wsTh, wsTl, 2048);
  hipMemsetAsync(alsd, 0, (size_t)4096*16*4, stream);
  alk_mm<8><<<dim3(8,32),256,0,stream>>>(x1h, x1l, 2048, wsTh, wsTl, alsd, 2048);
  hipMemsetAsync(acc2, 0, (size_t)4096*1024*4, stream);
  for (int c=0;c<2;c++){
    tpd<<<dim3(128,64),256,0,stream>>>(g2_w, 8192, c*4096, 2048, 2048, w2th);
    mgemm<0,0,u16><<<dim3(32,32),256,0,stream>>>(x1h, nullptr, 2048, w2th, 2048,
                                           h2, 4096, 2048, nullptr, 0.f, nullptr, nullptr);
    gat_aggN<4,1024><<<4096,256,0,stream>>>(h2, alsd, off_g, csr_g, acc2, c*4);
  }
  finishx2<<<16384,256,0,stream>>>(acc2, g2_b, x2h, x2l, 1023);

  // ---- GAT3 ----
  wsvec<<<2048,256,0,stream>>>(g3_w, g3_as, g3_ad, wsv, wdv, 1024, 8, 512);
  mk_wsT<<<64,256,0,stream>>>(wsv, wdv, wsTh, wsTl, 1024);
  hipMemsetAsync(alsd, 0, (size_t)4096*16*4, stream);
  alk_mm<8><<<dim3(8,32),256,0,stream>>>(x2h, x2l, 1024, wsTh, wsTl, alsd, 1024);
  hipMemsetAsync(acc3, 0, (size_t)4096*512*4, stream);
  tpd<<<dim3(128,32),256,0,stream>>>(g3_w, 4096, 0, 1024, 1024, w3th);
  mgemm<0,0,u16><<<dim3(32,32),256,0,stream>>>(x2h, nullptr, 1024, w3th, 1024,
                                         h3, 4096, 1024, nullptr, 0.f, nullptr, nullptr);
  gat_aggN<8,512><<<4096,256,0,stream>>>(h3, alsd, off_g, csr_g, acc3, 0);
  finishx<<<8192,256,0,stream>>>(acc3, g3_b, x3, 511);
  pool_gcn<<<128,256,0,stream>>>(x3, dis, off_g, csr_g, zbuf);

  // ---- Transformer branch ----
  tpd<<<dim3(64,3),256,0,stream>>>(t_wq, 2048, 0, 78, 96, qkvTh);
  tpd<<<dim3(64,3),256,0,stream>>>(t_wk, 2048, 0, 78, 96, qkvTh + (size_t)2048*96);
  tpd<<<dim3(64,3),256,0,stream>>>(t_wv, 2048, 0, 78, 96, qkvTh + (size_t)4096*96);
  tpd<<<dim3(16,3),256,0,stream>>>(t_ws, 512,  0, 78, 96, qkvTh + (size_t)6144*96);
  catb<<<26,256,0,stream>>>(t_bq, t_bk, t_bv, t_bs, cbias);
  mgemm<1,0,u16><<<dim3(52,32),256,0,stream>>>(xph, nullptr, 96, qkvTh, 96,
                                         qkvs, 6656, 96, cbias, 0.f, nullptr, nullptr);
  tr_agg<<<4096,256,0,stream>>>(qkvs, off_t, csr_t, xt);

  // ---- fused head ----
  head_k<<<128,256,0,stream>>>(zbuf, xt, fp, gcnT, gcn_b,
                               fc1T, fc1_b, fc2T, fc2_b,
                               b1T, b1_b, b2T, b2_b, b3T, b3_b, b4_w, b4_b,
                               (float*)d_out);
}